// Round 13
// baseline (731.472 us; speedup 1.0000x reference)
//
#include <hip/hip_runtime.h>

#define DEVINL __device__ __forceinline__

typedef __attribute__((ext_vector_type(8))) short bf16x8;
typedef __attribute__((ext_vector_type(8))) unsigned short u16x8;
typedef __attribute__((ext_vector_type(4))) float f32x4;

// RNE f32 -> bf16 bits (no NaN handling needed for this workload)
DEVINL unsigned short f2bh(float f){
  unsigned u = __float_as_uint(f);
  return (unsigned short)((u + 0x7FFFu + ((u >> 16) & 1u)) >> 16);
}
DEVINL float bh2f(unsigned short h){ return __uint_as_float(((unsigned)h) << 16); }

// Wave64 max-reduce of a u64 key via DPP (VALU latency, no DS pipe).
DEVINL unsigned long long dpp_max_u64(unsigned long long k) {
#define DPP_STEP(ctrl)                                                        \
  {                                                                           \
    int hi = (int)(k >> 32), lo = (int)(unsigned)k;                           \
    int oh = __builtin_amdgcn_update_dpp(0, hi, ctrl, 0xF, 0xF, 1);           \
    int ol = __builtin_amdgcn_update_dpp(0, lo, ctrl, 0xF, 0xF, 1);           \
    unsigned long long ok =                                                   \
        ((unsigned long long)(unsigned)oh << 32) | (unsigned)ol;              \
    if (ok > k) k = ok;                                                       \
  }
  DPP_STEP(0x111)  // row_shr:1
  DPP_STEP(0x112)  // row_shr:2
  DPP_STEP(0x114)  // row_shr:4
  DPP_STEP(0x118)  // row_shr:8
  DPP_STEP(0x142)  // row_bcast:15
  DPP_STEP(0x143)  // row_bcast:31
#undef DPP_STEP
  return k;
}

// ---------------------------------------------------------------- FPS body
// R4-proven structure + (a) packed float4 centroid broadcast (1 ds_read_b128)
// and (b) log-depth contiguous-range argmax tree: right element wins only on
// strict > and each merge joins [m,m+off) with [m+off,m+2off), so the
// leftmost (smallest-index) max survives -- bit-identical to the linear scan.
template<int N, int NP, int NT>
DEVINL void fps_body(const float* __restrict__ xyz, float* __restrict__ nxyz,
                     int b, int t) {
  constexpr int PTS = N / NT;
  constexpr int NW = NT / 64;
  __shared__ __align__(16) float4 pts4[N];
  __shared__ int farr[NP];
  __shared__ unsigned long long sk[2][(NW > 1 ? NW : 1)];
  float px[PTS], py[PTS], pz[PTS], dst[PTS];
  const float* base = xyz + (size_t)b * N * 3;
#pragma unroll
  for (int j = 0; j < PTS; ++j) {
    int i = t + j * NT;
    float x = base[i * 3 + 0], y = base[i * 3 + 1], z = base[i * 3 + 2];
    px[j] = x; py[j] = y; pz[j] = z;
    pts4[i] = float4{x, y, z, 0.f};
    dst[j] = 1e10f;
  }
  if constexpr (NW > 1) __syncthreads();
  int far = 0;
  const int wv = t >> 6, ln = t & 63;
  for (int s = 0; s < NP; ++s) {
    float4 c4 = pts4[far];
    float cx = c4.x, cy = c4.y, cz = c4.z;
    if (t == 0) farr[s] = far;
    float v[PTS]; int ix[PTS];
#pragma unroll
    for (int j = 0; j < PTS; ++j) {
      // no-fma, left-to-right: matches numpy elementwise + sum order
      float dx = __fsub_rn(px[j], cx), dy = __fsub_rn(py[j], cy), dz = __fsub_rn(pz[j], cz);
      float d = __fadd_rn(__fadd_rn(__fmul_rn(dx, dx), __fmul_rn(dy, dy)), __fmul_rn(dz, dz));
      float nd = fminf(dst[j], d);
      dst[j] = nd;
      v[j] = nd; ix[j] = j;
    }
#pragma unroll
    for (int off = 1; off < PTS; off <<= 1)
#pragma unroll
      for (int m = 0; m < PTS; m += 2 * off)
        if (v[m + off] > v[m]) { v[m] = v[m + off]; ix[m] = ix[m + off]; }
    float bv = v[0];
    int bi = t + ix[0] * NT;
    // pack: max key == max dist, tie -> larger ~idx == smaller idx
    unsigned long long key =
        ((unsigned long long)__float_as_uint(bv) << 32) | (unsigned)(~bi);
    key = dpp_max_u64(key);
    if constexpr (NW == 1) {
      int rl = __builtin_amdgcn_readlane((int)(unsigned)key, 63);
      far = (int)(~(unsigned)rl);
    } else {
      const int p = s & 1;
      if (ln == 63) sk[p][wv] = key;
      __syncthreads();
      unsigned long long m = sk[p][0];
#pragma unroll
      for (int q = 1; q < NW; ++q) {
        unsigned long long qk = sk[p][q];
        if (qk > m) m = qk;
      }
      far = (int)(~(unsigned)m);
    }
  }
  if constexpr (NW > 1) __syncthreads();
  for (int s2 = t; s2 < NP; s2 += NT) {
    float4 p = pts4[farr[s2]];
    float* o = nxyz + ((size_t)b * NP + s2) * 3;
    o[0] = p.x; o[1] = p.y; o[2] = p.z;
  }
}

// ---------------------------------------------------------------- ball query body (unchanged semantics)
template<int N, int NS>
DEVINL void bq_body(const float* __restrict__ pts, const float* __restrict__ centers,
                    int* __restrict__ gidx, int Q, float r2, int blk, int t) {
  const int wv = t >> 6, ln = t & 63;
  const int g = blk * 4 + wv;
  const int b = g / Q, q = g % Q;
  const float* pb = pts + (size_t)b * N * 3;
  const float* c = centers + ((size_t)b * Q + q) * 3;
  const float cx = c[0], cy = c[1], cz = c[2];
  __shared__ int gbuf[4][NS];
  int taken = 0;
  for (int base = 0; base < N; base += 64) {
    if (taken >= NS) break;
    int i = base + ln;
    float dx = __fsub_rn(pb[i * 3 + 0], cx), dy = __fsub_rn(pb[i * 3 + 1], cy),
          dz = __fsub_rn(pb[i * 3 + 2], cz);
    float d = __fadd_rn(__fadd_rn(__fmul_rn(dx, dx), __fmul_rn(dy, dy)), __fmul_rn(dz, dz));
    bool in = (d <= r2);
    unsigned long long mk = __ballot(in);
    int rank = __popcll(mk & ((1ull << ln) - 1ull));
    int pos = taken + rank;
    if (in && pos < NS) gbuf[wv][pos] = i;
    taken += (int)__popcll(mk);
  }
  int total = taken < NS ? taken : NS;
  int first = gbuf[wv][0];
  int* out = gidx + ((size_t)b * Q + q) * NS;
  for (int j = ln; j < NS; j += 64) out[j] = (j < total) ? gbuf[wv][j] : first;
}

// ---------------------------------------------------------------- weight prep body
struct WPEnt { const float* W; unsigned short* hi; unsigned short* lo; int K, N, row0, beg, end; };
struct WPTab { WPEnt e[8]; };
DEVINL void wprep_body(const WPTab& tab, int idx) {
#pragma unroll
  for (int i = 0; i < 8; ++i) {
    const WPEnt& E = tab.e[i];
    if (idx >= E.beg && idx < E.end) {
      int local = idx - E.beg;
      int k = local / E.N, n = local - k * E.N;
      float v = E.W[(size_t)(E.row0 + k) * E.N + n];
      unsigned short h = f2bh(v);
      E.hi[(size_t)n * E.K + k] = h;
      E.lo[(size_t)n * E.K + k] = f2bh(v - bh2f(h));
    }
  }
}

// ---------------------------------------------------------------- fused launches
// [fps1 || wprep]
__global__ __launch_bounds__(256) void fps1_wprep_kernel(const float* __restrict__ xyz,
                                                         float* __restrict__ nx1, WPTab tab) {
  if (blockIdx.x < 32) { fps_body<4096, 512, 256>(xyz, nx1, blockIdx.x, threadIdx.x); return; }
  wprep_body(tab, (blockIdx.x - 32) * 256 + threadIdx.x);
}

// [fps2 || bq1]: fps2 as single wave (barrier-free); waves 1-3 retire.
__global__ __launch_bounds__(256) void fps2_bq1_kernel(const float* __restrict__ xyz,
                                                       const float* __restrict__ nx1,
                                                       int* __restrict__ gidx1,
                                                       float* __restrict__ nx2, float r21) {
  if (blockIdx.x < 32) {
    if (threadIdx.x < 64) fps_body<512, 128, 64>(nx1, nx2, blockIdx.x, threadIdx.x);
    return;
  }
  bq_body<4096, 32>(xyz, nx1, gidx1, 512, r21, blockIdx.x - 32, threadIdx.x);
}

// ---------------------------------------------------------------- split-bf16 MFMA layer (CW-col chunks)
// T14 async-STAGE prefetch; CW=128 halves barrier phases vs 64-col chunks.
// MFMA order per tile bit-identical.
template<int K, int N, int CW, int AS, int WS, bool XYZC, int NTH>
DEVINL void do_layer(const unsigned short* __restrict__ Ghi, const unsigned short* __restrict__ Glo,
                     const float* __restrict__ Wxyz,
                     const float* __restrict__ A, unsigned short* __restrict__ Whi,
                     unsigned short* __restrict__ Wlo, const float* __restrict__ sxyz,
                     f32x4* acc, int t) {
  constexpr int KT = K / 32;
  constexpr int NCH = N / CW;
  constexpr int K8 = K / 8;
  constexpr int SI = (CW * K8) / NTH;
  constexpr int CT = CW / 16;
  const int l = t & 63, wv = t >> 6;

  u16x8 rh[SI], rl[SI];
#pragma unroll
  for (int s = 0; s < SI; ++s) {
    int u = t + s * NTH;
    int nn = u / K8, k8 = (u - nn * K8) * 8;
    rh[s] = *reinterpret_cast<const u16x8*>(Ghi + (size_t)nn * K + k8);
    rl[s] = *reinterpret_cast<const u16x8*>(Glo + (size_t)nn * K + k8);
  }

  bf16x8 ahi[KT], alo[KT];
  {
    const int row = wv * 16 + (l & 15);
    const float* ap = A + row * AS + (l >> 4) * 8;
#pragma unroll
    for (int kt = 0; kt < KT; ++kt) {
      float4 v0 = *reinterpret_cast<const float4*>(ap + kt * 32);
      float4 v1 = *reinterpret_cast<const float4*>(ap + kt * 32 + 4);
      float f[8] = {v0.x, v0.y, v0.z, v0.w, v1.x, v1.y, v1.z, v1.w};
      bf16x8 h, lo2;
#pragma unroll
      for (int j = 0; j < 8; ++j) {
        unsigned short hb = f2bh(f[j]);
        h[j] = (short)hb;
        lo2[j] = (short)f2bh(f[j] - bh2f(hb));
      }
      ahi[kt] = h; alo[kt] = lo2;
    }
  }
#pragma unroll
  for (int i = 0; i < N / 16; ++i) acc[i] = f32x4{0.f, 0.f, 0.f, 0.f};

#pragma unroll
  for (int c = 0; c < NCH; ++c) {
    __syncthreads();  // all waves done reading previous W contents
#pragma unroll
    for (int s = 0; s < SI; ++s) {
      int u = t + s * NTH;
      int nn = u / K8, k8 = (u - nn * K8) * 8;
      *reinterpret_cast<u16x8*>(Whi + nn * WS + k8) = rh[s];
      *reinterpret_cast<u16x8*>(Wlo + nn * WS + k8) = rl[s];
    }
    if (c + 1 < NCH) {
#pragma unroll
      for (int s = 0; s < SI; ++s) {
        int u = t + s * NTH;
        int nn = u / K8, k8 = (u - nn * K8) * 8;
        rh[s] = *reinterpret_cast<const u16x8*>(Ghi + (size_t)((c + 1) * CW + nn) * K + k8);
        rl[s] = *reinterpret_cast<const u16x8*>(Glo + (size_t)((c + 1) * CW + nn) * K + k8);
      }
    }
    __syncthreads();
#pragma unroll
    for (int ct = 0; ct < CT; ++ct) {
      const unsigned short* wp = Whi + (ct * 16 + (l & 15)) * WS + (l >> 4) * 8;
      const unsigned short* wq = Wlo + (ct * 16 + (l & 15)) * WS + (l >> 4) * 8;
      f32x4 a = acc[c * CT + ct];
#pragma unroll
      for (int kt = 0; kt < KT; ++kt) {
        bf16x8 wh = *reinterpret_cast<const bf16x8*>(wp + kt * 32);
        bf16x8 wl = *reinterpret_cast<const bf16x8*>(wq + kt * 32);
        a = __builtin_amdgcn_mfma_f32_16x16x32_bf16(ahi[kt], wh, a, 0, 0, 0);
        a = __builtin_amdgcn_mfma_f32_16x16x32_bf16(alo[kt], wh, a, 0, 0, 0);
        a = __builtin_amdgcn_mfma_f32_16x16x32_bf16(ahi[kt], wl, a, 0, 0, 0);
      }
      acc[c * CT + ct] = a;
    }
  }
  if constexpr (XYZC) {
    float xr[4][3];
#pragma unroll
    for (int r = 0; r < 4; ++r) {
      int row = wv * 16 + (l >> 4) * 4 + r;
      xr[r][0] = sxyz[row * 4 + 0];
      xr[r][1] = sxyz[row * 4 + 1];
      xr[r][2] = sxyz[row * 4 + 2];
    }
#pragma unroll
    for (int gt = 0; gt < N / 16; ++gt) {
      int col = gt * 16 + (l & 15);
      float w0 = Wxyz[col], w1 = Wxyz[N + col], w2 = Wxyz[2 * N + col];
#pragma unroll
      for (int r = 0; r < 4; ++r)
        acc[gt][r] += xr[r][0] * w0 + xr[r][1] * w1 + xr[r][2] * w2;
    }
  }
}

// ---------------------------------------------------------------- SA2 fused, 512 threads / 128 rows, 128-col chunks
template<int NPTS, int Q, int M, int GPB, int FD, int C1, int C2, int C3>
__global__ __launch_bounds__(512) void sa2_kernel(
    const float* __restrict__ pts, const float* __restrict__ centers,
    const int* __restrict__ gidx, const float* __restrict__ feats,
    const float* __restrict__ W0, const float* __restrict__ B0,
    const unsigned short* __restrict__ G0h, const unsigned short* __restrict__ G0l,
    const unsigned short* __restrict__ G1h, const unsigned short* __restrict__ G1l,
    const float* __restrict__ B1,
    const unsigned short* __restrict__ G2h, const unsigned short* __restrict__ G2l,
    const float* __restrict__ B2,
    float* __restrict__ fout) {
  constexpr int NTH = 512;
  constexpr int ROWS = M * GPB;                 // 128
  constexpr int NWV = NTH / 64;                 // 8
  static_assert(ROWS == 16 * NWV, "wave owns 16 rows");
  constexpr int MK1 = (FD > C1 ? FD : C1);
  constexpr int MAXK = (MK1 > C2 ? MK1 : C2);
  constexpr int AS = MAXK + 12;
  constexpr int WS = MAXK + 8;
  constexpr int CW = 128;
  __shared__ __align__(16) float A[ROWS * AS];
  __shared__ __align__(16) unsigned short Whi[CW * WS];
  __shared__ __align__(16) unsigned short Wlo[CW * WS];
  __shared__ float sxyz[ROWS * 4];
  __shared__ int idxs[ROWS];
  __shared__ float ctr[GPB][4];
  __shared__ float red[NWV][C3];

  const int t = threadIdx.x;
  const int blk = blockIdx.x;
  const int b = blk / (Q / GPB);
  const int q0 = (blk % (Q / GPB)) * GPB;
  const int l = t & 63, wv = t >> 6;

  if (t < GPB * 3) {
    int g = t / 3, c2 = t % 3;
    ctr[g][c2] = centers[((size_t)b * Q + q0 + g) * 3 + c2];
  }
  for (int m = t; m < ROWS; m += NTH)
    idxs[m] = gidx[((size_t)b * Q + q0 + (m / M)) * M + (m % M)];
  __syncthreads();
  const float* pb = pts + (size_t)b * NPTS * 3;
  for (int m = t; m < ROWS; m += NTH) {
    int g = m / M, i = idxs[m];
    sxyz[m * 4 + 0] = pb[i * 3 + 0] - ctr[g][0];
    sxyz[m * 4 + 1] = pb[i * 3 + 1] - ctr[g][1];
    sxyz[m * 4 + 2] = pb[i * 3 + 2] - ctr[g][2];
  }
  {  // FD=128 gather
    const int m = t >> 2, co = (t & 3) * (FD / 4);
    const float* src = feats + ((size_t)b * NPTS + idxs[m]) * FD + co;
    float* dst = A + m * AS + co;
#pragma unroll
    for (int j = 0; j < FD / 4; j += 4)
      *reinterpret_cast<float4*>(dst + j) = *reinterpret_cast<const float4*>(src + j);
  }
  __syncthreads();

  f32x4 acc[C3 / 16];

  do_layer<FD, C1, CW, AS, WS, true, NTH>(G0h, G0l, W0, A, Whi, Wlo, sxyz, acc, t);
#pragma unroll
  for (int gt = 0; gt < C1 / 16; ++gt) {
    int col = gt * 16 + (l & 15);
    float bia = B0[col];
#pragma unroll
    for (int r = 0; r < 4; ++r)
      A[(wv * 16 + (l >> 4) * 4 + r) * AS + col] = fmaxf(acc[gt][r] + bia, 0.f);
  }

  do_layer<C1, C2, CW, AS, WS, false, NTH>(G1h, G1l, nullptr, A, Whi, Wlo, sxyz, acc, t);
#pragma unroll
  for (int gt = 0; gt < C2 / 16; ++gt) {
    int col = gt * 16 + (l & 15);
    float bia = B1[col];
#pragma unroll
    for (int r = 0; r < 4; ++r)
      A[(wv * 16 + (l >> 4) * 4 + r) * AS + col] = fmaxf(acc[gt][r] + bia, 0.f);
  }

  do_layer<C2, C3, CW, AS, WS, false, NTH>(G2h, G2l, nullptr, A, Whi, Wlo, sxyz, acc, t);
#pragma unroll
  for (int gt = 0; gt < C3 / 16; ++gt) {
    int col = gt * 16 + (l & 15);
    float v = fmaxf(fmaxf(acc[gt][0], acc[gt][1]), fmaxf(acc[gt][2], acc[gt][3]));
    v = fmaxf(v, __shfl_xor(v, 16, 64));
    v = fmaxf(v, __shfl_xor(v, 32, 64));
    if (l < 16) red[wv][col] = v + B2[col];
  }
  __syncthreads();
  constexpr int WPG = NWV / GPB;
  for (int u = t; u < GPB * C3; u += NTH) {
    int g = u / C3, c2 = u - g * C3;
    float v = red[g * WPG][c2];
#pragma unroll
    for (int w = 1; w < WPG; ++w) v = fmaxf(v, red[g * WPG + w][c2]);
    fout[((size_t)b * Q + q0 + g) * C3 + c2] = fmaxf(v, 0.f);
  }
}

// ---------------------------------------------------------------- SA1 body, grid-strided: stage W once, process TPB tiles
template<int NPTS, int Q, int M, int GPB, int TPB>
DEVINL void sa1_body(const float* __restrict__ pts, const float* __restrict__ centers,
                     const int* __restrict__ gidx,
                     const float* __restrict__ W0, const float* __restrict__ B0,
                     const unsigned short* __restrict__ G1h, const unsigned short* __restrict__ G1l,
                     const float* __restrict__ B1,
                     const unsigned short* __restrict__ G2h, const unsigned short* __restrict__ G2l,
                     const float* __restrict__ B2,
                     float* __restrict__ fout, int sblk, int t) {
  static_assert(M * GPB == 64, "");
  constexpr int C1 = 64, C2 = 64, C3 = 128;
  constexpr int AS = 76;
  constexpr int WS = 72;
  constexpr int NC = C2 + C3;
  __shared__ __align__(16) float A[64 * AS];
  __shared__ __align__(16) unsigned short Wh[NC * WS];
  __shared__ __align__(16) unsigned short Wl[NC * WS];
  __shared__ float sxyz[64 * 4];
  __shared__ int idxs[64];
  __shared__ float ctr[GPB][4];
  __shared__ float red[4][C3];

  const int l = t & 63, wv = t >> 6;

  for (int u = t; u < NC * 8; u += 256) {
    int col = u >> 3, k8 = (u & 7) * 8;
    const unsigned short* sh = (col < C2) ? G1h + (size_t)col * 64 + k8
                                          : G2h + (size_t)(col - C2) * 64 + k8;
    const unsigned short* sl = (col < C2) ? G1l + (size_t)col * 64 + k8
                                          : G2l + (size_t)(col - C2) * 64 + k8;
    *reinterpret_cast<u16x8*>(Wh + col * WS + k8) = *reinterpret_cast<const u16x8*>(sh);
    *reinterpret_cast<u16x8*>(Wl + col * WS + k8) = *reinterpret_cast<const u16x8*>(sl);
  }

  for (int it = 0; it < TPB; ++it) {
    const int blk = sblk * TPB + it;
    const int b = blk / (Q / GPB);
    const int q0 = (blk % (Q / GPB)) * GPB;

    if (t < GPB * 3) {
      int g = t / 3, c2 = t % 3;
      ctr[g][c2] = centers[((size_t)b * Q + q0 + g) * 3 + c2];
    }
    for (int m = t; m < 64; m += 256)
      idxs[m] = gidx[((size_t)b * Q + q0 + (m / M)) * M + (m % M)];
    __syncthreads();
    const float* pb = pts + (size_t)b * NPTS * 3;
    for (int m = t; m < 64; m += 256) {
      int g = m / M, i = idxs[m];
      sxyz[m * 4 + 0] = pb[i * 3 + 0] - ctr[g][0];
      sxyz[m * 4 + 1] = pb[i * 3 + 1] - ctr[g][1];
      sxyz[m * 4 + 2] = pb[i * 3 + 2] - ctr[g][2];
    }
    __syncthreads();

    for (int u = t; u < 64 * C1; u += 256) {
      int m = u / C1, c2 = u - m * C1;
      float v = B0[c2] + sxyz[m * 4 + 0] * W0[0 * C1 + c2]
                       + sxyz[m * 4 + 1] * W0[1 * C1 + c2]
                       + sxyz[m * 4 + 2] * W0[2 * C1 + c2];
      A[m * AS + c2] = fmaxf(v, 0.f);
    }
    __syncthreads();

    f32x4 acc[8];
    // ---- L2: 64 -> 64, W cols [0,64), barrier-free
    {
      bf16x8 ah[2], al[2];
      const float* ap = A + (wv * 16 + (l & 15)) * AS + (l >> 4) * 8;
#pragma unroll
      for (int kt = 0; kt < 2; ++kt) {
        float4 v0 = *reinterpret_cast<const float4*>(ap + kt * 32);
        float4 v1 = *reinterpret_cast<const float4*>(ap + kt * 32 + 4);
        float f[8] = {v0.x, v0.y, v0.z, v0.w, v1.x, v1.y, v1.z, v1.w};
        bf16x8 h, lo2;
#pragma unroll
        for (int j = 0; j < 8; ++j) {
          unsigned short hb = f2bh(f[j]);
          h[j] = (short)hb;
          lo2[j] = (short)f2bh(f[j] - bh2f(hb));
        }
        ah[kt] = h; al[kt] = lo2;
      }
#pragma unroll
      for (int i = 0; i < 4; ++i) acc[i] = f32x4{0.f, 0.f, 0.f, 0.f};
#pragma unroll
      for (int ct = 0; ct < 4; ++ct) {
        const unsigned short* wp = Wh + (ct * 16 + (l & 15)) * WS + (l >> 4) * 8;
        const unsigned short* wq = Wl + (ct * 16 + (l & 15)) * WS + (l >> 4) * 8;
        f32x4 a = acc[ct];
#pragma unroll
        for (int kt = 0; kt < 2; ++kt) {
          bf16x8 wh = *reinterpret_cast<const bf16x8*>(wp + kt * 32);
          bf16x8 wl = *reinterpret_cast<const bf16x8*>(wq + kt * 32);
          a = __builtin_amdgcn_mfma_f32_16x16x32_bf16(ah[kt], wh, a, 0, 0, 0);
          a = __builtin_amdgcn_mfma_f32_16x16x32_bf16(al[kt], wh, a, 0, 0, 0);
          a = __builtin_amdgcn_mfma_f32_16x16x32_bf16(ah[kt], wl, a, 0, 0, 0);
        }
        acc[ct] = a;
      }
#pragma unroll
      for (int gt = 0; gt < 4; ++gt) {
        int col = gt * 16 + (l & 15);
        float bia = B1[col];
#pragma unroll
        for (int r = 0; r < 4; ++r)
          A[(wv * 16 + (l >> 4) * 4 + r) * AS + col] = fmaxf(acc[gt][r] + bia, 0.f);
      }
    }

    // ---- L3: 64 -> 128, W cols [64,192), maxpool epilogue
    {
      bf16x8 ah[2], al[2];
      const float* ap = A + (wv * 16 + (l & 15)) * AS + (l >> 4) * 8;
#pragma unroll
      for (int kt = 0; kt < 2; ++kt) {
        float4 v0 = *reinterpret_cast<const float4*>(ap + kt * 32);
        float4 v1 = *reinterpret_cast<const float4*>(ap + kt * 32 + 4);
        float f[8] = {v0.x, v0.y, v0.z, v0.w, v1.x, v1.y, v1.z, v1.w};
        bf16x8 h, lo2;
#pragma unroll
        for (int j = 0; j < 8; ++j) {
          unsigned short hb = f2bh(f[j]);
          h[j] = (short)hb;
          lo2[j] = (short)f2bh(f[j] - bh2f(hb));
        }
        ah[kt] = h; al[kt] = lo2;
      }
#pragma unroll
      for (int i = 0; i < 8; ++i) acc[i] = f32x4{0.f, 0.f, 0.f, 0.f};
#pragma unroll
      for (int gt = 0; gt < 8; ++gt) {
        const unsigned short* wp = Wh + (C2 + gt * 16 + (l & 15)) * WS + (l >> 4) * 8;
        const unsigned short* wq = Wl + (C2 + gt * 16 + (l & 15)) * WS + (l >> 4) * 8;
        f32x4 a = acc[gt];
#pragma unroll
        for (int kt = 0; kt < 2; ++kt) {
          bf16x8 wh = *reinterpret_cast<const bf16x8*>(wp + kt * 32);
          bf16x8 wl = *reinterpret_cast<const bf16x8*>(wq + kt * 32);
          a = __builtin_amdgcn_mfma_f32_16x16x32_bf16(ah[kt], wh, a, 0, 0, 0);
          a = __builtin_amdgcn_mfma_f32_16x16x32_bf16(al[kt], wh, a, 0, 0, 0);
          a = __builtin_amdgcn_mfma_f32_16x16x32_bf16(ah[kt], wl, a, 0, 0, 0);
        }
        acc[gt] = a;
      }
#pragma unroll
      for (int gt = 0; gt < 8; ++gt) {
        int col = gt * 16 + (l & 15);
        float v = fmaxf(fmaxf(acc[gt][0], acc[gt][1]), fmaxf(acc[gt][2], acc[gt][3]));
        v = fmaxf(v, __shfl_xor(v, 16, 64));
        v = fmaxf(v, __shfl_xor(v, 32, 64));
        if (l < 16) red[wv][col] = v + B2[col];
      }
    }
    __syncthreads();
    constexpr int WPG = 4 / GPB;
    for (int u = t; u < GPB * C3; u += 256) {
      int g = u / C3, c2 = u - g * C3;
      float v = red[g * WPG][c2];
#pragma unroll
      for (int w = 1; w < WPG; ++w) v = fmaxf(v, red[g * WPG + w][c2]);
      fout[((size_t)b * Q + q0 + g) * C3 + c2] = fmaxf(v, 0.f);
    }
    __syncthreads();
  }
}

// [bq2 || sa1]
__global__ __launch_bounds__(256) void bq2_sa1_kernel(
    const float* __restrict__ xyz, const float* __restrict__ nx1,
    const float* __restrict__ nx2, int* __restrict__ gidx2, float r22,
    const int* __restrict__ gidx1,
    const float* __restrict__ s1w0, const float* __restrict__ s1b0,
    const unsigned short* __restrict__ g11h, const unsigned short* __restrict__ g11l,
    const float* __restrict__ s1b1,
    const unsigned short* __restrict__ g12h, const unsigned short* __restrict__ g12l,
    const float* __restrict__ s1b2, float* __restrict__ f1) {
  if (blockIdx.x < 1024) {
    bq_body<512, 64>(nx1, nx2, gidx2, 128, r22, blockIdx.x, threadIdx.x);
    return;
  }
  sa1_body<4096, 512, 32, 2, 8>(xyz, nx1, gidx1, s1w0, s1b0, g11h, g11l, s1b1,
                                g12h, g12l, s1b2, f1, blockIdx.x - 1024, threadIdx.x);
}

// ---------------------------------------------------------------- SA3 fused
constexpr int AS3 = 532;
DEVINL void sa3_frags(const float* __restrict__ A, int l, int KT, bf16x8* ahi, bf16x8* alo) {
  const float* ap = A + (l & 15) * AS3 + (l >> 4) * 8;
  for (int kt = 0; kt < KT; ++kt) {
    float4 v0 = *reinterpret_cast<const float4*>(ap + kt * 32);
    float4 v1 = *reinterpret_cast<const float4*>(ap + kt * 32 + 4);
    float f[8] = {v0.x, v0.y, v0.z, v0.w, v1.x, v1.y, v1.z, v1.w};
    bf16x8 h, lo2;
#pragma unroll
    for (int j = 0; j < 8; ++j) {
      unsigned short hb = f2bh(f[j]);
      h[j] = (short)hb;
      lo2[j] = (short)f2bh(f[j] - bh2f(hb));
    }
    ahi[kt] = h; alo[kt] = lo2;
  }
}

template<int K>
DEVINL void sa3_mm64(const unsigned short* __restrict__ Gh, const unsigned short* __restrict__ Gl,
                     int ncol0, int l, const bf16x8* ahi, const bf16x8* alo, f32x4* acc4) {
  constexpr int KT = K / 32;
#pragma unroll
  for (int ct = 0; ct < 4; ++ct) {
    const unsigned short* hp = Gh + (size_t)(ncol0 + ct * 16 + (l & 15)) * K + (l >> 4) * 8;
    const unsigned short* lp = Gl + (size_t)(ncol0 + ct * 16 + (l & 15)) * K + (l >> 4) * 8;
    f32x4 a = acc4[ct];
#pragma unroll
    for (int kt = 0; kt < KT; ++kt) {
      bf16x8 wh = *reinterpret_cast<const bf16x8*>(hp + kt * 32);
      bf16x8 wl = *reinterpret_cast<const bf16x8*>(lp + kt * 32);
      a = __builtin_amdgcn_mfma_f32_16x16x32_bf16(ahi[kt], wh, a, 0, 0, 0);
      a = __builtin_amdgcn_mfma_f32_16x16x32_bf16(alo[kt], wh, a, 0, 0, 0);
      a = __builtin_amdgcn_mfma_f32_16x16x32_bf16(ahi[kt], wl, a, 0, 0, 0);
    }
    acc4[ct] = a;
  }
}

__global__ __launch_bounds__(256) void sa3f_kernel(
    const float* __restrict__ nx2, const float* __restrict__ f2,
    const float* __restrict__ W0full,
    const unsigned short* __restrict__ G0h, const unsigned short* __restrict__ G0l,
    const float* __restrict__ B0,
    const unsigned short* __restrict__ G1h, const unsigned short* __restrict__ G1l,
    const float* __restrict__ B1,
    const unsigned short* __restrict__ G2h, const unsigned short* __restrict__ G2l,
    const float* __restrict__ B2,
    float* __restrict__ partial) {
  __shared__ __align__(16) float A[16 * AS3];
  __shared__ float sxyz[16][4];
  const int t = threadIdx.x, l = t & 63, w = t >> 6;
  const int b = blockIdx.x >> 3, rb = blockIdx.x & 7;
  const int row0 = rb * 16;
  {
    int r = t >> 4, cc = (t & 15) * 16;
    const float* src = f2 + ((size_t)b * 128 + row0 + r) * 256 + cc;
    float* dstp = A + r * AS3 + cc;
#pragma unroll
    for (int j = 0; j < 16; j += 4)
      *reinterpret_cast<float4*>(dstp + j) = *reinterpret_cast<const float4*>(src + j);
    if (t < 16) {
      const float* s = nx2 + ((size_t)b * 128 + row0 + t) * 3;
      sxyz[t][0] = s[0]; sxyz[t][1] = s[1]; sxyz[t][2] = s[2];
    }
  }
  __syncthreads();

  {  // L1: K=256 MFMA + xyz f32 correction -> N=256 (wave cols 64)
    bf16x8 ah[8], al[8];
    sa3_frags(A, l, 8, ah, al);
    __syncthreads();
    f32x4 acc[4];
#pragma unroll
    for (int i = 0; i < 4; ++i) acc[i] = f32x4{0.f, 0.f, 0.f, 0.f};
    sa3_mm64<256>(G0h, G0l, w * 64, l, ah, al, acc);
    float xr[4][3];
#pragma unroll
    for (int r = 0; r < 4; ++r) {
      int row = (l >> 4) * 4 + r;
      xr[r][0] = sxyz[row][0]; xr[r][1] = sxyz[row][1]; xr[r][2] = sxyz[row][2];
    }
#pragma unroll
    for (int ct = 0; ct < 4; ++ct) {
      int col = w * 64 + ct * 16 + (l & 15);
      float w0 = W0full[col], w1 = W0full[256 + col], w2 = W0full[512 + col];
      float bia = B0[col];
#pragma unroll
      for (int r = 0; r < 4; ++r) {
        int row = (l >> 4) * 4 + r;
        float v = acc[ct][r] + xr[r][0] * w0 + xr[r][1] * w1 + xr[r][2] * w2 + bia;
        A[row * AS3 + col] = fmaxf(v, 0.f);
      }
    }
    __syncthreads();
  }

  {  // L2: K=256 -> N=512 (wave cols 128)
    bf16x8 ah[8], al[8];
    sa3_frags(A, l, 8, ah, al);
    __syncthreads();
    f32x4 acc[8];
#pragma unroll
    for (int i = 0; i < 8; ++i) acc[i] = f32x4{0.f, 0.f, 0.f, 0.f};
    sa3_mm64<256>(G1h, G1l, w * 128, l, ah, al, acc);
    sa3_mm64<256>(G1h, G1l, w * 128 + 64, l, ah, al, acc + 4);
#pragma unroll
    for (int cc = 0; cc < 8; ++cc) {
      int col = w * 128 + cc * 16 + (l & 15);
      float bia = B1[col];
#pragma unroll
      for (int r = 0; r < 4; ++r) {
        int row = (l >> 4) * 4 + r;
        A[row * AS3 + col] = fmaxf(acc[cc][r] + bia, 0.f);
      }
    }
    __syncthreads();
  }

  {  // L3: K=512 -> N=1024 (wave cols 256), maxpool 16 rows -> partial
    bf16x8 ah[16], al[16];
    sa3_frags(A, l, 16, ah, al);
    float* pout = partial + ((size_t)(b * 8 + rb)) * 1024;
#pragma unroll
    for (int sub = 0; sub < 4; ++sub) {
      f32x4 acc[4];
#pragma unroll
      for (int i = 0; i < 4; ++i) acc[i] = f32x4{0.f, 0.f, 0.f, 0.f};
      sa3_mm64<512>(G2h, G2l, w * 256 + sub * 64, l, ah, al, acc);
#pragma unroll
      for (int ct = 0; ct < 4; ++ct) {
        int col = w * 256 + sub * 64 + ct * 16 + (l & 15);
        float v = fmaxf(fmaxf(acc[ct][0], acc[ct][1]), fmaxf(acc[ct][2], acc[ct][3]));
        v = fmaxf(v, __shfl_xor(v, 16, 64));
        v = fmaxf(v, __shfl_xor(v, 32, 64));
        if (l < 16) pout[col] = v + B2[col];  // relu deferred to heads (monotone)
      }
    }
  }
}

// ---------------------------------------------------------------- heads (8-way partial max + relu + dots)
__global__ __launch_bounds__(256) void heads_kernel(const float* __restrict__ partial,
                                                    const float* __restrict__ cw,
                                                    const float* __restrict__ cb,
                                                    const float* __restrict__ rw,
                                                    const float* __restrict__ rb,
                                                    float* __restrict__ out) {
  const int b = blockIdx.x, t = threadIdx.x;
  const float* pb = partial + (size_t)b * 8 * 1024;
  float a0 = 0, a1 = 0, a2 = 0, a3 = 0, a4 = 0;
  for (int k = t; k < 1024; k += 256) {
    float m = pb[k];
#pragma unroll
    for (int p = 1; p < 8; ++p) m = fmaxf(m, pb[p * 1024 + k]);
    float f = fmaxf(m, 0.f);
    a0 += f * cw[k];
    const float* r = rw + (size_t)k * 4;
    a1 += f * r[0]; a2 += f * r[1]; a3 += f * r[2]; a4 += f * r[3];
  }
#pragma unroll
  for (int m = 32; m >= 1; m >>= 1) {
    a0 += __shfl_xor(a0, m, 64); a1 += __shfl_xor(a1, m, 64);
    a2 += __shfl_xor(a2, m, 64); a3 += __shfl_xor(a3, m, 64);
    a4 += __shfl_xor(a4, m, 64);
  }
  __shared__ float red[4][5];
  const int wv = t >> 6, ln = t & 63;
  if (ln == 0) { red[wv][0] = a0; red[wv][1] = a1; red[wv][2] = a2; red[wv][3] = a3; red[wv][4] = a4; }
  __syncthreads();
  if (t == 0) {
    float s0 = red[0][0] + red[1][0] + red[2][0] + red[3][0];
    float s1 = red[0][1] + red[1][1] + red[2][1] + red[3][1];
    float s2 = red[0][2] + red[1][2] + red[2][2] + red[3][2];
    float s3 = red[0][3] + red[1][3] + red[2][3] + red[3][3];
    float s4 = red[0][4] + red[1][4] + red[2][4] + red[3][4];
    out[b] = s0 + cb[0];
    out[32 + b * 4 + 0] = s1 + rb[0];
    out[32 + b * 4 + 1] = s2 + rb[1];
    out[32 + b * 4 + 2] = s3 + rb[2];
    out[32 + b * 4 + 3] = s4 + rb[3];
  }
}

// ---------------------------------------------------------------- launch
extern "C" void kernel_launch(void* const* d_in, const int* in_sizes, int n_in,
                              void* d_out, int out_size, void* d_ws, size_t ws_size,
                              hipStream_t stream) {
  (void)in_sizes; (void)n_in; (void)out_size; (void)ws_size;
  const float* xyz  = (const float*)d_in[0];
  const float* s1w0 = (const float*)d_in[1];  const float* s1b0 = (const float*)d_in[2];
  const float* s1w1 = (const float*)d_in[3];  const float* s1b1 = (const float*)d_in[4];
  const float* s1w2 = (const float*)d_in[5];  const float* s1b2 = (const float*)d_in[6];
  const float* s2w0 = (const float*)d_in[7];  const float* s2b0 = (const float*)d_in[8];
  const float* s2w1 = (const float*)d_in[9];  const float* s2b1 = (const float*)d_in[10];
  const float* s2w2 = (const float*)d_in[11]; const float* s2b2 = (const float*)d_in[12];
  const float* s3w0 = (const float*)d_in[13]; const float* s3b0 = (const float*)d_in[14];
  const float* s3w1 = (const float*)d_in[15]; const float* s3b1 = (const float*)d_in[16];
  const float* s3w2 = (const float*)d_in[17]; const float* s3b2 = (const float*)d_in[18];
  const float* clsw = (const float*)d_in[19]; const float* clsb = (const float*)d_in[20];
  const float* regw = (const float*)d_in[21]; const float* regb = (const float*)d_in[22];

  char* ws = (char*)d_ws;
  float* nx1   = (float*)(ws + 0);          // 32*512*3
  int*   gidx1 = (int*)  (ws + 196608);     // 32*512*32
  float* f1    = (float*)(ws + 2293760);    // 32*512*128
  float* nx2   = (float*)(ws + 10682368);   // 32*128*3
  int*   gidx2 = (int*)  (ws + 10731520);   // 32*128*64
  float* f2    = (float*)(ws + 11780096);   // 32*128*256

  // SA1/SA2 prepped weights (u16 hi/lo, transposed [n][k])
  unsigned short* wt = (unsigned short*)(ws + 20168704);
  unsigned short* g11h = wt;            // 64*64
  unsigned short* g11l = wt + 4096;
  unsigned short* g12h = wt + 8192;     // 128*64
  unsigned short* g12l = wt + 16384;
  unsigned short* g20h = wt + 24576;    // 128*128 (rows 3..130 of s2w0)
  unsigned short* g20l = wt + 40960;
  unsigned short* g21h = wt + 57344;    // 128*128
  unsigned short* g21l = wt + 73728;
  unsigned short* g22h = wt + 90112;    // 256*128
  unsigned short* g22l = wt + 122880;   // ends at byte 20168704+311296 = 20480000
  // SA3 prepped weights
  unsigned short* g30h = (unsigned short*)(ws + 20480000);  // 256x256
  unsigned short* g30l = (unsigned short*)(ws + 20611072);
  unsigned short* g31h = (unsigned short*)(ws + 20742144);  // 512x256
  unsigned short* g31l = (unsigned short*)(ws + 21004288);
  unsigned short* g32h = (unsigned short*)(ws + 21266432);  // 1024x512
  unsigned short* g32l = (unsigned short*)(ws + 22315008);
  float* partial = (float*)(ws + 23363584);                 // 32*8*1024 f32 -> ends 24412160

  const float r21 = (float)(0.2 * 0.2);
  const float r22 = (float)(0.4 * 0.4);

  WPTab tab;
  int off = 0;
  auto set = [&](int i, const float* W, unsigned short* hi, unsigned short* lo,
                 int K, int N, int row0) {
    tab.e[i] = WPEnt{W, hi, lo, K, N, row0, off, off + K * N};
    off += K * N;
  };
  set(0, s1w1, g11h, g11l, 64, 64, 0);
  set(1, s1w2, g12h, g12l, 64, 128, 0);
  set(2, s2w0, g20h, g20l, 128, 128, 3);
  set(3, s2w1, g21h, g21l, 128, 128, 0);
  set(4, s2w2, g22h, g22l, 128, 256, 0);
  set(5, s3w0, g30h, g30l, 256, 256, 3);
  set(6, s3w1, g31h, g31l, 256, 512, 0);
  set(7, s3w2, g32h, g32l, 512, 1024, 0);
  const int wblocks = (off + 255) / 256;

  fps1_wprep_kernel<<<32 + wblocks, 256, 0, stream>>>(xyz, nx1, tab);
  fps2_bq1_kernel<<<32 + 4096, 256, 0, stream>>>(xyz, nx1, gidx1, nx2, r21);
  bq2_sa1_kernel<<<1024 + 1024, 256, 0, stream>>>(
      xyz, nx1, nx2, gidx2, r22, gidx1,
      s1w0, s1b0, g11h, g11l, s1b1, g12h, g12l, s1b2, f1);
  sa2_kernel<512, 128, 64, 2, 128, 128, 128, 256><<<2048, 512, 0, stream>>>(
      nx1, nx2, gidx2, f1, s2w0, s2b0,
      g20h, g20l, g21h, g21l, s2b1, g22h, g22l, s2b2, f2);
  sa3f_kernel<<<256, 256, 0, stream>>>(nx2, f2, s3w0, g30h, g30l, s3b0,
                                       g31h, g31l, s3b1, g32h, g32l, s3b2, partial);
  heads_kernel<<<32, 256, 0, stream>>>(partial, clsw, clsb, regw, regb, (float*)d_out);
}

// Round 14
// 707.310 us; speedup vs baseline: 1.0342x; 1.0342x over previous
//
#include <hip/hip_runtime.h>

#define DEVINL __device__ __forceinline__

typedef __attribute__((ext_vector_type(8))) short bf16x8;
typedef __attribute__((ext_vector_type(8))) unsigned short u16x8;
typedef __attribute__((ext_vector_type(4))) float f32x4;

// RNE f32 -> bf16 bits (no NaN handling needed for this workload)
DEVINL unsigned short f2bh(float f){
  unsigned u = __float_as_uint(f);
  return (unsigned short)((u + 0x7FFFu + ((u >> 16) & 1u)) >> 16);
}
DEVINL float bh2f(unsigned short h){ return __uint_as_float(((unsigned)h) << 16); }

// Wave64 max-reduce of a u64 key via DPP (VALU latency, no DS pipe).
DEVINL unsigned long long dpp_max_u64(unsigned long long k) {
#define DPP_STEP(ctrl)                                                        \
  {                                                                           \
    int hi = (int)(k >> 32), lo = (int)(unsigned)k;                           \
    int oh = __builtin_amdgcn_update_dpp(0, hi, ctrl, 0xF, 0xF, 1);           \
    int ol = __builtin_amdgcn_update_dpp(0, lo, ctrl, 0xF, 0xF, 1);           \
    unsigned long long ok =                                                   \
        ((unsigned long long)(unsigned)oh << 32) | (unsigned)ol;              \
    if (ok > k) k = ok;                                                       \
  }
  DPP_STEP(0x111)  // row_shr:1
  DPP_STEP(0x112)  // row_shr:2
  DPP_STEP(0x114)  // row_shr:4
  DPP_STEP(0x118)  // row_shr:8
  DPP_STEP(0x142)  // row_bcast:15
  DPP_STEP(0x143)  // row_bcast:31
#undef DPP_STEP
  return k;
}

// ---------------------------------------------------------------- FPS body (R4-proven, LOCKED)
// Two tree-based variants regressed (R5, R13): the linear strict-> scan with
// split scalar LDS arrays is the measured optimum for this chain. Do not
// touch the inner loop again.
template<int N, int NP, int NT>
DEVINL void fps_body(const float* __restrict__ xyz, float* __restrict__ nxyz,
                     int b, int t) {
  constexpr int PTS = N / NT;
  constexpr int NW = NT / 64;
  __shared__ float xs[N], ys[N], zs[N];
  __shared__ int farr[NP];
  __shared__ unsigned long long sk[2][(NW > 1 ? NW : 1)];
  float px[PTS], py[PTS], pz[PTS], dst[PTS];
  const float* base = xyz + (size_t)b * N * 3;
#pragma unroll
  for (int j = 0; j < PTS; ++j) {
    int i = t + j * NT;
    float x = base[i * 3 + 0], y = base[i * 3 + 1], z = base[i * 3 + 2];
    px[j] = x; py[j] = y; pz[j] = z;
    xs[i] = x; ys[i] = y; zs[i] = z;
    dst[j] = 1e10f;
  }
  if constexpr (NW > 1) __syncthreads();
  int far = 0;
  const int wv = t >> 6, ln = t & 63;
  for (int s = 0; s < NP; ++s) {
    float cx = xs[far], cy = ys[far], cz = zs[far];
    if (t == 0) farr[s] = far;
    float bv = -1.f; int bi = 0;
#pragma unroll
    for (int j = 0; j < PTS; ++j) {
      // no-fma, left-to-right: matches numpy elementwise + sum order
      float dx = __fsub_rn(px[j], cx), dy = __fsub_rn(py[j], cy), dz = __fsub_rn(pz[j], cz);
      float d = __fadd_rn(__fadd_rn(__fmul_rn(dx, dx), __fmul_rn(dy, dy)), __fmul_rn(dz, dz));
      float nd = fminf(dst[j], d);
      dst[j] = nd;
      int i = t + j * NT;
      if (nd > bv) { bv = nd; bi = i; }  // strict >: first max kept per thread
    }
    // pack: max key == max dist, tie -> larger ~idx == smaller idx
    unsigned long long key =
        ((unsigned long long)__float_as_uint(bv) << 32) | (unsigned)(~bi);
    key = dpp_max_u64(key);
    if constexpr (NW == 1) {
      int rl = __builtin_amdgcn_readlane((int)(unsigned)key, 63);
      far = (int)(~(unsigned)rl);
    } else {
      const int p = s & 1;
      if (ln == 63) sk[p][wv] = key;
      __syncthreads();
      unsigned long long m = sk[p][0];
#pragma unroll
      for (int q = 1; q < NW; ++q) {
        unsigned long long qk = sk[p][q];
        if (qk > m) m = qk;
      }
      far = (int)(~(unsigned)m);
    }
  }
  if constexpr (NW > 1) __syncthreads();
  for (int s2 = t; s2 < NP; s2 += NT) {
    int fi = farr[s2];
    float* o = nxyz + ((size_t)b * NP + s2) * 3;
    o[0] = xs[fi]; o[1] = ys[fi]; o[2] = zs[fi];
  }
}

// ---------------------------------------------------------------- ball query body (unchanged semantics)
template<int N, int NS>
DEVINL void bq_body(const float* __restrict__ pts, const float* __restrict__ centers,
                    int* __restrict__ gidx, int Q, float r2, int blk, int t) {
  const int wv = t >> 6, ln = t & 63;
  const int g = blk * 4 + wv;
  const int b = g / Q, q = g % Q;
  const float* pb = pts + (size_t)b * N * 3;
  const float* c = centers + ((size_t)b * Q + q) * 3;
  const float cx = c[0], cy = c[1], cz = c[2];
  __shared__ int gbuf[4][NS];
  int taken = 0;
  for (int base = 0; base < N; base += 64) {
    if (taken >= NS) break;
    int i = base + ln;
    float dx = __fsub_rn(pb[i * 3 + 0], cx), dy = __fsub_rn(pb[i * 3 + 1], cy),
          dz = __fsub_rn(pb[i * 3 + 2], cz);
    float d = __fadd_rn(__fadd_rn(__fmul_rn(dx, dx), __fmul_rn(dy, dy)), __fmul_rn(dz, dz));
    bool in = (d <= r2);
    unsigned long long mk = __ballot(in);
    int rank = __popcll(mk & ((1ull << ln) - 1ull));
    int pos = taken + rank;
    if (in && pos < NS) gbuf[wv][pos] = i;
    taken += (int)__popcll(mk);
  }
  int total = taken < NS ? taken : NS;
  int first = gbuf[wv][0];
  int* out = gidx + ((size_t)b * Q + q) * NS;
  for (int j = ln; j < NS; j += 64) out[j] = (j < total) ? gbuf[wv][j] : first;
}

// ---------------------------------------------------------------- weight prep body
struct WPEnt { const float* W; unsigned short* hi; unsigned short* lo; int K, N, row0, beg, end; };
struct WPTab { WPEnt e[8]; };
DEVINL void wprep_body(const WPTab& tab, int idx) {
#pragma unroll
  for (int i = 0; i < 8; ++i) {
    const WPEnt& E = tab.e[i];
    if (idx >= E.beg && idx < E.end) {
      int local = idx - E.beg;
      int k = local / E.N, n = local - k * E.N;
      float v = E.W[(size_t)(E.row0 + k) * E.N + n];
      unsigned short h = f2bh(v);
      E.hi[(size_t)n * E.K + k] = h;
      E.lo[(size_t)n * E.K + k] = f2bh(v - bh2f(h));
    }
  }
}

// ---------------------------------------------------------------- fused launches
// [fps1 || wprep]
__global__ __launch_bounds__(256) void fps1_wprep_kernel(const float* __restrict__ xyz,
                                                         float* __restrict__ nx1, WPTab tab) {
  if (blockIdx.x < 32) { fps_body<4096, 512, 256>(xyz, nx1, blockIdx.x, threadIdx.x); return; }
  wprep_body(tab, (blockIdx.x - 32) * 256 + threadIdx.x);
}

// [fps2 || bq1]: fps2 as single wave (barrier-free); waves 1-3 retire.
__global__ __launch_bounds__(256) void fps2_bq1_kernel(const float* __restrict__ xyz,
                                                       const float* __restrict__ nx1,
                                                       int* __restrict__ gidx1,
                                                       float* __restrict__ nx2, float r21) {
  if (blockIdx.x < 32) {
    if (threadIdx.x < 64) fps_body<512, 128, 64>(nx1, nx2, blockIdx.x, threadIdx.x);
    return;
  }
  bq_body<4096, 32>(xyz, nx1, gidx1, 512, r21, blockIdx.x - 32, threadIdx.x);
}

// ---------------------------------------------------------------- split-bf16 MFMA layer (CW-col chunks)
// T14 async-STAGE prefetch; CW=128 halves barrier phases vs 64-col chunks.
template<int K, int N, int CW, int AS, int WS, bool XYZC, int NTH>
DEVINL void do_layer(const unsigned short* __restrict__ Ghi, const unsigned short* __restrict__ Glo,
                     const float* __restrict__ Wxyz,
                     const float* __restrict__ A, unsigned short* __restrict__ Whi,
                     unsigned short* __restrict__ Wlo, const float* __restrict__ sxyz,
                     f32x4* acc, int t) {
  constexpr int KT = K / 32;
  constexpr int NCH = N / CW;
  constexpr int K8 = K / 8;
  constexpr int SI = (CW * K8) / NTH;
  constexpr int CT = CW / 16;
  const int l = t & 63, wv = t >> 6;

  u16x8 rh[SI], rl[SI];
#pragma unroll
  for (int s = 0; s < SI; ++s) {
    int u = t + s * NTH;
    int nn = u / K8, k8 = (u - nn * K8) * 8;
    rh[s] = *reinterpret_cast<const u16x8*>(Ghi + (size_t)nn * K + k8);
    rl[s] = *reinterpret_cast<const u16x8*>(Glo + (size_t)nn * K + k8);
  }

  bf16x8 ahi[KT], alo[KT];
  {
    const int row = wv * 16 + (l & 15);
    const float* ap = A + row * AS + (l >> 4) * 8;
#pragma unroll
    for (int kt = 0; kt < KT; ++kt) {
      float4 v0 = *reinterpret_cast<const float4*>(ap + kt * 32);
      float4 v1 = *reinterpret_cast<const float4*>(ap + kt * 32 + 4);
      float f[8] = {v0.x, v0.y, v0.z, v0.w, v1.x, v1.y, v1.z, v1.w};
      bf16x8 h, lo2;
#pragma unroll
      for (int j = 0; j < 8; ++j) {
        unsigned short hb = f2bh(f[j]);
        h[j] = (short)hb;
        lo2[j] = (short)f2bh(f[j] - bh2f(hb));
      }
      ahi[kt] = h; alo[kt] = lo2;
    }
  }
#pragma unroll
  for (int i = 0; i < N / 16; ++i) acc[i] = f32x4{0.f, 0.f, 0.f, 0.f};

#pragma unroll
  for (int c = 0; c < NCH; ++c) {
    __syncthreads();  // all waves done reading previous W contents
#pragma unroll
    for (int s = 0; s < SI; ++s) {
      int u = t + s * NTH;
      int nn = u / K8, k8 = (u - nn * K8) * 8;
      *reinterpret_cast<u16x8*>(Whi + nn * WS + k8) = rh[s];
      *reinterpret_cast<u16x8*>(Wlo + nn * WS + k8) = rl[s];
    }
    if (c + 1 < NCH) {
#pragma unroll
      for (int s = 0; s < SI; ++s) {
        int u = t + s * NTH;
        int nn = u / K8, k8 = (u - nn * K8) * 8;
        rh[s] = *reinterpret_cast<const u16x8*>(Ghi + (size_t)((c + 1) * CW + nn) * K + k8);
        rl[s] = *reinterpret_cast<const u16x8*>(Glo + (size_t)((c + 1) * CW + nn) * K + k8);
      }
    }
    __syncthreads();
#pragma unroll
    for (int ct = 0; ct < CT; ++ct) {
      const unsigned short* wp = Whi + (ct * 16 + (l & 15)) * WS + (l >> 4) * 8;
      const unsigned short* wq = Wlo + (ct * 16 + (l & 15)) * WS + (l >> 4) * 8;
      f32x4 a = acc[c * CT + ct];
#pragma unroll
      for (int kt = 0; kt < KT; ++kt) {
        bf16x8 wh = *reinterpret_cast<const bf16x8*>(wp + kt * 32);
        bf16x8 wl = *reinterpret_cast<const bf16x8*>(wq + kt * 32);
        a = __builtin_amdgcn_mfma_f32_16x16x32_bf16(ahi[kt], wh, a, 0, 0, 0);
        a = __builtin_amdgcn_mfma_f32_16x16x32_bf16(alo[kt], wh, a, 0, 0, 0);
        a = __builtin_amdgcn_mfma_f32_16x16x32_bf16(ahi[kt], wl, a, 0, 0, 0);
      }
      acc[c * CT + ct] = a;
    }
  }
  if constexpr (XYZC) {
    float xr[4][3];
#pragma unroll
    for (int r = 0; r < 4; ++r) {
      int row = wv * 16 + (l >> 4) * 4 + r;
      xr[r][0] = sxyz[row * 4 + 0];
      xr[r][1] = sxyz[row * 4 + 1];
      xr[r][2] = sxyz[row * 4 + 2];
    }
#pragma unroll
    for (int gt = 0; gt < N / 16; ++gt) {
      int col = gt * 16 + (l & 15);
      float w0 = Wxyz[col], w1 = Wxyz[N + col], w2 = Wxyz[2 * N + col];
#pragma unroll
      for (int r = 0; r < 4; ++r)
        acc[gt][r] += xr[r][0] * w0 + xr[r][1] * w1 + xr[r][2] * w2;
    }
  }
}

// ---------------------------------------------------------------- SA2 fused, 512 threads / 128 rows, 128-col chunks
template<int NPTS, int Q, int M, int GPB, int FD, int C1, int C2, int C3>
__global__ __launch_bounds__(512) void sa2_kernel(
    const float* __restrict__ pts, const float* __restrict__ centers,
    const int* __restrict__ gidx, const float* __restrict__ feats,
    const float* __restrict__ W0, const float* __restrict__ B0,
    const unsigned short* __restrict__ G0h, const unsigned short* __restrict__ G0l,
    const unsigned short* __restrict__ G1h, const unsigned short* __restrict__ G1l,
    const float* __restrict__ B1,
    const unsigned short* __restrict__ G2h, const unsigned short* __restrict__ G2l,
    const float* __restrict__ B2,
    float* __restrict__ fout) {
  constexpr int NTH = 512;
  constexpr int ROWS = M * GPB;                 // 128
  constexpr int NWV = NTH / 64;                 // 8
  static_assert(ROWS == 16 * NWV, "wave owns 16 rows");
  constexpr int MK1 = (FD > C1 ? FD : C1);
  constexpr int MAXK = (MK1 > C2 ? MK1 : C2);
  constexpr int AS = MAXK + 12;
  constexpr int WS = MAXK + 8;
  constexpr int CW = 128;
  __shared__ __align__(16) float A[ROWS * AS];
  __shared__ __align__(16) unsigned short Whi[CW * WS];
  __shared__ __align__(16) unsigned short Wlo[CW * WS];
  __shared__ float sxyz[ROWS * 4];
  __shared__ int idxs[ROWS];
  __shared__ float ctr[GPB][4];
  __shared__ float red[NWV][C3];

  const int t = threadIdx.x;
  const int blk = blockIdx.x;
  const int b = blk / (Q / GPB);
  const int q0 = (blk % (Q / GPB)) * GPB;
  const int l = t & 63, wv = t >> 6;

  if (t < GPB * 3) {
    int g = t / 3, c2 = t % 3;
    ctr[g][c2] = centers[((size_t)b * Q + q0 + g) * 3 + c2];
  }
  for (int m = t; m < ROWS; m += NTH)
    idxs[m] = gidx[((size_t)b * Q + q0 + (m / M)) * M + (m % M)];
  __syncthreads();
  const float* pb = pts + (size_t)b * NPTS * 3;
  for (int m = t; m < ROWS; m += NTH) {
    int g = m / M, i = idxs[m];
    sxyz[m * 4 + 0] = pb[i * 3 + 0] - ctr[g][0];
    sxyz[m * 4 + 1] = pb[i * 3 + 1] - ctr[g][1];
    sxyz[m * 4 + 2] = pb[i * 3 + 2] - ctr[g][2];
  }
  {  // FD=128 gather
    const int m = t >> 2, co = (t & 3) * (FD / 4);
    const float* src = feats + ((size_t)b * NPTS + idxs[m]) * FD + co;
    float* dst = A + m * AS + co;
#pragma unroll
    for (int j = 0; j < FD / 4; j += 4)
      *reinterpret_cast<float4*>(dst + j) = *reinterpret_cast<const float4*>(src + j);
  }
  __syncthreads();

  f32x4 acc[C3 / 16];

  do_layer<FD, C1, CW, AS, WS, true, NTH>(G0h, G0l, W0, A, Whi, Wlo, sxyz, acc, t);
#pragma unroll
  for (int gt = 0; gt < C1 / 16; ++gt) {
    int col = gt * 16 + (l & 15);
    float bia = B0[col];
#pragma unroll
    for (int r = 0; r < 4; ++r)
      A[(wv * 16 + (l >> 4) * 4 + r) * AS + col] = fmaxf(acc[gt][r] + bia, 0.f);
  }

  do_layer<C1, C2, CW, AS, WS, false, NTH>(G1h, G1l, nullptr, A, Whi, Wlo, sxyz, acc, t);
#pragma unroll
  for (int gt = 0; gt < C2 / 16; ++gt) {
    int col = gt * 16 + (l & 15);
    float bia = B1[col];
#pragma unroll
    for (int r = 0; r < 4; ++r)
      A[(wv * 16 + (l >> 4) * 4 + r) * AS + col] = fmaxf(acc[gt][r] + bia, 0.f);
  }

  do_layer<C2, C3, CW, AS, WS, false, NTH>(G2h, G2l, nullptr, A, Whi, Wlo, sxyz, acc, t);
#pragma unroll
  for (int gt = 0; gt < C3 / 16; ++gt) {
    int col = gt * 16 + (l & 15);
    float v = fmaxf(fmaxf(acc[gt][0], acc[gt][1]), fmaxf(acc[gt][2], acc[gt][3]));
    v = fmaxf(v, __shfl_xor(v, 16, 64));
    v = fmaxf(v, __shfl_xor(v, 32, 64));
    if (l < 16) red[wv][col] = v + B2[col];
  }
  __syncthreads();
  constexpr int WPG = NWV / GPB;
  for (int u = t; u < GPB * C3; u += NTH) {
    int g = u / C3, c2 = u - g * C3;
    float v = red[g * WPG][c2];
#pragma unroll
    for (int w = 1; w < WPG; ++w) v = fmaxf(v, red[g * WPG + w][c2]);
    fout[((size_t)b * Q + q0 + g) * C3 + c2] = fmaxf(v, 0.f);
  }
}

// ---------------------------------------------------------------- SA1 body, grid-strided: stage W once, process TPB tiles
template<int NPTS, int Q, int M, int GPB, int TPB>
DEVINL void sa1_body(const float* __restrict__ pts, const float* __restrict__ centers,
                     const int* __restrict__ gidx,
                     const float* __restrict__ W0, const float* __restrict__ B0,
                     const unsigned short* __restrict__ G1h, const unsigned short* __restrict__ G1l,
                     const float* __restrict__ B1,
                     const unsigned short* __restrict__ G2h, const unsigned short* __restrict__ G2l,
                     const float* __restrict__ B2,
                     float* __restrict__ fout, int sblk, int t) {
  static_assert(M * GPB == 64, "");
  constexpr int C1 = 64, C2 = 64, C3 = 128;
  constexpr int AS = 76;
  constexpr int WS = 72;
  constexpr int NC = C2 + C3;
  __shared__ __align__(16) float A[64 * AS];
  __shared__ __align__(16) unsigned short Wh[NC * WS];
  __shared__ __align__(16) unsigned short Wl[NC * WS];
  __shared__ float sxyz[64 * 4];
  __shared__ int idxs[64];
  __shared__ float ctr[GPB][4];
  __shared__ float red[4][C3];

  const int l = t & 63, wv = t >> 6;

  for (int u = t; u < NC * 8; u += 256) {
    int col = u >> 3, k8 = (u & 7) * 8;
    const unsigned short* sh = (col < C2) ? G1h + (size_t)col * 64 + k8
                                          : G2h + (size_t)(col - C2) * 64 + k8;
    const unsigned short* sl = (col < C2) ? G1l + (size_t)col * 64 + k8
                                          : G2l + (size_t)(col - C2) * 64 + k8;
    *reinterpret_cast<u16x8*>(Wh + col * WS + k8) = *reinterpret_cast<const u16x8*>(sh);
    *reinterpret_cast<u16x8*>(Wl + col * WS + k8) = *reinterpret_cast<const u16x8*>(sl);
  }

  for (int it = 0; it < TPB; ++it) {
    const int blk = sblk * TPB + it;
    const int b = blk / (Q / GPB);
    const int q0 = (blk % (Q / GPB)) * GPB;

    if (t < GPB * 3) {
      int g = t / 3, c2 = t % 3;
      ctr[g][c2] = centers[((size_t)b * Q + q0 + g) * 3 + c2];
    }
    for (int m = t; m < 64; m += 256)
      idxs[m] = gidx[((size_t)b * Q + q0 + (m / M)) * M + (m % M)];
    __syncthreads();
    const float* pb = pts + (size_t)b * NPTS * 3;
    for (int m = t; m < 64; m += 256) {
      int g = m / M, i = idxs[m];
      sxyz[m * 4 + 0] = pb[i * 3 + 0] - ctr[g][0];
      sxyz[m * 4 + 1] = pb[i * 3 + 1] - ctr[g][1];
      sxyz[m * 4 + 2] = pb[i * 3 + 2] - ctr[g][2];
    }
    __syncthreads();

    for (int u = t; u < 64 * C1; u += 256) {
      int m = u / C1, c2 = u - m * C1;
      float v = B0[c2] + sxyz[m * 4 + 0] * W0[0 * C1 + c2]
                       + sxyz[m * 4 + 1] * W0[1 * C1 + c2]
                       + sxyz[m * 4 + 2] * W0[2 * C1 + c2];
      A[m * AS + c2] = fmaxf(v, 0.f);
    }
    __syncthreads();

    f32x4 acc[8];
    // ---- L2: 64 -> 64, W cols [0,64), barrier-free
    {
      bf16x8 ah[2], al[2];
      const float* ap = A + (wv * 16 + (l & 15)) * AS + (l >> 4) * 8;
#pragma unroll
      for (int kt = 0; kt < 2; ++kt) {
        float4 v0 = *reinterpret_cast<const float4*>(ap + kt * 32);
        float4 v1 = *reinterpret_cast<const float4*>(ap + kt * 32 + 4);
        float f[8] = {v0.x, v0.y, v0.z, v0.w, v1.x, v1.y, v1.z, v1.w};
        bf16x8 h, lo2;
#pragma unroll
        for (int j = 0; j < 8; ++j) {
          unsigned short hb = f2bh(f[j]);
          h[j] = (short)hb;
          lo2[j] = (short)f2bh(f[j] - bh2f(hb));
        }
        ah[kt] = h; al[kt] = lo2;
      }
#pragma unroll
      for (int i = 0; i < 4; ++i) acc[i] = f32x4{0.f, 0.f, 0.f, 0.f};
#pragma unroll
      for (int ct = 0; ct < 4; ++ct) {
        const unsigned short* wp = Wh + (ct * 16 + (l & 15)) * WS + (l >> 4) * 8;
        const unsigned short* wq = Wl + (ct * 16 + (l & 15)) * WS + (l >> 4) * 8;
        f32x4 a = acc[ct];
#pragma unroll
        for (int kt = 0; kt < 2; ++kt) {
          bf16x8 wh = *reinterpret_cast<const bf16x8*>(wp + kt * 32);
          bf16x8 wl = *reinterpret_cast<const bf16x8*>(wq + kt * 32);
          a = __builtin_amdgcn_mfma_f32_16x16x32_bf16(ah[kt], wh, a, 0, 0, 0);
          a = __builtin_amdgcn_mfma_f32_16x16x32_bf16(al[kt], wh, a, 0, 0, 0);
          a = __builtin_amdgcn_mfma_f32_16x16x32_bf16(ah[kt], wl, a, 0, 0, 0);
        }
        acc[ct] = a;
      }
#pragma unroll
      for (int gt = 0; gt < 4; ++gt) {
        int col = gt * 16 + (l & 15);
        float bia = B1[col];
#pragma unroll
        for (int r = 0; r < 4; ++r)
          A[(wv * 16 + (l >> 4) * 4 + r) * AS + col] = fmaxf(acc[gt][r] + bia, 0.f);
      }
    }

    // ---- L3: 64 -> 128, W cols [64,192), maxpool epilogue
    {
      bf16x8 ah[2], al[2];
      const float* ap = A + (wv * 16 + (l & 15)) * AS + (l >> 4) * 8;
#pragma unroll
      for (int kt = 0; kt < 2; ++kt) {
        float4 v0 = *reinterpret_cast<const float4*>(ap + kt * 32);
        float4 v1 = *reinterpret_cast<const float4*>(ap + kt * 32 + 4);
        float f[8] = {v0.x, v0.y, v0.z, v0.w, v1.x, v1.y, v1.z, v1.w};
        bf16x8 h, lo2;
#pragma unroll
        for (int j = 0; j < 8; ++j) {
          unsigned short hb = f2bh(f[j]);
          h[j] = (short)hb;
          lo2[j] = (short)f2bh(f[j] - bh2f(hb));
        }
        ah[kt] = h; al[kt] = lo2;
      }
#pragma unroll
      for (int i = 0; i < 8; ++i) acc[i] = f32x4{0.f, 0.f, 0.f, 0.f};
#pragma unroll
      for (int gt = 0; gt < 8; ++gt) {
        const unsigned short* wp = Wh + (C2 + gt * 16 + (l & 15)) * WS + (l >> 4) * 8;
        const unsigned short* wq = Wl + (C2 + gt * 16 + (l & 15)) * WS + (l >> 4) * 8;
        f32x4 a = acc[gt];
#pragma unroll
        for (int kt = 0; kt < 2; ++kt) {
          bf16x8 wh = *reinterpret_cast<const bf16x8*>(wp + kt * 32);
          bf16x8 wl = *reinterpret_cast<const bf16x8*>(wq + kt * 32);
          a = __builtin_amdgcn_mfma_f32_16x16x32_bf16(ah[kt], wh, a, 0, 0, 0);
          a = __builtin_amdgcn_mfma_f32_16x16x32_bf16(al[kt], wh, a, 0, 0, 0);
          a = __builtin_amdgcn_mfma_f32_16x16x32_bf16(ah[kt], wl, a, 0, 0, 0);
        }
        acc[gt] = a;
      }
#pragma unroll
      for (int gt = 0; gt < 8; ++gt) {
        int col = gt * 16 + (l & 15);
        float v = fmaxf(fmaxf(acc[gt][0], acc[gt][1]), fmaxf(acc[gt][2], acc[gt][3]));
        v = fmaxf(v, __shfl_xor(v, 16, 64));
        v = fmaxf(v, __shfl_xor(v, 32, 64));
        if (l < 16) red[wv][col] = v + B2[col];
      }
    }
    __syncthreads();
    constexpr int WPG = 4 / GPB;
    for (int u = t; u < GPB * C3; u += 256) {
      int g = u / C3, c2 = u - g * C3;
      float v = red[g * WPG][c2];
#pragma unroll
      for (int w = 1; w < WPG; ++w) v = fmaxf(v, red[g * WPG + w][c2]);
      fout[((size_t)b * Q + q0 + g) * C3 + c2] = fmaxf(v, 0.f);
    }
    __syncthreads();
  }
}

// [bq2 || sa1]
__global__ __launch_bounds__(256) void bq2_sa1_kernel(
    const float* __restrict__ xyz, const float* __restrict__ nx1,
    const float* __restrict__ nx2, int* __restrict__ gidx2, float r22,
    const int* __restrict__ gidx1,
    const float* __restrict__ s1w0, const float* __restrict__ s1b0,
    const unsigned short* __restrict__ g11h, const unsigned short* __restrict__ g11l,
    const float* __restrict__ s1b1,
    const unsigned short* __restrict__ g12h, const unsigned short* __restrict__ g12l,
    const float* __restrict__ s1b2, float* __restrict__ f1) {
  if (blockIdx.x < 1024) {
    bq_body<512, 64>(nx1, nx2, gidx2, 128, r22, blockIdx.x, threadIdx.x);
    return;
  }
  sa1_body<4096, 512, 32, 2, 8>(xyz, nx1, gidx1, s1w0, s1b0, g11h, g11l, s1b1,
                                g12h, g12l, s1b2, f1, blockIdx.x - 1024, threadIdx.x);
}

// ---------------------------------------------------------------- SA3 fused
constexpr int AS3 = 532;
DEVINL void sa3_frags(const float* __restrict__ A, int l, int KT, bf16x8* ahi, bf16x8* alo) {
  const float* ap = A + (l & 15) * AS3 + (l >> 4) * 8;
  for (int kt = 0; kt < KT; ++kt) {
    float4 v0 = *reinterpret_cast<const float4*>(ap + kt * 32);
    float4 v1 = *reinterpret_cast<const float4*>(ap + kt * 32 + 4);
    float f[8] = {v0.x, v0.y, v0.z, v0.w, v1.x, v1.y, v1.z, v1.w};
    bf16x8 h, lo2;
#pragma unroll
    for (int j = 0; j < 8; ++j) {
      unsigned short hb = f2bh(f[j]);
      h[j] = (short)hb;
      lo2[j] = (short)f2bh(f[j] - bh2f(hb));
    }
    ahi[kt] = h; alo[kt] = lo2;
  }
}

template<int K>
DEVINL void sa3_mm64(const unsigned short* __restrict__ Gh, const unsigned short* __restrict__ Gl,
                     int ncol0, int l, const bf16x8* ahi, const bf16x8* alo, f32x4* acc4) {
  constexpr int KT = K / 32;
#pragma unroll
  for (int ct = 0; ct < 4; ++ct) {
    const unsigned short* hp = Gh + (size_t)(ncol0 + ct * 16 + (l & 15)) * K + (l >> 4) * 8;
    const unsigned short* lp = Gl + (size_t)(ncol0 + ct * 16 + (l & 15)) * K + (l >> 4) * 8;
    f32x4 a = acc4[ct];
#pragma unroll
    for (int kt = 0; kt < KT; ++kt) {
      bf16x8 wh = *reinterpret_cast<const bf16x8*>(hp + kt * 32);
      bf16x8 wl = *reinterpret_cast<const bf16x8*>(lp + kt * 32);
      a = __builtin_amdgcn_mfma_f32_16x16x32_bf16(ahi[kt], wh, a, 0, 0, 0);
      a = __builtin_amdgcn_mfma_f32_16x16x32_bf16(alo[kt], wh, a, 0, 0, 0);
      a = __builtin_amdgcn_mfma_f32_16x16x32_bf16(ahi[kt], wl, a, 0, 0, 0);
    }
    acc4[ct] = a;
  }
}

__global__ __launch_bounds__(256) void sa3f_kernel(
    const float* __restrict__ nx2, const float* __restrict__ f2,
    const float* __restrict__ W0full,
    const unsigned short* __restrict__ G0h, const unsigned short* __restrict__ G0l,
    const float* __restrict__ B0,
    const unsigned short* __restrict__ G1h, const unsigned short* __restrict__ G1l,
    const float* __restrict__ B1,
    const unsigned short* __restrict__ G2h, const unsigned short* __restrict__ G2l,
    const float* __restrict__ B2,
    float* __restrict__ partial) {
  __shared__ __align__(16) float A[16 * AS3];
  __shared__ float sxyz[16][4];
  const int t = threadIdx.x, l = t & 63, w = t >> 6;
  const int b = blockIdx.x >> 3, rb = blockIdx.x & 7;
  const int row0 = rb * 16;
  {
    int r = t >> 4, cc = (t & 15) * 16;
    const float* src = f2 + ((size_t)b * 128 + row0 + r) * 256 + cc;
    float* dstp = A + r * AS3 + cc;
#pragma unroll
    for (int j = 0; j < 16; j += 4)
      *reinterpret_cast<float4*>(dstp + j) = *reinterpret_cast<const float4*>(src + j);
    if (t < 16) {
      const float* s = nx2 + ((size_t)b * 128 + row0 + t) * 3;
      sxyz[t][0] = s[0]; sxyz[t][1] = s[1]; sxyz[t][2] = s[2];
    }
  }
  __syncthreads();

  {  // L1: K=256 MFMA + xyz f32 correction -> N=256 (wave cols 64)
    bf16x8 ah[8], al[8];
    sa3_frags(A, l, 8, ah, al);
    __syncthreads();
    f32x4 acc[4];
#pragma unroll
    for (int i = 0; i < 4; ++i) acc[i] = f32x4{0.f, 0.f, 0.f, 0.f};
    sa3_mm64<256>(G0h, G0l, w * 64, l, ah, al, acc);
    float xr[4][3];
#pragma unroll
    for (int r = 0; r < 4; ++r) {
      int row = (l >> 4) * 4 + r;
      xr[r][0] = sxyz[row][0]; xr[r][1] = sxyz[row][1]; xr[r][2] = sxyz[row][2];
    }
#pragma unroll
    for (int ct = 0; ct < 4; ++ct) {
      int col = w * 64 + ct * 16 + (l & 15);
      float w0 = W0full[col], w1 = W0full[256 + col], w2 = W0full[512 + col];
      float bia = B0[col];
#pragma unroll
      for (int r = 0; r < 4; ++r) {
        int row = (l >> 4) * 4 + r;
        float v = acc[ct][r] + xr[r][0] * w0 + xr[r][1] * w1 + xr[r][2] * w2 + bia;
        A[row * AS3 + col] = fmaxf(v, 0.f);
      }
    }
    __syncthreads();
  }

  {  // L2: K=256 -> N=512 (wave cols 128)
    bf16x8 ah[8], al[8];
    sa3_frags(A, l, 8, ah, al);
    __syncthreads();
    f32x4 acc[8];
#pragma unroll
    for (int i = 0; i < 8; ++i) acc[i] = f32x4{0.f, 0.f, 0.f, 0.f};
    sa3_mm64<256>(G1h, G1l, w * 128, l, ah, al, acc);
    sa3_mm64<256>(G1h, G1l, w * 128 + 64, l, ah, al, acc + 4);
#pragma unroll
    for (int cc = 0; cc < 8; ++cc) {
      int col = w * 128 + cc * 16 + (l & 15);
      float bia = B1[col];
#pragma unroll
      for (int r = 0; r < 4; ++r) {
        int row = (l >> 4) * 4 + r;
        A[row * AS3 + col] = fmaxf(acc[cc][r] + bia, 0.f);
      }
    }
    __syncthreads();
  }

  {  // L3: K=512 -> N=1024 (wave cols 256), maxpool 16 rows -> partial
    bf16x8 ah[16], al[16];
    sa3_frags(A, l, 16, ah, al);
    float* pout = partial + ((size_t)(b * 8 + rb)) * 1024;
#pragma unroll
    for (int sub = 0; sub < 4; ++sub) {
      f32x4 acc[4];
#pragma unroll
      for (int i = 0; i < 4; ++i) acc[i] = f32x4{0.f, 0.f, 0.f, 0.f};
      sa3_mm64<512>(G2h, G2l, w * 256 + sub * 64, l, ah, al, acc);
#pragma unroll
      for (int ct = 0; ct < 4; ++ct) {
        int col = w * 256 + sub * 64 + ct * 16 + (l & 15);
        float v = fmaxf(fmaxf(acc[ct][0], acc[ct][1]), fmaxf(acc[ct][2], acc[ct][3]));
        v = fmaxf(v, __shfl_xor(v, 16, 64));
        v = fmaxf(v, __shfl_xor(v, 32, 64));
        if (l < 16) pout[col] = v + B2[col];  // relu deferred to heads (monotone)
      }
    }
  }
}

// ---------------------------------------------------------------- heads (8-way partial max + relu + dots)
__global__ __launch_bounds__(256) void heads_kernel(const float* __restrict__ partial,
                                                    const float* __restrict__ cw,
                                                    const float* __restrict__ cb,
                                                    const float* __restrict__ rw,
                                                    const float* __restrict__ rb,
                                                    float* __restrict__ out) {
  const int b = blockIdx.x, t = threadIdx.x;
  const float* pb = partial + (size_t)b * 8 * 1024;
  float a0 = 0, a1 = 0, a2 = 0, a3 = 0, a4 = 0;
  for (int k = t; k < 1024; k += 256) {
    float m = pb[k];
#pragma unroll
    for (int p = 1; p < 8; ++p) m = fmaxf(m, pb[p * 1024 + k]);
    float f = fmaxf(m, 0.f);
    a0 += f * cw[k];
    const float* r = rw + (size_t)k * 4;
    a1 += f * r[0]; a2 += f * r[1]; a3 += f * r[2]; a4 += f * r[3];
  }
#pragma unroll
  for (int m = 32; m >= 1; m >>= 1) {
    a0 += __shfl_xor(a0, m, 64); a1 += __shfl_xor(a1, m, 64);
    a2 += __shfl_xor(a2, m, 64); a3 += __shfl_xor(a3, m, 64);
    a4 += __shfl_xor(a4, m, 64);
  }
  __shared__ float red[4][5];
  const int wv = t >> 6, ln = t & 63;
  if (ln == 0) { red[wv][0] = a0; red[wv][1] = a1; red[wv][2] = a2; red[wv][3] = a3; red[wv][4] = a4; }
  __syncthreads();
  if (t == 0) {
    float s0 = red[0][0] + red[1][0] + red[2][0] + red[3][0];
    float s1 = red[0][1] + red[1][1] + red[2][1] + red[3][1];
    float s2 = red[0][2] + red[1][2] + red[2][2] + red[3][2];
    float s3 = red[0][3] + red[1][3] + red[2][3] + red[3][3];
    float s4 = red[0][4] + red[1][4] + red[2][4] + red[3][4];
    out[b] = s0 + cb[0];
    out[32 + b * 4 + 0] = s1 + rb[0];
    out[32 + b * 4 + 1] = s2 + rb[1];
    out[32 + b * 4 + 2] = s3 + rb[2];
    out[32 + b * 4 + 3] = s4 + rb[3];
  }
}

// ---------------------------------------------------------------- launch
extern "C" void kernel_launch(void* const* d_in, const int* in_sizes, int n_in,
                              void* d_out, int out_size, void* d_ws, size_t ws_size,
                              hipStream_t stream) {
  (void)in_sizes; (void)n_in; (void)out_size; (void)ws_size;
  const float* xyz  = (const float*)d_in[0];
  const float* s1w0 = (const float*)d_in[1];  const float* s1b0 = (const float*)d_in[2];
  const float* s1w1 = (const float*)d_in[3];  const float* s1b1 = (const float*)d_in[4];
  const float* s1w2 = (const float*)d_in[5];  const float* s1b2 = (const float*)d_in[6];
  const float* s2w0 = (const float*)d_in[7];  const float* s2b0 = (const float*)d_in[8];
  const float* s2w1 = (const float*)d_in[9];  const float* s2b1 = (const float*)d_in[10];
  const float* s2w2 = (const float*)d_in[11]; const float* s2b2 = (const float*)d_in[12];
  const float* s3w0 = (const float*)d_in[13]; const float* s3b0 = (const float*)d_in[14];
  const float* s3w1 = (const float*)d_in[15]; const float* s3b1 = (const float*)d_in[16];
  const float* s3w2 = (const float*)d_in[17]; const float* s3b2 = (const float*)d_in[18];
  const float* clsw = (const float*)d_in[19]; const float* clsb = (const float*)d_in[20];
  const float* regw = (const float*)d_in[21]; const float* regb = (const float*)d_in[22];

  char* ws = (char*)d_ws;
  float* nx1   = (float*)(ws + 0);          // 32*512*3
  int*   gidx1 = (int*)  (ws + 196608);     // 32*512*32
  float* f1    = (float*)(ws + 2293760);    // 32*512*128
  float* nx2   = (float*)(ws + 10682368);   // 32*128*3
  int*   gidx2 = (int*)  (ws + 10731520);   // 32*128*64
  float* f2    = (float*)(ws + 11780096);   // 32*128*256

  // SA1/SA2 prepped weights (u16 hi/lo, transposed [n][k])
  unsigned short* wt = (unsigned short*)(ws + 20168704);
  unsigned short* g11h = wt;            // 64*64
  unsigned short* g11l = wt + 4096;
  unsigned short* g12h = wt + 8192;     // 128*64
  unsigned short* g12l = wt + 16384;
  unsigned short* g20h = wt + 24576;    // 128*128 (rows 3..130 of s2w0)
  unsigned short* g20l = wt + 40960;
  unsigned short* g21h = wt + 57344;    // 128*128
  unsigned short* g21l = wt + 73728;
  unsigned short* g22h = wt + 90112;    // 256*128
  unsigned short* g22l = wt + 122880;   // ends at byte 20168704+311296 = 20480000
  // SA3 prepped weights
  unsigned short* g30h = (unsigned short*)(ws + 20480000);  // 256x256
  unsigned short* g30l = (unsigned short*)(ws + 20611072);
  unsigned short* g31h = (unsigned short*)(ws + 20742144);  // 512x256
  unsigned short* g31l = (unsigned short*)(ws + 21004288);
  unsigned short* g32h = (unsigned short*)(ws + 21266432);  // 1024x512
  unsigned short* g32l = (unsigned short*)(ws + 22315008);
  float* partial = (float*)(ws + 23363584);                 // 32*8*1024 f32 -> ends 24412160

  const float r21 = (float)(0.2 * 0.2);
  const float r22 = (float)(0.4 * 0.4);

  WPTab tab;
  int off = 0;
  auto set = [&](int i, const float* W, unsigned short* hi, unsigned short* lo,
                 int K, int N, int row0) {
    tab.e[i] = WPEnt{W, hi, lo, K, N, row0, off, off + K * N};
    off += K * N;
  };
  set(0, s1w1, g11h, g11l, 64, 64, 0);
  set(1, s1w2, g12h, g12l, 64, 128, 0);
  set(2, s2w0, g20h, g20l, 128, 128, 3);
  set(3, s2w1, g21h, g21l, 128, 128, 0);
  set(4, s2w2, g22h, g22l, 128, 256, 0);
  set(5, s3w0, g30h, g30l, 256, 256, 3);
  set(6, s3w1, g31h, g31l, 256, 512, 0);
  set(7, s3w2, g32h, g32l, 512, 1024, 0);
  const int wblocks = (off + 255) / 256;

  fps1_wprep_kernel<<<32 + wblocks, 256, 0, stream>>>(xyz, nx1, tab);
  fps2_bq1_kernel<<<32 + 4096, 256, 0, stream>>>(xyz, nx1, gidx1, nx2, r21);
  bq2_sa1_kernel<<<1024 + 1024, 256, 0, stream>>>(
      xyz, nx1, nx2, gidx2, r22, gidx1,
      s1w0, s1b0, g11h, g11l, s1b1, g12h, g12l, s1b2, f1);
  sa2_kernel<512, 128, 64, 2, 128, 128, 128, 256><<<2048, 512, 0, stream>>>(
      nx1, nx2, gidx2, f1, s2w0, s2b0,
      g20h, g20l, g21h, g21l, s2b1, g22h, g22l, s2b2, f2);
  sa3f_kernel<<<256, 256, 0, stream>>>(nx2, f2, s3w0, g30h, g30l, s3b0,
                                       g31h, g31l, s3b1, g32h, g32l, s3b2, partial);
  heads_kernel<<<32, 256, 0, stream>>>(partial, clsw, clsb, regw, regb, (float*)d_out);
}

// Round 15
// 659.553 us; speedup vs baseline: 1.1090x; 1.0724x over previous
//
#include <hip/hip_runtime.h>

#define DEVINL __device__ __forceinline__

typedef __attribute__((ext_vector_type(8))) short bf16x8;
typedef __attribute__((ext_vector_type(8))) unsigned short u16x8;
typedef __attribute__((ext_vector_type(4))) float f32x4;

// RNE f32 -> bf16 bits (no NaN handling needed for this workload)
DEVINL unsigned short f2bh(float f){
  unsigned u = __float_as_uint(f);
  return (unsigned short)((u + 0x7FFFu + ((u >> 16) & 1u)) >> 16);
}
DEVINL float bh2f(unsigned short h){ return __uint_as_float(((unsigned)h) << 16); }

// Wave64 max-reduce of a u64 key via DPP (VALU latency, no DS pipe).
DEVINL unsigned long long dpp_max_u64(unsigned long long k) {
#define DPP_STEP(ctrl)                                                        \
  {                                                                           \
    int hi = (int)(k >> 32), lo = (int)(unsigned)k;                           \
    int oh = __builtin_amdgcn_update_dpp(0, hi, ctrl, 0xF, 0xF, 1);           \
    int ol = __builtin_amdgcn_update_dpp(0, lo, ctrl, 0xF, 0xF, 1);           \
    unsigned long long ok =                                                   \
        ((unsigned long long)(unsigned)oh << 32) | (unsigned)ol;              \
    if (ok > k) k = ok;                                                       \
  }
  DPP_STEP(0x111)  // row_shr:1
  DPP_STEP(0x112)  // row_shr:2
  DPP_STEP(0x114)  // row_shr:4
  DPP_STEP(0x118)  // row_shr:8
  DPP_STEP(0x142)  // row_bcast:15
  DPP_STEP(0x143)  // row_bcast:31
#undef DPP_STEP
  return k;
}

// ---------------------------------------------------------------- FPS body (R4-proven, LOCKED)
template<int N, int NP, int NT>
DEVINL void fps_body(const float* __restrict__ xyz, float* __restrict__ nxyz,
                     int b, int t) {
  constexpr int PTS = N / NT;
  constexpr int NW = NT / 64;
  __shared__ float xs[N], ys[N], zs[N];
  __shared__ int farr[NP];
  __shared__ unsigned long long sk[2][(NW > 1 ? NW : 1)];
  float px[PTS], py[PTS], pz[PTS], dst[PTS];
  const float* base = xyz + (size_t)b * N * 3;
#pragma unroll
  for (int j = 0; j < PTS; ++j) {
    int i = t + j * NT;
    float x = base[i * 3 + 0], y = base[i * 3 + 1], z = base[i * 3 + 2];
    px[j] = x; py[j] = y; pz[j] = z;
    xs[i] = x; ys[i] = y; zs[i] = z;
    dst[j] = 1e10f;
  }
  if constexpr (NW > 1) __syncthreads();
  int far = 0;
  const int wv = t >> 6, ln = t & 63;
  for (int s = 0; s < NP; ++s) {
    float cx = xs[far], cy = ys[far], cz = zs[far];
    if (t == 0) farr[s] = far;
    float bv = -1.f; int bi = 0;
#pragma unroll
    for (int j = 0; j < PTS; ++j) {
      // no-fma, left-to-right: matches numpy elementwise + sum order
      float dx = __fsub_rn(px[j], cx), dy = __fsub_rn(py[j], cy), dz = __fsub_rn(pz[j], cz);
      float d = __fadd_rn(__fadd_rn(__fmul_rn(dx, dx), __fmul_rn(dy, dy)), __fmul_rn(dz, dz));
      float nd = fminf(dst[j], d);
      dst[j] = nd;
      int i = t + j * NT;
      if (nd > bv) { bv = nd; bi = i; }  // strict >: first max kept per thread
    }
    // pack: max key == max dist, tie -> larger ~idx == smaller idx
    unsigned long long key =
        ((unsigned long long)__float_as_uint(bv) << 32) | (unsigned)(~bi);
    key = dpp_max_u64(key);
    if constexpr (NW == 1) {
      int rl = __builtin_amdgcn_readlane((int)(unsigned)key, 63);
      far = (int)(~(unsigned)rl);
    } else {
      const int p = s & 1;
      if (ln == 63) sk[p][wv] = key;
      __syncthreads();
      unsigned long long m = sk[p][0];
#pragma unroll
      for (int q = 1; q < NW; ++q) {
        unsigned long long qk = sk[p][q];
        if (qk > m) m = qk;
      }
      far = (int)(~(unsigned)m);
    }
  }
  if constexpr (NW > 1) __syncthreads();
  for (int s2 = t; s2 < NP; s2 += NT) {
    int fi = farr[s2];
    float* o = nxyz + ((size_t)b * NP + s2) * 3;
    o[0] = xs[fi]; o[1] = ys[fi]; o[2] = zs[fi];
  }
}

// ---------------------------------------------------------------- ball query body
// Software-pipelined: chunk c+1's loads issue before chunk c's ballot/break
// (speculative, bounds-guarded, side-effect-free). Break moved to loop
// bottom: processed-chunk set identical to the check-at-top original.
template<int N, int NS>
DEVINL void bq_body(const float* __restrict__ pts, const float* __restrict__ centers,
                    int* __restrict__ gidx, int Q, float r2, int blk, int t) {
  const int wv = t >> 6, ln = t & 63;
  const int g = blk * 4 + wv;
  const int b = g / Q, q = g % Q;
  const float* pb = pts + (size_t)b * N * 3;
  const float* c = centers + ((size_t)b * Q + q) * 3;
  const float cx = c[0], cy = c[1], cz = c[2];
  __shared__ int gbuf[4][NS];
  float nx = pb[ln * 3 + 0], ny = pb[ln * 3 + 1], nz = pb[ln * 3 + 2];
  int taken = 0;
  for (int base = 0; base < N; base += 64) {
    const float x = nx, y = ny, z = nz;
    if (base + 64 < N) {
      const float* np = pb + (size_t)(base + 64 + ln) * 3;
      nx = np[0]; ny = np[1]; nz = np[2];
    }
    int i = base + ln;
    float dx = __fsub_rn(x, cx), dy = __fsub_rn(y, cy), dz = __fsub_rn(z, cz);
    float d = __fadd_rn(__fadd_rn(__fmul_rn(dx, dx), __fmul_rn(dy, dy)), __fmul_rn(dz, dz));
    bool in = (d <= r2);
    unsigned long long mk = __ballot(in);
    int rank = __popcll(mk & ((1ull << ln) - 1ull));
    int pos = taken + rank;
    if (in && pos < NS) gbuf[wv][pos] = i;
    taken += (int)__popcll(mk);
    if (taken >= NS) break;
  }
  int total = taken < NS ? taken : NS;
  int first = gbuf[wv][0];
  int* out = gidx + ((size_t)b * Q + q) * NS;
  for (int j = ln; j < NS; j += 64) out[j] = (j < total) ? gbuf[wv][j] : first;
}

// ---------------------------------------------------------------- weight prep body
struct WPEnt { const float* W; unsigned short* hi; unsigned short* lo; int K, N, row0, beg, end; };
struct WPTab { WPEnt e[8]; };
DEVINL void wprep_body(const WPTab& tab, int idx) {
#pragma unroll
  for (int i = 0; i < 8; ++i) {
    const WPEnt& E = tab.e[i];
    if (idx >= E.beg && idx < E.end) {
      int local = idx - E.beg;
      int k = local / E.N, n = local - k * E.N;
      float v = E.W[(size_t)(E.row0 + k) * E.N + n];
      unsigned short h = f2bh(v);
      E.hi[(size_t)n * E.K + k] = h;
      E.lo[(size_t)n * E.K + k] = f2bh(v - bh2f(h));
    }
  }
}

// ---------------------------------------------------------------- fused launches
// [fps1 || wprep]
__global__ __launch_bounds__(256) void fps1_wprep_kernel(const float* __restrict__ xyz,
                                                         float* __restrict__ nx1, WPTab tab) {
  if (blockIdx.x < 32) { fps_body<4096, 512, 256>(xyz, nx1, blockIdx.x, threadIdx.x); return; }
  wprep_body(tab, (blockIdx.x - 32) * 256 + threadIdx.x);
}

// [fps2 || bq1]: fps2 as single wave (barrier-free); waves 1-3 retire.
__global__ __launch_bounds__(256) void fps2_bq1_kernel(const float* __restrict__ xyz,
                                                       const float* __restrict__ nx1,
                                                       int* __restrict__ gidx1,
                                                       float* __restrict__ nx2, float r21) {
  if (blockIdx.x < 32) {
    if (threadIdx.x < 64) fps_body<512, 128, 64>(nx1, nx2, blockIdx.x, threadIdx.x);
    return;
  }
  bq_body<4096, 32>(xyz, nx1, gidx1, 512, r21, blockIdx.x - 32, threadIdx.x);
}

// ---------------------------------------------------------------- split-bf16 MFMA layer (CW-col chunks)
template<int K, int N, int CW, int AS, int WS, bool XYZC, int NTH>
DEVINL void do_layer(const unsigned short* __restrict__ Ghi, const unsigned short* __restrict__ Glo,
                     const float* __restrict__ Wxyz,
                     const float* __restrict__ A, unsigned short* __restrict__ Whi,
                     unsigned short* __restrict__ Wlo, const float* __restrict__ sxyz,
                     f32x4* acc, int t) {
  constexpr int KT = K / 32;
  constexpr int NCH = N / CW;
  constexpr int K8 = K / 8;
  constexpr int SI = (CW * K8) / NTH;
  constexpr int CT = CW / 16;
  const int l = t & 63, wv = t >> 6;

  u16x8 rh[SI], rl[SI];
#pragma unroll
  for (int s = 0; s < SI; ++s) {
    int u = t + s * NTH;
    int nn = u / K8, k8 = (u - nn * K8) * 8;
    rh[s] = *reinterpret_cast<const u16x8*>(Ghi + (size_t)nn * K + k8);
    rl[s] = *reinterpret_cast<const u16x8*>(Glo + (size_t)nn * K + k8);
  }

  bf16x8 ahi[KT], alo[KT];
  {
    const int row = wv * 16 + (l & 15);
    const float* ap = A + row * AS + (l >> 4) * 8;
#pragma unroll
    for (int kt = 0; kt < KT; ++kt) {
      float4 v0 = *reinterpret_cast<const float4*>(ap + kt * 32);
      float4 v1 = *reinterpret_cast<const float4*>(ap + kt * 32 + 4);
      float f[8] = {v0.x, v0.y, v0.z, v0.w, v1.x, v1.y, v1.z, v1.w};
      bf16x8 h, lo2;
#pragma unroll
      for (int j = 0; j < 8; ++j) {
        unsigned short hb = f2bh(f[j]);
        h[j] = (short)hb;
        lo2[j] = (short)f2bh(f[j] - bh2f(hb));
      }
      ahi[kt] = h; alo[kt] = lo2;
    }
  }
#pragma unroll
  for (int i = 0; i < N / 16; ++i) acc[i] = f32x4{0.f, 0.f, 0.f, 0.f};

#pragma unroll
  for (int c = 0; c < NCH; ++c) {
    __syncthreads();  // all waves done reading previous W contents
#pragma unroll
    for (int s = 0; s < SI; ++s) {
      int u = t + s * NTH;
      int nn = u / K8, k8 = (u - nn * K8) * 8;
      *reinterpret_cast<u16x8*>(Whi + nn * WS + k8) = rh[s];
      *reinterpret_cast<u16x8*>(Wlo + nn * WS + k8) = rl[s];
    }
    if (c + 1 < NCH) {
#pragma unroll
      for (int s = 0; s < SI; ++s) {
        int u = t + s * NTH;
        int nn = u / K8, k8 = (u - nn * K8) * 8;
        rh[s] = *reinterpret_cast<const u16x8*>(Ghi + (size_t)((c + 1) * CW + nn) * K + k8);
        rl[s] = *reinterpret_cast<const u16x8*>(Glo + (size_t)((c + 1) * CW + nn) * K + k8);
      }
    }
    __syncthreads();
#pragma unroll
    for (int ct = 0; ct < CT; ++ct) {
      const unsigned short* wp = Whi + (ct * 16 + (l & 15)) * WS + (l >> 4) * 8;
      const unsigned short* wq = Wlo + (ct * 16 + (l & 15)) * WS + (l >> 4) * 8;
      f32x4 a = acc[c * CT + ct];
#pragma unroll
      for (int kt = 0; kt < KT; ++kt) {
        bf16x8 wh = *reinterpret_cast<const bf16x8*>(wp + kt * 32);
        bf16x8 wl = *reinterpret_cast<const bf16x8*>(wq + kt * 32);
        a = __builtin_amdgcn_mfma_f32_16x16x32_bf16(ahi[kt], wh, a, 0, 0, 0);
        a = __builtin_amdgcn_mfma_f32_16x16x32_bf16(alo[kt], wh, a, 0, 0, 0);
        a = __builtin_amdgcn_mfma_f32_16x16x32_bf16(ahi[kt], wl, a, 0, 0, 0);
      }
      acc[c * CT + ct] = a;
    }
  }
  if constexpr (XYZC) {
    float xr[4][3];
#pragma unroll
    for (int r = 0; r < 4; ++r) {
      int row = wv * 16 + (l >> 4) * 4 + r;
      xr[r][0] = sxyz[row * 4 + 0];
      xr[r][1] = sxyz[row * 4 + 1];
      xr[r][2] = sxyz[row * 4 + 2];
    }
#pragma unroll
    for (int gt = 0; gt < N / 16; ++gt) {
      int col = gt * 16 + (l & 15);
      float w0 = Wxyz[col], w1 = Wxyz[N + col], w2 = Wxyz[2 * N + col];
#pragma unroll
      for (int r = 0; r < 4; ++r)
        acc[gt][r] += xr[r][0] * w0 + xr[r][1] * w1 + xr[r][2] * w2;
    }
  }
}

// ---------------------------------------------------------------- SA2 fused, 512 threads / 128 rows, 128-col chunks
template<int NPTS, int Q, int M, int GPB, int FD, int C1, int C2, int C3>
__global__ __launch_bounds__(512) void sa2_kernel(
    const float* __restrict__ pts, const float* __restrict__ centers,
    const int* __restrict__ gidx, const float* __restrict__ feats,
    const float* __restrict__ W0, const float* __restrict__ B0,
    const unsigned short* __restrict__ G0h, const unsigned short* __restrict__ G0l,
    const unsigned short* __restrict__ G1h, const unsigned short* __restrict__ G1l,
    const float* __restrict__ B1,
    const unsigned short* __restrict__ G2h, const unsigned short* __restrict__ G2l,
    const float* __restrict__ B2,
    float* __restrict__ fout) {
  constexpr int NTH = 512;
  constexpr int ROWS = M * GPB;                 // 128
  constexpr int NWV = NTH / 64;                 // 8
  static_assert(ROWS == 16 * NWV, "wave owns 16 rows");
  constexpr int MK1 = (FD > C1 ? FD : C1);
  constexpr int MAXK = (MK1 > C2 ? MK1 : C2);
  constexpr int AS = MAXK + 12;
  constexpr int WS = MAXK + 8;
  constexpr int CW = 128;
  __shared__ __align__(16) float A[ROWS * AS];
  __shared__ __align__(16) unsigned short Whi[CW * WS];
  __shared__ __align__(16) unsigned short Wlo[CW * WS];
  __shared__ float sxyz[ROWS * 4];
  __shared__ int idxs[ROWS];
  __shared__ float ctr[GPB][4];
  __shared__ float red[NWV][C3];

  const int t = threadIdx.x;
  const int blk = blockIdx.x;
  const int b = blk / (Q / GPB);
  const int q0 = (blk % (Q / GPB)) * GPB;
  const int l = t & 63, wv = t >> 6;

  if (t < GPB * 3) {
    int g = t / 3, c2 = t % 3;
    ctr[g][c2] = centers[((size_t)b * Q + q0 + g) * 3 + c2];
  }
  for (int m = t; m < ROWS; m += NTH)
    idxs[m] = gidx[((size_t)b * Q + q0 + (m / M)) * M + (m % M)];
  __syncthreads();
  const float* pb = pts + (size_t)b * NPTS * 3;
  // one-component-per-thread gather (3x memory parallelism)
  for (int u = t; u < ROWS * 3; u += NTH) {
    int m = u / 3, cmp = u - m * 3;
    int g = m / M, i = idxs[m];
    sxyz[m * 4 + cmp] = pb[i * 3 + cmp] - ctr[g][cmp];
  }
  {  // FD=128 gather
    const int m = t >> 2, co = (t & 3) * (FD / 4);
    const float* src = feats + ((size_t)b * NPTS + idxs[m]) * FD + co;
    float* dst = A + m * AS + co;
#pragma unroll
    for (int j = 0; j < FD / 4; j += 4)
      *reinterpret_cast<float4*>(dst + j) = *reinterpret_cast<const float4*>(src + j);
  }
  __syncthreads();

  f32x4 acc[C3 / 16];

  do_layer<FD, C1, CW, AS, WS, true, NTH>(G0h, G0l, W0, A, Whi, Wlo, sxyz, acc, t);
#pragma unroll
  for (int gt = 0; gt < C1 / 16; ++gt) {
    int col = gt * 16 + (l & 15);
    float bia = B0[col];
#pragma unroll
    for (int r = 0; r < 4; ++r)
      A[(wv * 16 + (l >> 4) * 4 + r) * AS + col] = fmaxf(acc[gt][r] + bia, 0.f);
  }

  do_layer<C1, C2, CW, AS, WS, false, NTH>(G1h, G1l, nullptr, A, Whi, Wlo, sxyz, acc, t);
#pragma unroll
  for (int gt = 0; gt < C2 / 16; ++gt) {
    int col = gt * 16 + (l & 15);
    float bia = B1[col];
#pragma unroll
    for (int r = 0; r < 4; ++r)
      A[(wv * 16 + (l >> 4) * 4 + r) * AS + col] = fmaxf(acc[gt][r] + bia, 0.f);
  }

  do_layer<C2, C3, CW, AS, WS, false, NTH>(G2h, G2l, nullptr, A, Whi, Wlo, sxyz, acc, t);
#pragma unroll
  for (int gt = 0; gt < C3 / 16; ++gt) {
    int col = gt * 16 + (l & 15);
    float v = fmaxf(fmaxf(acc[gt][0], acc[gt][1]), fmaxf(acc[gt][2], acc[gt][3]));
    v = fmaxf(v, __shfl_xor(v, 16, 64));
    v = fmaxf(v, __shfl_xor(v, 32, 64));
    if (l < 16) red[wv][col] = v + B2[col];
  }
  __syncthreads();
  constexpr int WPG = NWV / GPB;
  for (int u = t; u < GPB * C3; u += NTH) {
    int g = u / C3, c2 = u - g * C3;
    float v = red[g * WPG][c2];
#pragma unroll
    for (int w = 1; w < WPG; ++w) v = fmaxf(v, red[g * WPG + w][c2]);
    fout[((size_t)b * Q + q0 + g) * C3 + c2] = fmaxf(v, 0.f);
  }
}

// ---------------------------------------------------------------- SA1 body, grid-strided: stage W once, process TPB tiles
template<int NPTS, int Q, int M, int GPB, int TPB>
DEVINL void sa1_body(const float* __restrict__ pts, const float* __restrict__ centers,
                     const int* __restrict__ gidx,
                     const float* __restrict__ W0, const float* __restrict__ B0,
                     const unsigned short* __restrict__ G1h, const unsigned short* __restrict__ G1l,
                     const float* __restrict__ B1,
                     const unsigned short* __restrict__ G2h, const unsigned short* __restrict__ G2l,
                     const float* __restrict__ B2,
                     float* __restrict__ fout, int sblk, int t) {
  static_assert(M * GPB == 64, "");
  constexpr int C1 = 64, C2 = 64, C3 = 128;
  constexpr int AS = 76;
  constexpr int WS = 72;
  constexpr int NC = C2 + C3;
  __shared__ __align__(16) float A[64 * AS];
  __shared__ __align__(16) unsigned short Wh[NC * WS];
  __shared__ __align__(16) unsigned short Wl[NC * WS];
  __shared__ float sxyz[64 * 4];
  __shared__ int idxs[64];
  __shared__ float ctr[GPB][4];
  __shared__ float red[4][C3];

  const int l = t & 63, wv = t >> 6;

  for (int u = t; u < NC * 8; u += 256) {
    int col = u >> 3, k8 = (u & 7) * 8;
    const unsigned short* sh = (col < C2) ? G1h + (size_t)col * 64 + k8
                                          : G2h + (size_t)(col - C2) * 64 + k8;
    const unsigned short* sl = (col < C2) ? G1l + (size_t)col * 64 + k8
                                          : G2l + (size_t)(col - C2) * 64 + k8;
    *reinterpret_cast<u16x8*>(Wh + col * WS + k8) = *reinterpret_cast<const u16x8*>(sh);
    *reinterpret_cast<u16x8*>(Wl + col * WS + k8) = *reinterpret_cast<const u16x8*>(sl);
  }

  for (int it = 0; it < TPB; ++it) {
    const int blk = sblk * TPB + it;
    const int b = blk / (Q / GPB);
    const int q0 = (blk % (Q / GPB)) * GPB;

    if (t < GPB * 3) {
      int g = t / 3, c2 = t % 3;
      ctr[g][c2] = centers[((size_t)b * Q + q0 + g) * 3 + c2];
    }
    for (int m = t; m < 64; m += 256)
      idxs[m] = gidx[((size_t)b * Q + q0 + (m / M)) * M + (m % M)];
    __syncthreads();
    const float* pb = pts + (size_t)b * NPTS * 3;
    // one-component-per-thread gather (3x memory parallelism)
    for (int u = t; u < 64 * 3; u += 256) {
      int m = u / 3, cmp = u - m * 3;
      int g = m / M, i = idxs[m];
      sxyz[m * 4 + cmp] = pb[i * 3 + cmp] - ctr[g][cmp];
    }
    __syncthreads();

    for (int u = t; u < 64 * C1; u += 256) {
      int m = u / C1, c2 = u - m * C1;
      float v = B0[c2] + sxyz[m * 4 + 0] * W0[0 * C1 + c2]
                       + sxyz[m * 4 + 1] * W0[1 * C1 + c2]
                       + sxyz[m * 4 + 2] * W0[2 * C1 + c2];
      A[m * AS + c2] = fmaxf(v, 0.f);
    }
    __syncthreads();

    f32x4 acc[8];
    // ---- L2: 64 -> 64, W cols [0,64), barrier-free
    {
      bf16x8 ah[2], al[2];
      const float* ap = A + (wv * 16 + (l & 15)) * AS + (l >> 4) * 8;
#pragma unroll
      for (int kt = 0; kt < 2; ++kt) {
        float4 v0 = *reinterpret_cast<const float4*>(ap + kt * 32);
        float4 v1 = *reinterpret_cast<const float4*>(ap + kt * 32 + 4);
        float f[8] = {v0.x, v0.y, v0.z, v0.w, v1.x, v1.y, v1.z, v1.w};
        bf16x8 h, lo2;
#pragma unroll
        for (int j = 0; j < 8; ++j) {
          unsigned short hb = f2bh(f[j]);
          h[j] = (short)hb;
          lo2[j] = (short)f2bh(f[j] - bh2f(hb));
        }
        ah[kt] = h; al[kt] = lo2;
      }
#pragma unroll
      for (int i = 0; i < 4; ++i) acc[i] = f32x4{0.f, 0.f, 0.f, 0.f};
#pragma unroll
      for (int ct = 0; ct < 4; ++ct) {
        const unsigned short* wp = Wh + (ct * 16 + (l & 15)) * WS + (l >> 4) * 8;
        const unsigned short* wq = Wl + (ct * 16 + (l & 15)) * WS + (l >> 4) * 8;
        f32x4 a = acc[ct];
#pragma unroll
        for (int kt = 0; kt < 2; ++kt) {
          bf16x8 wh = *reinterpret_cast<const bf16x8*>(wp + kt * 32);
          bf16x8 wl = *reinterpret_cast<const bf16x8*>(wq + kt * 32);
          a = __builtin_amdgcn_mfma_f32_16x16x32_bf16(ah[kt], wh, a, 0, 0, 0);
          a = __builtin_amdgcn_mfma_f32_16x16x32_bf16(al[kt], wh, a, 0, 0, 0);
          a = __builtin_amdgcn_mfma_f32_16x16x32_bf16(ah[kt], wl, a, 0, 0, 0);
        }
        acc[ct] = a;
      }
#pragma unroll
      for (int gt = 0; gt < 4; ++gt) {
        int col = gt * 16 + (l & 15);
        float bia = B1[col];
#pragma unroll
        for (int r = 0; r < 4; ++r)
          A[(wv * 16 + (l >> 4) * 4 + r) * AS + col] = fmaxf(acc[gt][r] + bia, 0.f);
      }
    }

    // ---- L3: 64 -> 128, W cols [64,192), maxpool epilogue
    {
      bf16x8 ah[2], al[2];
      const float* ap = A + (wv * 16 + (l & 15)) * AS + (l >> 4) * 8;
#pragma unroll
      for (int kt = 0; kt < 2; ++kt) {
        float4 v0 = *reinterpret_cast<const float4*>(ap + kt * 32);
        float4 v1 = *reinterpret_cast<const float4*>(ap + kt * 32 + 4);
        float f[8] = {v0.x, v0.y, v0.z, v0.w, v1.x, v1.y, v1.z, v1.w};
        bf16x8 h, lo2;
#pragma unroll
        for (int j = 0; j < 8; ++j) {
          unsigned short hb = f2bh(f[j]);
          h[j] = (short)hb;
          lo2[j] = (short)f2bh(f[j] - bh2f(hb));
        }
        ah[kt] = h; al[kt] = lo2;
      }
#pragma unroll
      for (int i = 0; i < 8; ++i) acc[i] = f32x4{0.f, 0.f, 0.f, 0.f};
#pragma unroll
      for (int gt = 0; gt < 8; ++gt) {
        const unsigned short* wp = Wh + (C2 + gt * 16 + (l & 15)) * WS + (l >> 4) * 8;
        const unsigned short* wq = Wl + (C2 + gt * 16 + (l & 15)) * WS + (l >> 4) * 8;
        f32x4 a = acc[gt];
#pragma unroll
        for (int kt = 0; kt < 2; ++kt) {
          bf16x8 wh = *reinterpret_cast<const bf16x8*>(wp + kt * 32);
          bf16x8 wl = *reinterpret_cast<const bf16x8*>(wq + kt * 32);
          a = __builtin_amdgcn_mfma_f32_16x16x32_bf16(ah[kt], wh, a, 0, 0, 0);
          a = __builtin_amdgcn_mfma_f32_16x16x32_bf16(al[kt], wh, a, 0, 0, 0);
          a = __builtin_amdgcn_mfma_f32_16x16x32_bf16(ah[kt], wl, a, 0, 0, 0);
        }
        acc[gt] = a;
      }
#pragma unroll
      for (int gt = 0; gt < 8; ++gt) {
        int col = gt * 16 + (l & 15);
        float v = fmaxf(fmaxf(acc[gt][0], acc[gt][1]), fmaxf(acc[gt][2], acc[gt][3]));
        v = fmaxf(v, __shfl_xor(v, 16, 64));
        v = fmaxf(v, __shfl_xor(v, 32, 64));
        if (l < 16) red[wv][col] = v + B2[col];
      }
    }
    __syncthreads();
    constexpr int WPG = 4 / GPB;
    for (int u = t; u < GPB * C3; u += 256) {
      int g = u / C3, c2 = u - g * C3;
      float v = red[g * WPG][c2];
#pragma unroll
      for (int w = 1; w < WPG; ++w) v = fmaxf(v, red[g * WPG + w][c2]);
      fout[((size_t)b * Q + q0 + g) * C3 + c2] = fmaxf(v, 0.f);
    }
    __syncthreads();
  }
}

// [bq2 || sa1]
__global__ __launch_bounds__(256) void bq2_sa1_kernel(
    const float* __restrict__ xyz, const float* __restrict__ nx1,
    const float* __restrict__ nx2, int* __restrict__ gidx2, float r22,
    const int* __restrict__ gidx1,
    const float* __restrict__ s1w0, const float* __restrict__ s1b0,
    const unsigned short* __restrict__ g11h, const unsigned short* __restrict__ g11l,
    const float* __restrict__ s1b1,
    const unsigned short* __restrict__ g12h, const unsigned short* __restrict__ g12l,
    const float* __restrict__ s1b2, float* __restrict__ f1) {
  if (blockIdx.x < 1024) {
    bq_body<512, 64>(nx1, nx2, gidx2, 128, r22, blockIdx.x, threadIdx.x);
    return;
  }
  sa1_body<4096, 512, 32, 2, 8>(xyz, nx1, gidx1, s1w0, s1b0, g11h, g11l, s1b1,
                                g12h, g12l, s1b2, f1, blockIdx.x - 1024, threadIdx.x);
}

// ---------------------------------------------------------------- SA3 fused (512 threads / 8 waves: 2 waves/SIMD TLP)
constexpr int AS3 = 532;
DEVINL void sa3_frags(const float* __restrict__ A, int l, int KT, bf16x8* ahi, bf16x8* alo) {
  const float* ap = A + (l & 15) * AS3 + (l >> 4) * 8;
  for (int kt = 0; kt < KT; ++kt) {
    float4 v0 = *reinterpret_cast<const float4*>(ap + kt * 32);
    float4 v1 = *reinterpret_cast<const float4*>(ap + kt * 32 + 4);
    float f[8] = {v0.x, v0.y, v0.z, v0.w, v1.x, v1.y, v1.z, v1.w};
    bf16x8 h, lo2;
#pragma unroll
    for (int j = 0; j < 8; ++j) {
      unsigned short hb = f2bh(f[j]);
      h[j] = (short)hb;
      lo2[j] = (short)f2bh(f[j] - bh2f(hb));
    }
    ahi[kt] = h; alo[kt] = lo2;
  }
}

template<int CT, int K>
DEVINL void sa3_mmN(const unsigned short* __restrict__ Gh, const unsigned short* __restrict__ Gl,
                    int ncol0, int l, const bf16x8* ahi, const bf16x8* alo, f32x4* acc4) {
  constexpr int KT = K / 32;
#pragma unroll
  for (int ct = 0; ct < CT; ++ct) {
    const unsigned short* hp = Gh + (size_t)(ncol0 + ct * 16 + (l & 15)) * K + (l >> 4) * 8;
    const unsigned short* lp = Gl + (size_t)(ncol0 + ct * 16 + (l & 15)) * K + (l >> 4) * 8;
    f32x4 a = acc4[ct];
#pragma unroll
    for (int kt = 0; kt < KT; ++kt) {
      bf16x8 wh = *reinterpret_cast<const bf16x8*>(hp + kt * 32);
      bf16x8 wl = *reinterpret_cast<const bf16x8*>(lp + kt * 32);
      a = __builtin_amdgcn_mfma_f32_16x16x32_bf16(ahi[kt], wh, a, 0, 0, 0);
      a = __builtin_amdgcn_mfma_f32_16x16x32_bf16(alo[kt], wh, a, 0, 0, 0);
      a = __builtin_amdgcn_mfma_f32_16x16x32_bf16(ahi[kt], wl, a, 0, 0, 0);
    }
    acc4[ct] = a;
  }
}

__global__ __launch_bounds__(512) void sa3f_kernel(
    const float* __restrict__ nx2, const float* __restrict__ f2,
    const float* __restrict__ W0full,
    const unsigned short* __restrict__ G0h, const unsigned short* __restrict__ G0l,
    const float* __restrict__ B0,
    const unsigned short* __restrict__ G1h, const unsigned short* __restrict__ G1l,
    const float* __restrict__ B1,
    const unsigned short* __restrict__ G2h, const unsigned short* __restrict__ G2l,
    const float* __restrict__ B2,
    float* __restrict__ partial) {
  __shared__ __align__(16) float A[16 * AS3];
  __shared__ float sxyz[16][4];
  const int t = threadIdx.x, l = t & 63, w = t >> 6;  // w in 0..7
  const int b = blockIdx.x >> 3, rb = blockIdx.x & 7;
  const int row0 = rb * 16;
  {
    int r = t >> 5, cc = (t & 31) * 8;
    const float* src = f2 + ((size_t)b * 128 + row0 + r) * 256 + cc;
    float* dstp = A + r * AS3 + cc;
#pragma unroll
    for (int j = 0; j < 8; j += 4)
      *reinterpret_cast<float4*>(dstp + j) = *reinterpret_cast<const float4*>(src + j);
    if (t < 16) {
      const float* s = nx2 + ((size_t)b * 128 + row0 + t) * 3;
      sxyz[t][0] = s[0]; sxyz[t][1] = s[1]; sxyz[t][2] = s[2];
    }
  }
  __syncthreads();

  {  // L1: K=256 MFMA + xyz f32 correction -> N=256 (wave cols 32)
    bf16x8 ah[8], al[8];
    sa3_frags(A, l, 8, ah, al);
    __syncthreads();
    f32x4 acc[2];
#pragma unroll
    for (int i = 0; i < 2; ++i) acc[i] = f32x4{0.f, 0.f, 0.f, 0.f};
    sa3_mmN<2, 256>(G0h, G0l, w * 32, l, ah, al, acc);
    float xr[4][3];
#pragma unroll
    for (int r = 0; r < 4; ++r) {
      int row = (l >> 4) * 4 + r;
      xr[r][0] = sxyz[row][0]; xr[r][1] = sxyz[row][1]; xr[r][2] = sxyz[row][2];
    }
#pragma unroll
    for (int ct = 0; ct < 2; ++ct) {
      int col = w * 32 + ct * 16 + (l & 15);
      float w0 = W0full[col], w1 = W0full[256 + col], w2 = W0full[512 + col];
      float bia = B0[col];
#pragma unroll
      for (int r = 0; r < 4; ++r) {
        int row = (l >> 4) * 4 + r;
        float v = acc[ct][r] + xr[r][0] * w0 + xr[r][1] * w1 + xr[r][2] * w2 + bia;
        A[row * AS3 + col] = fmaxf(v, 0.f);
      }
    }
    __syncthreads();
  }

  {  // L2: K=256 -> N=512 (wave cols 64)
    bf16x8 ah[8], al[8];
    sa3_frags(A, l, 8, ah, al);
    __syncthreads();
    f32x4 acc[4];
#pragma unroll
    for (int i = 0; i < 4; ++i) acc[i] = f32x4{0.f, 0.f, 0.f, 0.f};
    sa3_mmN<4, 256>(G1h, G1l, w * 64, l, ah, al, acc);
#pragma unroll
    for (int cc = 0; cc < 4; ++cc) {
      int col = w * 64 + cc * 16 + (l & 15);
      float bia = B1[col];
#pragma unroll
      for (int r = 0; r < 4; ++r) {
        int row = (l >> 4) * 4 + r;
        A[row * AS3 + col] = fmaxf(acc[cc][r] + bia, 0.f);
      }
    }
    __syncthreads();
  }

  {  // L3: K=512 -> N=1024 (wave cols 128 = 2 subs x 64), maxpool -> partial
    bf16x8 ah[16], al[16];
    sa3_frags(A, l, 16, ah, al);
    float* pout = partial + ((size_t)(b * 8 + rb)) * 1024;
#pragma unroll
    for (int sub = 0; sub < 2; ++sub) {
      f32x4 acc[4];
#pragma unroll
      for (int i = 0; i < 4; ++i) acc[i] = f32x4{0.f, 0.f, 0.f, 0.f};
      sa3_mmN<4, 512>(G2h, G2l, w * 128 + sub * 64, l, ah, al, acc);
#pragma unroll
      for (int ct = 0; ct < 4; ++ct) {
        int col = w * 128 + sub * 64 + ct * 16 + (l & 15);
        float v = fmaxf(fmaxf(acc[ct][0], acc[ct][1]), fmaxf(acc[ct][2], acc[ct][3]));
        v = fmaxf(v, __shfl_xor(v, 16, 64));
        v = fmaxf(v, __shfl_xor(v, 32, 64));
        if (l < 16) pout[col] = v + B2[col];  // relu deferred to heads (monotone)
      }
    }
  }
}

// ---------------------------------------------------------------- heads (8-way partial max + relu + dots)
__global__ __launch_bounds__(256) void heads_kernel(const float* __restrict__ partial,
                                                    const float* __restrict__ cw,
                                                    const float* __restrict__ cb,
                                                    const float* __restrict__ rw,
                                                    const float* __restrict__ rb,
                                                    float* __restrict__ out) {
  const int b = blockIdx.x, t = threadIdx.x;
  const float* pb = partial + (size_t)b * 8 * 1024;
  float a0 = 0, a1 = 0, a2 = 0, a3 = 0, a4 = 0;
  for (int k = t; k < 1024; k += 256) {
    float m = pb[k];
#pragma unroll
    for (int p = 1; p < 8; ++p) m = fmaxf(m, pb[p * 1024 + k]);
    float f = fmaxf(m, 0.f);
    a0 += f * cw[k];
    const float* r = rw + (size_t)k * 4;
    a1 += f * r[0]; a2 += f * r[1]; a3 += f * r[2]; a4 += f * r[3];
  }
#pragma unroll
  for (int m = 32; m >= 1; m >>= 1) {
    a0 += __shfl_xor(a0, m, 64); a1 += __shfl_xor(a1, m, 64);
    a2 += __shfl_xor(a2, m, 64); a3 += __shfl_xor(a3, m, 64);
    a4 += __shfl_xor(a4, m, 64);
  }
  __shared__ float red[4][5];
  const int wv = t >> 6, ln = t & 63;
  if (ln == 0) { red[wv][0] = a0; red[wv][1] = a1; red[wv][2] = a2; red[wv][3] = a3; red[wv][4] = a4; }
  __syncthreads();
  if (t == 0) {
    float s0 = red[0][0] + red[1][0] + red[2][0] + red[3][0];
    float s1 = red[0][1] + red[1][1] + red[2][1] + red[3][1];
    float s2 = red[0][2] + red[1][2] + red[2][2] + red[3][2];
    float s3 = red[0][3] + red[1][3] + red[2][3] + red[3][3];
    float s4 = red[0][4] + red[1][4] + red[2][4] + red[3][4];
    out[b] = s0 + cb[0];
    out[32 + b * 4 + 0] = s1 + rb[0];
    out[32 + b * 4 + 1] = s2 + rb[1];
    out[32 + b * 4 + 2] = s3 + rb[2];
    out[32 + b * 4 + 3] = s4 + rb[3];
  }
}

// ---------------------------------------------------------------- launch
extern "C" void kernel_launch(void* const* d_in, const int* in_sizes, int n_in,
                              void* d_out, int out_size, void* d_ws, size_t ws_size,
                              hipStream_t stream) {
  (void)in_sizes; (void)n_in; (void)out_size; (void)ws_size;
  const float* xyz  = (const float*)d_in[0];
  const float* s1w0 = (const float*)d_in[1];  const float* s1b0 = (const float*)d_in[2];
  const float* s1w1 = (const float*)d_in[3];  const float* s1b1 = (const float*)d_in[4];
  const float* s1w2 = (const float*)d_in[5];  const float* s1b2 = (const float*)d_in[6];
  const float* s2w0 = (const float*)d_in[7];  const float* s2b0 = (const float*)d_in[8];
  const float* s2w1 = (const float*)d_in[9];  const float* s2b1 = (const float*)d_in[10];
  const float* s2w2 = (const float*)d_in[11]; const float* s2b2 = (const float*)d_in[12];
  const float* s3w0 = (const float*)d_in[13]; const float* s3b0 = (const float*)d_in[14];
  const float* s3w1 = (const float*)d_in[15]; const float* s3b1 = (const float*)d_in[16];
  const float* s3w2 = (const float*)d_in[17]; const float* s3b2 = (const float*)d_in[18];
  const float* clsw = (const float*)d_in[19]; const float* clsb = (const float*)d_in[20];
  const float* regw = (const float*)d_in[21]; const float* regb = (const float*)d_in[22];

  char* ws = (char*)d_ws;
  float* nx1   = (float*)(ws + 0);          // 32*512*3
  int*   gidx1 = (int*)  (ws + 196608);     // 32*512*32
  float* f1    = (float*)(ws + 2293760);    // 32*512*128
  float* nx2   = (float*)(ws + 10682368);   // 32*128*3
  int*   gidx2 = (int*)  (ws + 10731520);   // 32*128*64
  float* f2    = (float*)(ws + 11780096);   // 32*128*256

  // SA1/SA2 prepped weights (u16 hi/lo, transposed [n][k])
  unsigned short* wt = (unsigned short*)(ws + 20168704);
  unsigned short* g11h = wt;            // 64*64
  unsigned short* g11l = wt + 4096;
  unsigned short* g12h = wt + 8192;     // 128*64
  unsigned short* g12l = wt + 16384;
  unsigned short* g20h = wt + 24576;    // 128*128 (rows 3..130 of s2w0)
  unsigned short* g20l = wt + 40960;
  unsigned short* g21h = wt + 57344;    // 128*128
  unsigned short* g21l = wt + 73728;
  unsigned short* g22h = wt + 90112;    // 256*128
  unsigned short* g22l = wt + 122880;   // ends at byte 20168704+311296 = 20480000
  // SA3 prepped weights
  unsigned short* g30h = (unsigned short*)(ws + 20480000);  // 256x256
  unsigned short* g30l = (unsigned short*)(ws + 20611072);
  unsigned short* g31h = (unsigned short*)(ws + 20742144);  // 512x256
  unsigned short* g31l = (unsigned short*)(ws + 21004288);
  unsigned short* g32h = (unsigned short*)(ws + 21266432);  // 1024x512
  unsigned short* g32l = (unsigned short*)(ws + 22315008);
  float* partial = (float*)(ws + 23363584);                 // 32*8*1024 f32 -> ends 24412160

  const float r21 = (float)(0.2 * 0.2);
  const float r22 = (float)(0.4 * 0.4);

  WPTab tab;
  int off = 0;
  auto set = [&](int i, const float* W, unsigned short* hi, unsigned short* lo,
                 int K, int N, int row0) {
    tab.e[i] = WPEnt{W, hi, lo, K, N, row0, off, off + K * N};
    off += K * N;
  };
  set(0, s1w1, g11h, g11l, 64, 64, 0);
  set(1, s1w2, g12h, g12l, 64, 128, 0);
  set(2, s2w0, g20h, g20l, 128, 128, 3);
  set(3, s2w1, g21h, g21l, 128, 128, 0);
  set(4, s2w2, g22h, g22l, 128, 256, 0);
  set(5, s3w0, g30h, g30l, 256, 256, 3);
  set(6, s3w1, g31h, g31l, 256, 512, 0);
  set(7, s3w2, g32h, g32l, 512, 1024, 0);
  const int wblocks = (off + 255) / 256;

  fps1_wprep_kernel<<<32 + wblocks, 256, 0, stream>>>(xyz, nx1, tab);
  fps2_bq1_kernel<<<32 + 4096, 256, 0, stream>>>(xyz, nx1, gidx1, nx2, r21);
  bq2_sa1_kernel<<<1024 + 1024, 256, 0, stream>>>(
      xyz, nx1, nx2, gidx2, r22, gidx1,
      s1w0, s1b0, g11h, g11l, s1b1, g12h, g12l, s1b2, f1);
  sa2_kernel<512, 128, 64, 2, 128, 128, 128, 256><<<2048, 512, 0, stream>>>(
      nx1, nx2, gidx2, f1, s2w0, s2b0,
      g20h, g20l, g21h, g21l, s2b1, g22h, g22l, s2b2, f2);
  sa3f_kernel<<<256, 512, 0, stream>>>(nx2, f2, s3w0, g30h, g30l, s3b0,
                                       g31h, g31l, s3b1, g32h, g32l, s3b2, partial);
  heads_kernel<<<32, 256, 0, stream>>>(partial, clsw, clsb, regw, regb, (float*)d_out);
}

// Round 16
// 643.869 us; speedup vs baseline: 1.1361x; 1.0244x over previous
//
#include <hip/hip_runtime.h>
#include <hip/hip_bf16.h>

#define DEVINL __device__ __forceinline__

typedef __attribute__((ext_vector_type(8))) short bf16x8;
typedef __attribute__((ext_vector_type(8))) unsigned short u16x8;
typedef __attribute__((ext_vector_type(4))) float f32x4;

// f32 -> bf16 bits via the NATIVE cast (RNE). The compiler emits hardware
// v_cvt_pk_bf16_f32 (2 elems/instr) instead of the 4-op bit-twiddle RNE
// emulation -- bit-identical results for normal values (both RNE), ~4-8x
// fewer VALU ops on the MLP kernels' hot A-split path (T12/m240 guidance).
DEVINL unsigned short f2bh(float f){
  __hip_bfloat16 h = __float2bfloat16(f);
  return __bfloat16_as_ushort(h);
}
DEVINL float bh2f(unsigned short h){ return __uint_as_float(((unsigned)h) << 16); }

// Wave64 max-reduce of a u64 key via DPP (VALU latency, no DS pipe).
DEVINL unsigned long long dpp_max_u64(unsigned long long k) {
#define DPP_STEP(ctrl)                                                        \
  {                                                                           \
    int hi = (int)(k >> 32), lo = (int)(unsigned)k;                           \
    int oh = __builtin_amdgcn_update_dpp(0, hi, ctrl, 0xF, 0xF, 1);           \
    int ol = __builtin_amdgcn_update_dpp(0, lo, ctrl, 0xF, 0xF, 1);           \
    unsigned long long ok =                                                   \
        ((unsigned long long)(unsigned)oh << 32) | (unsigned)ol;              \
    if (ok > k) k = ok;                                                       \
  }
  DPP_STEP(0x111)  // row_shr:1
  DPP_STEP(0x112)  // row_shr:2
  DPP_STEP(0x114)  // row_shr:4
  DPP_STEP(0x118)  // row_shr:8
  DPP_STEP(0x142)  // row_bcast:15
  DPP_STEP(0x143)  // row_bcast:31
#undef DPP_STEP
  return k;
}

// ---------------------------------------------------------------- FPS body (R4-proven, LOCKED)
template<int N, int NP, int NT>
DEVINL void fps_body(const float* __restrict__ xyz, float* __restrict__ nxyz,
                     int b, int t) {
  constexpr int PTS = N / NT;
  constexpr int NW = NT / 64;
  __shared__ float xs[N], ys[N], zs[N];
  __shared__ int farr[NP];
  __shared__ unsigned long long sk[2][(NW > 1 ? NW : 1)];
  float px[PTS], py[PTS], pz[PTS], dst[PTS];
  const float* base = xyz + (size_t)b * N * 3;
#pragma unroll
  for (int j = 0; j < PTS; ++j) {
    int i = t + j * NT;
    float x = base[i * 3 + 0], y = base[i * 3 + 1], z = base[i * 3 + 2];
    px[j] = x; py[j] = y; pz[j] = z;
    xs[i] = x; ys[i] = y; zs[i] = z;
    dst[j] = 1e10f;
  }
  if constexpr (NW > 1) __syncthreads();
  int far = 0;
  const int wv = t >> 6, ln = t & 63;
  for (int s = 0; s < NP; ++s) {
    float cx = xs[far], cy = ys[far], cz = zs[far];
    if (t == 0) farr[s] = far;
    float bv = -1.f; int bi = 0;
#pragma unroll
    for (int j = 0; j < PTS; ++j) {
      // no-fma, left-to-right: matches numpy elementwise + sum order
      float dx = __fsub_rn(px[j], cx), dy = __fsub_rn(py[j], cy), dz = __fsub_rn(pz[j], cz);
      float d = __fadd_rn(__fadd_rn(__fmul_rn(dx, dx), __fmul_rn(dy, dy)), __fmul_rn(dz, dz));
      float nd = fminf(dst[j], d);
      dst[j] = nd;
      int i = t + j * NT;
      if (nd > bv) { bv = nd; bi = i; }  // strict >: first max kept per thread
    }
    // pack: max key == max dist, tie -> larger ~idx == smaller idx
    unsigned long long key =
        ((unsigned long long)__float_as_uint(bv) << 32) | (unsigned)(~bi);
    key = dpp_max_u64(key);
    if constexpr (NW == 1) {
      int rl = __builtin_amdgcn_readlane((int)(unsigned)key, 63);
      far = (int)(~(unsigned)rl);
    } else {
      const int p = s & 1;
      if (ln == 63) sk[p][wv] = key;
      __syncthreads();
      unsigned long long m = sk[p][0];
#pragma unroll
      for (int q = 1; q < NW; ++q) {
        unsigned long long qk = sk[p][q];
        if (qk > m) m = qk;
      }
      far = (int)(~(unsigned)m);
    }
  }
  if constexpr (NW > 1) __syncthreads();
  for (int s2 = t; s2 < NP; s2 += NT) {
    int fi = farr[s2];
    float* o = nxyz + ((size_t)b * NP + s2) * 3;
    o[0] = xs[fi]; o[1] = ys[fi]; o[2] = zs[fi];
  }
}

// ---------------------------------------------------------------- ball query body (pipelined)
template<int N, int NS>
DEVINL void bq_body(const float* __restrict__ pts, const float* __restrict__ centers,
                    int* __restrict__ gidx, int Q, float r2, int blk, int t) {
  const int wv = t >> 6, ln = t & 63;
  const int g = blk * 4 + wv;
  const int b = g / Q, q = g % Q;
  const float* pb = pts + (size_t)b * N * 3;
  const float* c = centers + ((size_t)b * Q + q) * 3;
  const float cx = c[0], cy = c[1], cz = c[2];
  __shared__ int gbuf[4][NS];
  float nx = pb[ln * 3 + 0], ny = pb[ln * 3 + 1], nz = pb[ln * 3 + 2];
  int taken = 0;
  for (int base = 0; base < N; base += 64) {
    const float x = nx, y = ny, z = nz;
    if (base + 64 < N) {
      const float* np = pb + (size_t)(base + 64 + ln) * 3;
      nx = np[0]; ny = np[1]; nz = np[2];
    }
    int i = base + ln;
    float dx = __fsub_rn(x, cx), dy = __fsub_rn(y, cy), dz = __fsub_rn(z, cz);
    float d = __fadd_rn(__fadd_rn(__fmul_rn(dx, dx), __fmul_rn(dy, dy)), __fmul_rn(dz, dz));
    bool in = (d <= r2);
    unsigned long long mk = __ballot(in);
    int rank = __popcll(mk & ((1ull << ln) - 1ull));
    int pos = taken + rank;
    if (in && pos < NS) gbuf[wv][pos] = i;
    taken += (int)__popcll(mk);
    if (taken >= NS) break;
  }
  int total = taken < NS ? taken : NS;
  int first = gbuf[wv][0];
  int* out = gidx + ((size_t)b * Q + q) * NS;
  for (int j = ln; j < NS; j += 64) out[j] = (j < total) ? gbuf[wv][j] : first;
}

// ---------------------------------------------------------------- weight prep body
struct WPEnt { const float* W; unsigned short* hi; unsigned short* lo; int K, N, row0, beg, end; };
struct WPTab { WPEnt e[8]; };
DEVINL void wprep_body(const WPTab& tab, int idx) {
#pragma unroll
  for (int i = 0; i < 8; ++i) {
    const WPEnt& E = tab.e[i];
    if (idx >= E.beg && idx < E.end) {
      int local = idx - E.beg;
      int k = local / E.N, n = local - k * E.N;
      float v = E.W[(size_t)(E.row0 + k) * E.N + n];
      unsigned short h = f2bh(v);
      E.hi[(size_t)n * E.K + k] = h;
      E.lo[(size_t)n * E.K + k] = f2bh(v - bh2f(h));
    }
  }
}

// ---------------------------------------------------------------- fused launches
// [fps1 || wprep]
__global__ __launch_bounds__(256) void fps1_wprep_kernel(const float* __restrict__ xyz,
                                                         float* __restrict__ nx1, WPTab tab) {
  if (blockIdx.x < 32) { fps_body<4096, 512, 256>(xyz, nx1, blockIdx.x, threadIdx.x); return; }
  wprep_body(tab, (blockIdx.x - 32) * 256 + threadIdx.x);
}

// [fps2 || bq1]: fps2 as single wave (barrier-free); waves 1-3 retire.
__global__ __launch_bounds__(256) void fps2_bq1_kernel(const float* __restrict__ xyz,
                                                       const float* __restrict__ nx1,
                                                       int* __restrict__ gidx1,
                                                       float* __restrict__ nx2, float r21) {
  if (blockIdx.x < 32) {
    if (threadIdx.x < 64) fps_body<512, 128, 64>(nx1, nx2, blockIdx.x, threadIdx.x);
    return;
  }
  bq_body<4096, 32>(xyz, nx1, gidx1, 512, r21, blockIdx.x - 32, threadIdx.x);
}

// ---------------------------------------------------------------- split-bf16 MFMA layer (CW-col chunks)
template<int K, int N, int CW, int AS, int WS, bool XYZC, int NTH>
DEVINL void do_layer(const unsigned short* __restrict__ Ghi, const unsigned short* __restrict__ Glo,
                     const float* __restrict__ Wxyz,
                     const float* __restrict__ A, unsigned short* __restrict__ Whi,
                     unsigned short* __restrict__ Wlo, const float* __restrict__ sxyz,
                     f32x4* acc, int t) {
  constexpr int KT = K / 32;
  constexpr int NCH = N / CW;
  constexpr int K8 = K / 8;
  constexpr int SI = (CW * K8) / NTH;
  constexpr int CT = CW / 16;
  const int l = t & 63, wv = t >> 6;

  u16x8 rh[SI], rl[SI];
#pragma unroll
  for (int s = 0; s < SI; ++s) {
    int u = t + s * NTH;
    int nn = u / K8, k8 = (u - nn * K8) * 8;
    rh[s] = *reinterpret_cast<const u16x8*>(Ghi + (size_t)nn * K + k8);
    rl[s] = *reinterpret_cast<const u16x8*>(Glo + (size_t)nn * K + k8);
  }

  bf16x8 ahi[KT], alo[KT];
  {
    const int row = wv * 16 + (l & 15);
    const float* ap = A + row * AS + (l >> 4) * 8;
#pragma unroll
    for (int kt = 0; kt < KT; ++kt) {
      float4 v0 = *reinterpret_cast<const float4*>(ap + kt * 32);
      float4 v1 = *reinterpret_cast<const float4*>(ap + kt * 32 + 4);
      float f[8] = {v0.x, v0.y, v0.z, v0.w, v1.x, v1.y, v1.z, v1.w};
      bf16x8 h, lo2;
#pragma unroll
      for (int j = 0; j < 8; ++j) {
        unsigned short hb = f2bh(f[j]);
        h[j] = (short)hb;
        lo2[j] = (short)f2bh(f[j] - bh2f(hb));
      }
      ahi[kt] = h; alo[kt] = lo2;
    }
  }
#pragma unroll
  for (int i = 0; i < N / 16; ++i) acc[i] = f32x4{0.f, 0.f, 0.f, 0.f};

#pragma unroll
  for (int c = 0; c < NCH; ++c) {
    __syncthreads();  // all waves done reading previous W contents
#pragma unroll
    for (int s = 0; s < SI; ++s) {
      int u = t + s * NTH;
      int nn = u / K8, k8 = (u - nn * K8) * 8;
      *reinterpret_cast<u16x8*>(Whi + nn * WS + k8) = rh[s];
      *reinterpret_cast<u16x8*>(Wlo + nn * WS + k8) = rl[s];
    }
    if (c + 1 < NCH) {
#pragma unroll
      for (int s = 0; s < SI; ++s) {
        int u = t + s * NTH;
        int nn = u / K8, k8 = (u - nn * K8) * 8;
        rh[s] = *reinterpret_cast<const u16x8*>(Ghi + (size_t)((c + 1) * CW + nn) * K + k8);
        rl[s] = *reinterpret_cast<const u16x8*>(Glo + (size_t)((c + 1) * CW + nn) * K + k8);
      }
    }
    __syncthreads();
#pragma unroll
    for (int ct = 0; ct < CT; ++ct) {
      const unsigned short* wp = Whi + (ct * 16 + (l & 15)) * WS + (l >> 4) * 8;
      const unsigned short* wq = Wlo + (ct * 16 + (l & 15)) * WS + (l >> 4) * 8;
      f32x4 a = acc[c * CT + ct];
#pragma unroll
      for (int kt = 0; kt < KT; ++kt) {
        bf16x8 wh = *reinterpret_cast<const bf16x8*>(wp + kt * 32);
        bf16x8 wl = *reinterpret_cast<const bf16x8*>(wq + kt * 32);
        a = __builtin_amdgcn_mfma_f32_16x16x32_bf16(ahi[kt], wh, a, 0, 0, 0);
        a = __builtin_amdgcn_mfma_f32_16x16x32_bf16(alo[kt], wh, a, 0, 0, 0);
        a = __builtin_amdgcn_mfma_f32_16x16x32_bf16(ahi[kt], wl, a, 0, 0, 0);
      }
      acc[c * CT + ct] = a;
    }
  }
  if constexpr (XYZC) {
    float xr[4][3];
#pragma unroll
    for (int r = 0; r < 4; ++r) {
      int row = wv * 16 + (l >> 4) * 4 + r;
      xr[r][0] = sxyz[row * 4 + 0];
      xr[r][1] = sxyz[row * 4 + 1];
      xr[r][2] = sxyz[row * 4 + 2];
    }
#pragma unroll
    for (int gt = 0; gt < N / 16; ++gt) {
      int col = gt * 16 + (l & 15);
      float w0 = Wxyz[col], w1 = Wxyz[N + col], w2 = Wxyz[2 * N + col];
#pragma unroll
      for (int r = 0; r < 4; ++r)
        acc[gt][r] += xr[r][0] * w0 + xr[r][1] * w1 + xr[r][2] * w2;
    }
  }
}

// ---------------------------------------------------------------- SA2 fused, 512 threads / 128 rows, 128-col chunks
template<int NPTS, int Q, int M, int GPB, int FD, int C1, int C2, int C3>
__global__ __launch_bounds__(512) void sa2_kernel(
    const float* __restrict__ pts, const float* __restrict__ centers,
    const int* __restrict__ gidx, const float* __restrict__ feats,
    const float* __restrict__ W0, const float* __restrict__ B0,
    const unsigned short* __restrict__ G0h, const unsigned short* __restrict__ G0l,
    const unsigned short* __restrict__ G1h, const unsigned short* __restrict__ G1l,
    const float* __restrict__ B1,
    const unsigned short* __restrict__ G2h, const unsigned short* __restrict__ G2l,
    const float* __restrict__ B2,
    float* __restrict__ fout) {
  constexpr int NTH = 512;
  constexpr int ROWS = M * GPB;                 // 128
  constexpr int NWV = NTH / 64;                 // 8
  static_assert(ROWS == 16 * NWV, "wave owns 16 rows");
  constexpr int MK1 = (FD > C1 ? FD : C1);
  constexpr int MAXK = (MK1 > C2 ? MK1 : C2);
  constexpr int AS = MAXK + 12;
  constexpr int WS = MAXK + 8;
  constexpr int CW = 128;
  __shared__ __align__(16) float A[ROWS * AS];
  __shared__ __align__(16) unsigned short Whi[CW * WS];
  __shared__ __align__(16) unsigned short Wlo[CW * WS];
  __shared__ float sxyz[ROWS * 4];
  __shared__ int idxs[ROWS];
  __shared__ float ctr[GPB][4];
  __shared__ float red[NWV][C3];

  const int t = threadIdx.x;
  const int blk = blockIdx.x;
  const int b = blk / (Q / GPB);
  const int q0 = (blk % (Q / GPB)) * GPB;
  const int l = t & 63, wv = t >> 6;

  if (t < GPB * 3) {
    int g = t / 3, c2 = t % 3;
    ctr[g][c2] = centers[((size_t)b * Q + q0 + g) * 3 + c2];
  }
  for (int m = t; m < ROWS; m += NTH)
    idxs[m] = gidx[((size_t)b * Q + q0 + (m / M)) * M + (m % M)];
  __syncthreads();
  const float* pb = pts + (size_t)b * NPTS * 3;
  // one-component-per-thread gather (3x memory parallelism)
  for (int u = t; u < ROWS * 3; u += NTH) {
    int m = u / 3, cmp = u - m * 3;
    int g = m / M, i = idxs[m];
    sxyz[m * 4 + cmp] = pb[i * 3 + cmp] - ctr[g][cmp];
  }
  {  // FD=128 gather
    const int m = t >> 2, co = (t & 3) * (FD / 4);
    const float* src = feats + ((size_t)b * NPTS + idxs[m]) * FD + co;
    float* dst = A + m * AS + co;
#pragma unroll
    for (int j = 0; j < FD / 4; j += 4)
      *reinterpret_cast<float4*>(dst + j) = *reinterpret_cast<const float4*>(src + j);
  }
  __syncthreads();

  f32x4 acc[C3 / 16];

  do_layer<FD, C1, CW, AS, WS, true, NTH>(G0h, G0l, W0, A, Whi, Wlo, sxyz, acc, t);
#pragma unroll
  for (int gt = 0; gt < C1 / 16; ++gt) {
    int col = gt * 16 + (l & 15);
    float bia = B0[col];
#pragma unroll
    for (int r = 0; r < 4; ++r)
      A[(wv * 16 + (l >> 4) * 4 + r) * AS + col] = fmaxf(acc[gt][r] + bia, 0.f);
  }

  do_layer<C1, C2, CW, AS, WS, false, NTH>(G1h, G1l, nullptr, A, Whi, Wlo, sxyz, acc, t);
#pragma unroll
  for (int gt = 0; gt < C2 / 16; ++gt) {
    int col = gt * 16 + (l & 15);
    float bia = B1[col];
#pragma unroll
    for (int r = 0; r < 4; ++r)
      A[(wv * 16 + (l >> 4) * 4 + r) * AS + col] = fmaxf(acc[gt][r] + bia, 0.f);
  }

  do_layer<C2, C3, CW, AS, WS, false, NTH>(G2h, G2l, nullptr, A, Whi, Wlo, sxyz, acc, t);
#pragma unroll
  for (int gt = 0; gt < C3 / 16; ++gt) {
    int col = gt * 16 + (l & 15);
    float v = fmaxf(fmaxf(acc[gt][0], acc[gt][1]), fmaxf(acc[gt][2], acc[gt][3]));
    v = fmaxf(v, __shfl_xor(v, 16, 64));
    v = fmaxf(v, __shfl_xor(v, 32, 64));
    if (l < 16) red[wv][col] = v + B2[col];
  }
  __syncthreads();
  constexpr int WPG = NWV / GPB;
  for (int u = t; u < GPB * C3; u += NTH) {
    int g = u / C3, c2 = u - g * C3;
    float v = red[g * WPG][c2];
#pragma unroll
    for (int w = 1; w < WPG; ++w) v = fmaxf(v, red[g * WPG + w][c2]);
    fout[((size_t)b * Q + q0 + g) * C3 + c2] = fmaxf(v, 0.f);
  }
}

// ---------------------------------------------------------------- SA1 body, grid-strided: stage W once, process TPB tiles
template<int NPTS, int Q, int M, int GPB, int TPB>
DEVINL void sa1_body(const float* __restrict__ pts, const float* __restrict__ centers,
                     const int* __restrict__ gidx,
                     const float* __restrict__ W0, const float* __restrict__ B0,
                     const unsigned short* __restrict__ G1h, const unsigned short* __restrict__ G1l,
                     const float* __restrict__ B1,
                     const unsigned short* __restrict__ G2h, const unsigned short* __restrict__ G2l,
                     const float* __restrict__ B2,
                     float* __restrict__ fout, int sblk, int t) {
  static_assert(M * GPB == 64, "");
  constexpr int C1 = 64, C2 = 64, C3 = 128;
  constexpr int AS = 76;
  constexpr int WS = 72;
  constexpr int NC = C2 + C3;
  __shared__ __align__(16) float A[64 * AS];
  __shared__ __align__(16) unsigned short Wh[NC * WS];
  __shared__ __align__(16) unsigned short Wl[NC * WS];
  __shared__ float sxyz[64 * 4];
  __shared__ int idxs[64];
  __shared__ float ctr[GPB][4];
  __shared__ float red[4][C3];

  const int l = t & 63, wv = t >> 6;

  for (int u = t; u < NC * 8; u += 256) {
    int col = u >> 3, k8 = (u & 7) * 8;
    const unsigned short* sh = (col < C2) ? G1h + (size_t)col * 64 + k8
                                          : G2h + (size_t)(col - C2) * 64 + k8;
    const unsigned short* sl = (col < C2) ? G1l + (size_t)col * 64 + k8
                                          : G2l + (size_t)(col - C2) * 64 + k8;
    *reinterpret_cast<u16x8*>(Wh + col * WS + k8) = *reinterpret_cast<const u16x8*>(sh);
    *reinterpret_cast<u16x8*>(Wl + col * WS + k8) = *reinterpret_cast<const u16x8*>(sl);
  }

  for (int it = 0; it < TPB; ++it) {
    const int blk = sblk * TPB + it;
    const int b = blk / (Q / GPB);
    const int q0 = (blk % (Q / GPB)) * GPB;

    if (t < GPB * 3) {
      int g = t / 3, c2 = t % 3;
      ctr[g][c2] = centers[((size_t)b * Q + q0 + g) * 3 + c2];
    }
    for (int m = t; m < 64; m += 256)
      idxs[m] = gidx[((size_t)b * Q + q0 + (m / M)) * M + (m % M)];
    __syncthreads();
    const float* pb = pts + (size_t)b * NPTS * 3;
    // one-component-per-thread gather (3x memory parallelism)
    for (int u = t; u < 64 * 3; u += 256) {
      int m = u / 3, cmp = u - m * 3;
      int g = m / M, i = idxs[m];
      sxyz[m * 4 + cmp] = pb[i * 3 + cmp] - ctr[g][cmp];
    }
    __syncthreads();

    for (int u = t; u < 64 * C1; u += 256) {
      int m = u / C1, c2 = u - m * C1;
      float v = B0[c2] + sxyz[m * 4 + 0] * W0[0 * C1 + c2]
                       + sxyz[m * 4 + 1] * W0[1 * C1 + c2]
                       + sxyz[m * 4 + 2] * W0[2 * C1 + c2];
      A[m * AS + c2] = fmaxf(v, 0.f);
    }
    __syncthreads();

    f32x4 acc[8];
    // ---- L2: 64 -> 64, W cols [0,64), barrier-free
    {
      bf16x8 ah[2], al[2];
      const float* ap = A + (wv * 16 + (l & 15)) * AS + (l >> 4) * 8;
#pragma unroll
      for (int kt = 0; kt < 2; ++kt) {
        float4 v0 = *reinterpret_cast<const float4*>(ap + kt * 32);
        float4 v1 = *reinterpret_cast<const float4*>(ap + kt * 32 + 4);
        float f[8] = {v0.x, v0.y, v0.z, v0.w, v1.x, v1.y, v1.z, v1.w};
        bf16x8 h, lo2;
#pragma unroll
        for (int j = 0; j < 8; ++j) {
          unsigned short hb = f2bh(f[j]);
          h[j] = (short)hb;
          lo2[j] = (short)f2bh(f[j] - bh2f(hb));
        }
        ah[kt] = h; al[kt] = lo2;
      }
#pragma unroll
      for (int i = 0; i < 4; ++i) acc[i] = f32x4{0.f, 0.f, 0.f, 0.f};
#pragma unroll
      for (int ct = 0; ct < 4; ++ct) {
        const unsigned short* wp = Wh + (ct * 16 + (l & 15)) * WS + (l >> 4) * 8;
        const unsigned short* wq = Wl + (ct * 16 + (l & 15)) * WS + (l >> 4) * 8;
        f32x4 a = acc[ct];
#pragma unroll
        for (int kt = 0; kt < 2; ++kt) {
          bf16x8 wh = *reinterpret_cast<const bf16x8*>(wp + kt * 32);
          bf16x8 wl = *reinterpret_cast<const bf16x8*>(wq + kt * 32);
          a = __builtin_amdgcn_mfma_f32_16x16x32_bf16(ah[kt], wh, a, 0, 0, 0);
          a = __builtin_amdgcn_mfma_f32_16x16x32_bf16(al[kt], wh, a, 0, 0, 0);
          a = __builtin_amdgcn_mfma_f32_16x16x32_bf16(ah[kt], wl, a, 0, 0, 0);
        }
        acc[ct] = a;
      }
#pragma unroll
      for (int gt = 0; gt < 4; ++gt) {
        int col = gt * 16 + (l & 15);
        float bia = B1[col];
#pragma unroll
        for (int r = 0; r < 4; ++r)
          A[(wv * 16 + (l >> 4) * 4 + r) * AS + col] = fmaxf(acc[gt][r] + bia, 0.f);
      }
    }

    // ---- L3: 64 -> 128, W cols [64,192), maxpool epilogue
    {
      bf16x8 ah[2], al[2];
      const float* ap = A + (wv * 16 + (l & 15)) * AS + (l >> 4) * 8;
#pragma unroll
      for (int kt = 0; kt < 2; ++kt) {
        float4 v0 = *reinterpret_cast<const float4*>(ap + kt * 32);
        float4 v1 = *reinterpret_cast<const float4*>(ap + kt * 32 + 4);
        float f[8] = {v0.x, v0.y, v0.z, v0.w, v1.x, v1.y, v1.z, v1.w};
        bf16x8 h, lo2;
#pragma unroll
        for (int j = 0; j < 8; ++j) {
          unsigned short hb = f2bh(f[j]);
          h[j] = (short)hb;
          lo2[j] = (short)f2bh(f[j] - bh2f(hb));
        }
        ah[kt] = h; al[kt] = lo2;
      }
#pragma unroll
      for (int i = 0; i < 8; ++i) acc[i] = f32x4{0.f, 0.f, 0.f, 0.f};
#pragma unroll
      for (int gt = 0; gt < 8; ++gt) {
        const unsigned short* wp = Wh + (C2 + gt * 16 + (l & 15)) * WS + (l >> 4) * 8;
        const unsigned short* wq = Wl + (C2 + gt * 16 + (l & 15)) * WS + (l >> 4) * 8;
        f32x4 a = acc[gt];
#pragma unroll
        for (int kt = 0; kt < 2; ++kt) {
          bf16x8 wh = *reinterpret_cast<const bf16x8*>(wp + kt * 32);
          bf16x8 wl = *reinterpret_cast<const bf16x8*>(wq + kt * 32);
          a = __builtin_amdgcn_mfma_f32_16x16x32_bf16(ah[kt], wh, a, 0, 0, 0);
          a = __builtin_amdgcn_mfma_f32_16x16x32_bf16(al[kt], wh, a, 0, 0, 0);
          a = __builtin_amdgcn_mfma_f32_16x16x32_bf16(ah[kt], wl, a, 0, 0, 0);
        }
        acc[gt] = a;
      }
#pragma unroll
      for (int gt = 0; gt < 8; ++gt) {
        int col = gt * 16 + (l & 15);
        float v = fmaxf(fmaxf(acc[gt][0], acc[gt][1]), fmaxf(acc[gt][2], acc[gt][3]));
        v = fmaxf(v, __shfl_xor(v, 16, 64));
        v = fmaxf(v, __shfl_xor(v, 32, 64));
        if (l < 16) red[wv][col] = v + B2[col];
      }
    }
    __syncthreads();
    constexpr int WPG = 4 / GPB;
    for (int u = t; u < GPB * C3; u += 256) {
      int g = u / C3, c2 = u - g * C3;
      float v = red[g * WPG][c2];
#pragma unroll
      for (int w = 1; w < WPG; ++w) v = fmaxf(v, red[g * WPG + w][c2]);
      fout[((size_t)b * Q + q0 + g) * C3 + c2] = fmaxf(v, 0.f);
    }
    __syncthreads();
  }
}

// [bq2 || sa1]
__global__ __launch_bounds__(256) void bq2_sa1_kernel(
    const float* __restrict__ xyz, const float* __restrict__ nx1,
    const float* __restrict__ nx2, int* __restrict__ gidx2, float r22,
    const int* __restrict__ gidx1,
    const float* __restrict__ s1w0, const float* __restrict__ s1b0,
    const unsigned short* __restrict__ g11h, const unsigned short* __restrict__ g11l,
    const float* __restrict__ s1b1,
    const unsigned short* __restrict__ g12h, const unsigned short* __restrict__ g12l,
    const float* __restrict__ s1b2, float* __restrict__ f1) {
  if (blockIdx.x < 1024) {
    bq_body<512, 64>(nx1, nx2, gidx2, 128, r22, blockIdx.x, threadIdx.x);
    return;
  }
  sa1_body<4096, 512, 32, 2, 8>(xyz, nx1, gidx1, s1w0, s1b0, g11h, g11l, s1b1,
                                g12h, g12l, s1b2, f1, blockIdx.x - 1024, threadIdx.x);
}

// ---------------------------------------------------------------- SA3 fused (512 threads / 8 waves)
constexpr int AS3 = 532;
DEVINL void sa3_frags(const float* __restrict__ A, int l, int KT, bf16x8* ahi, bf16x8* alo) {
  const float* ap = A + (l & 15) * AS3 + (l >> 4) * 8;
  for (int kt = 0; kt < KT; ++kt) {
    float4 v0 = *reinterpret_cast<const float4*>(ap + kt * 32);
    float4 v1 = *reinterpret_cast<const float4*>(ap + kt * 32 + 4);
    float f[8] = {v0.x, v0.y, v0.z, v0.w, v1.x, v1.y, v1.z, v1.w};
    bf16x8 h, lo2;
#pragma unroll
    for (int j = 0; j < 8; ++j) {
      unsigned short hb = f2bh(f[j]);
      h[j] = (short)hb;
      lo2[j] = (short)f2bh(f[j] - bh2f(hb));
    }
    ahi[kt] = h; alo[kt] = lo2;
  }
}

template<int CT, int K>
DEVINL void sa3_mmN(const unsigned short* __restrict__ Gh, const unsigned short* __restrict__ Gl,
                    int ncol0, int l, const bf16x8* ahi, const bf16x8* alo, f32x4* acc4) {
  constexpr int KT = K / 32;
#pragma unroll
  for (int ct = 0; ct < CT; ++ct) {
    const unsigned short* hp = Gh + (size_t)(ncol0 + ct * 16 + (l & 15)) * K + (l >> 4) * 8;
    const unsigned short* lp = Gl + (size_t)(ncol0 + ct * 16 + (l & 15)) * K + (l >> 4) * 8;
    f32x4 a = acc4[ct];
#pragma unroll
    for (int kt = 0; kt < KT; ++kt) {
      bf16x8 wh = *reinterpret_cast<const bf16x8*>(hp + kt * 32);
      bf16x8 wl = *reinterpret_cast<const bf16x8*>(lp + kt * 32);
      a = __builtin_amdgcn_mfma_f32_16x16x32_bf16(ahi[kt], wh, a, 0, 0, 0);
      a = __builtin_amdgcn_mfma_f32_16x16x32_bf16(alo[kt], wh, a, 0, 0, 0);
      a = __builtin_amdgcn_mfma_f32_16x16x32_bf16(ahi[kt], wl, a, 0, 0, 0);
    }
    acc4[ct] = a;
  }
}

__global__ __launch_bounds__(512) void sa3f_kernel(
    const float* __restrict__ nx2, const float* __restrict__ f2,
    const float* __restrict__ W0full,
    const unsigned short* __restrict__ G0h, const unsigned short* __restrict__ G0l,
    const float* __restrict__ B0,
    const unsigned short* __restrict__ G1h, const unsigned short* __restrict__ G1l,
    const float* __restrict__ B1,
    const unsigned short* __restrict__ G2h, const unsigned short* __restrict__ G2l,
    const float* __restrict__ B2,
    float* __restrict__ partial) {
  __shared__ __align__(16) float A[16 * AS3];
  __shared__ float sxyz[16][4];
  const int t = threadIdx.x, l = t & 63, w = t >> 6;  // w in 0..7
  const int b = blockIdx.x >> 3, rb = blockIdx.x & 7;
  const int row0 = rb * 16;
  {
    int r = t >> 5, cc = (t & 31) * 8;
    const float* src = f2 + ((size_t)b * 128 + row0 + r) * 256 + cc;
    float* dstp = A + r * AS3 + cc;
#pragma unroll
    for (int j = 0; j < 8; j += 4)
      *reinterpret_cast<float4*>(dstp + j) = *reinterpret_cast<const float4*>(src + j);
    if (t < 16) {
      const float* s = nx2 + ((size_t)b * 128 + row0 + t) * 3;
      sxyz[t][0] = s[0]; sxyz[t][1] = s[1]; sxyz[t][2] = s[2];
    }
  }
  __syncthreads();

  {  // L1: K=256 MFMA + xyz f32 correction -> N=256 (wave cols 32)
    bf16x8 ah[8], al[8];
    sa3_frags(A, l, 8, ah, al);
    __syncthreads();
    f32x4 acc[2];
#pragma unroll
    for (int i = 0; i < 2; ++i) acc[i] = f32x4{0.f, 0.f, 0.f, 0.f};
    sa3_mmN<2, 256>(G0h, G0l, w * 32, l, ah, al, acc);
    float xr[4][3];
#pragma unroll
    for (int r = 0; r < 4; ++r) {
      int row = (l >> 4) * 4 + r;
      xr[r][0] = sxyz[row][0]; xr[r][1] = sxyz[row][1]; xr[r][2] = sxyz[row][2];
    }
#pragma unroll
    for (int ct = 0; ct < 2; ++ct) {
      int col = w * 32 + ct * 16 + (l & 15);
      float w0 = W0full[col], w1 = W0full[256 + col], w2 = W0full[512 + col];
      float bia = B0[col];
#pragma unroll
      for (int r = 0; r < 4; ++r) {
        int row = (l >> 4) * 4 + r;
        float v = acc[ct][r] + xr[r][0] * w0 + xr[r][1] * w1 + xr[r][2] * w2 + bia;
        A[row * AS3 + col] = fmaxf(v, 0.f);
      }
    }
    __syncthreads();
  }

  {  // L2: K=256 -> N=512 (wave cols 64)
    bf16x8 ah[8], al[8];
    sa3_frags(A, l, 8, ah, al);
    __syncthreads();
    f32x4 acc[4];
#pragma unroll
    for (int i = 0; i < 4; ++i) acc[i] = f32x4{0.f, 0.f, 0.f, 0.f};
    sa3_mmN<4, 256>(G1h, G1l, w * 64, l, ah, al, acc);
#pragma unroll
    for (int cc = 0; cc < 4; ++cc) {
      int col = w * 64 + cc * 16 + (l & 15);
      float bia = B1[col];
#pragma unroll
      for (int r = 0; r < 4; ++r) {
        int row = (l >> 4) * 4 + r;
        A[row * AS3 + col] = fmaxf(acc[cc][r] + bia, 0.f);
      }
    }
    __syncthreads();
  }

  {  // L3: K=512 -> N=1024 (wave cols 128 = 2 subs x 64), maxpool -> partial
    bf16x8 ah[16], al[16];
    sa3_frags(A, l, 16, ah, al);
    float* pout = partial + ((size_t)(b * 8 + rb)) * 1024;
#pragma unroll
    for (int sub = 0; sub < 2; ++sub) {
      f32x4 acc[4];
#pragma unroll
      for (int i = 0; i < 4; ++i) acc[i] = f32x4{0.f, 0.f, 0.f, 0.f};
      sa3_mmN<4, 512>(G2h, G2l, w * 128 + sub * 64, l, ah, al, acc);
#pragma unroll
      for (int ct = 0; ct < 4; ++ct) {
        int col = w * 128 + sub * 64 + ct * 16 + (l & 15);
        float v = fmaxf(fmaxf(acc[ct][0], acc[ct][1]), fmaxf(acc[ct][2], acc[ct][3]));
        v = fmaxf(v, __shfl_xor(v, 16, 64));
        v = fmaxf(v, __shfl_xor(v, 32, 64));
        if (l < 16) pout[col] = v + B2[col];  // relu deferred to heads (monotone)
      }
    }
  }
}

// ---------------------------------------------------------------- heads (8-way partial max + relu + dots)
__global__ __launch_bounds__(256) void heads_kernel(const float* __restrict__ partial,
                                                    const float* __restrict__ cw,
                                                    const float* __restrict__ cb,
                                                    const float* __restrict__ rw,
                                                    const float* __restrict__ rb,
                                                    float* __restrict__ out) {
  const int b = blockIdx.x, t = threadIdx.x;
  const float* pb = partial + (size_t)b * 8 * 1024;
  float a0 = 0, a1 = 0, a2 = 0, a3 = 0, a4 = 0;
  for (int k = t; k < 1024; k += 256) {
    float m = pb[k];
#pragma unroll
    for (int p = 1; p < 8; ++p) m = fmaxf(m, pb[p * 1024 + k]);
    float f = fmaxf(m, 0.f);
    a0 += f * cw[k];
    const float* r = rw + (size_t)k * 4;
    a1 += f * r[0]; a2 += f * r[1]; a3 += f * r[2]; a4 += f * r[3];
  }
#pragma unroll
  for (int m = 32; m >= 1; m >>= 1) {
    a0 += __shfl_xor(a0, m, 64); a1 += __shfl_xor(a1, m, 64);
    a2 += __shfl_xor(a2, m, 64); a3 += __shfl_xor(a3, m, 64);
    a4 += __shfl_xor(a4, m, 64);
  }
  __shared__ float red[4][5];
  const int wv = t >> 6, ln = t & 63;
  if (ln == 0) { red[wv][0] = a0; red[wv][1] = a1; red[wv][2] = a2; red[wv][3] = a3; red[wv][4] = a4; }
  __syncthreads();
  if (t == 0) {
    float s0 = red[0][0] + red[1][0] + red[2][0] + red[3][0];
    float s1 = red[0][1] + red[1][1] + red[2][1] + red[3][1];
    float s2 = red[0][2] + red[1][2] + red[2][2] + red[3][2];
    float s3 = red[0][3] + red[1][3] + red[2][3] + red[3][3];
    float s4 = red[0][4] + red[1][4] + red[2][4] + red[3][4];
    out[b] = s0 + cb[0];
    out[32 + b * 4 + 0] = s1 + rb[0];
    out[32 + b * 4 + 1] = s2 + rb[1];
    out[32 + b * 4 + 2] = s3 + rb[2];
    out[32 + b * 4 + 3] = s4 + rb[3];
  }
}

// ---------------------------------------------------------------- launch
extern "C" void kernel_launch(void* const* d_in, const int* in_sizes, int n_in,
                              void* d_out, int out_size, void* d_ws, size_t ws_size,
                              hipStream_t stream) {
  (void)in_sizes; (void)n_in; (void)out_size; (void)ws_size;
  const float* xyz  = (const float*)d_in[0];
  const float* s1w0 = (const float*)d_in[1];  const float* s1b0 = (const float*)d_in[2];
  const float* s1w1 = (const float*)d_in[3];  const float* s1b1 = (const float*)d_in[4];
  const float* s1w2 = (const float*)d_in[5];  const float* s1b2 = (const float*)d_in[6];
  const float* s2w0 = (const float*)d_in[7];  const float* s2b0 = (const float*)d_in[8];
  const float* s2w1 = (const float*)d_in[9];  const float* s2b1 = (const float*)d_in[10];
  const float* s2w2 = (const float*)d_in[11]; const float* s2b2 = (const float*)d_in[12];
  const float* s3w0 = (const float*)d_in[13]; const float* s3b0 = (const float*)d_in[14];
  const float* s3w1 = (const float*)d_in[15]; const float* s3b1 = (const float*)d_in[16];
  const float* s3w2 = (const float*)d_in[17]; const float* s3b2 = (const float*)d_in[18];
  const float* clsw = (const float*)d_in[19]; const float* clsb = (const float*)d_in[20];
  const float* regw = (const float*)d_in[21]; const float* regb = (const float*)d_in[22];

  char* ws = (char*)d_ws;
  float* nx1   = (float*)(ws + 0);          // 32*512*3
  int*   gidx1 = (int*)  (ws + 196608);     // 32*512*32
  float* f1    = (float*)(ws + 2293760);    // 32*512*128
  float* nx2   = (float*)(ws + 10682368);   // 32*128*3
  int*   gidx2 = (int*)  (ws + 10731520);   // 32*128*64
  float* f2    = (float*)(ws + 11780096);   // 32*128*256

  // SA1/SA2 prepped weights (u16 hi/lo, transposed [n][k])
  unsigned short* wt = (unsigned short*)(ws + 20168704);
  unsigned short* g11h = wt;            // 64*64
  unsigned short* g11l = wt + 4096;
  unsigned short* g12h = wt + 8192;     // 128*64
  unsigned short* g12l = wt + 16384;
  unsigned short* g20h = wt + 24576;    // 128*128 (rows 3..130 of s2w0)
  unsigned short* g20l = wt + 40960;
  unsigned short* g21h = wt + 57344;    // 128*128
  unsigned short* g21l = wt + 73728;
  unsigned short* g22h = wt + 90112;    // 256*128
  unsigned short* g22l = wt + 122880;   // ends at byte 20168704+311296 = 20480000
  // SA3 prepped weights
  unsigned short* g30h = (unsigned short*)(ws + 20480000);  // 256x256
  unsigned short* g30l = (unsigned short*)(ws + 20611072);
  unsigned short* g31h = (unsigned short*)(ws + 20742144);  // 512x256
  unsigned short* g31l = (unsigned short*)(ws + 21004288);
  unsigned short* g32h = (unsigned short*)(ws + 21266432);  // 1024x512
  unsigned short* g32l = (unsigned short*)(ws + 22315008);
  float* partial = (float*)(ws + 23363584);                 // 32*8*1024 f32 -> ends 24412160

  const float r21 = (float)(0.2 * 0.2);
  const float r22 = (float)(0.4 * 0.4);

  WPTab tab;
  int off = 0;
  auto set = [&](int i, const float* W, unsigned short* hi, unsigned short* lo,
                 int K, int N, int row0) {
    tab.e[i] = WPEnt{W, hi, lo, K, N, row0, off, off + K * N};
    off += K * N;
  };
  set(0, s1w1, g11h, g11l, 64, 64, 0);
  set(1, s1w2, g12h, g12l, 64, 128, 0);
  set(2, s2w0, g20h, g20l, 128, 128, 3);
  set(3, s2w1, g21h, g21l, 128, 128, 0);
  set(4, s2w2, g22h, g22l, 128, 256, 0);
  set(5, s3w0, g30h, g30l, 256, 256, 3);
  set(6, s3w1, g31h, g31l, 256, 512, 0);
  set(7, s3w2, g32h, g32l, 512, 1024, 0);
  const int wblocks = (off + 255) / 256;

  fps1_wprep_kernel<<<32 + wblocks, 256, 0, stream>>>(xyz, nx1, tab);
  fps2_bq1_kernel<<<32 + 4096, 256, 0, stream>>>(xyz, nx1, gidx1, nx2, r21);
  bq2_sa1_kernel<<<1024 + 1024, 256, 0, stream>>>(
      xyz, nx1, nx2, gidx2, r22, gidx1,
      s1w0, s1b0, g11h, g11l, s1b1, g12h, g12l, s1b2, f1);
  sa2_kernel<512, 128, 64, 2, 128, 128, 128, 256><<<2048, 512, 0, stream>>>(
      nx1, nx2, gidx2, f1, s2w0, s2b0,
      g20h, g20l, g21h, g21l, s2b1, g22h, g22l, s2b2, f2);
  sa3f_kernel<<<256, 512, 0, stream>>>(nx2, f2, s3w0, g30h, g30l, s3b0,
                                       g31h, g31l, s3b1, g32h, g32l, s3b2, partial);
  heads_kernel<<<32, 256, 0, stream>>>(partial, clsw, clsb, regw, regb, (float*)d_out);
}

// Round 17
// 637.833 us; speedup vs baseline: 1.1468x; 1.0095x over previous
//
#include <hip/hip_runtime.h>
#include <hip/hip_bf16.h>

#define DEVINL __device__ __forceinline__

typedef __attribute__((ext_vector_type(8))) short bf16x8;
typedef __attribute__((ext_vector_type(8))) unsigned short u16x8;
typedef __attribute__((ext_vector_type(4))) float f32x4;

// f32 -> bf16 bits via the NATIVE cast (RNE): hardware v_cvt_pk_bf16_f32.
DEVINL unsigned short f2bh(float f){
  __hip_bfloat16 h = __float2bfloat16(f);
  return __bfloat16_as_ushort(h);
}
DEVINL float bh2f(unsigned short h){ return __uint_as_float(((unsigned)h) << 16); }

// Wave64 max-reduce of a u64 key via DPP (VALU latency, no DS pipe).
DEVINL unsigned long long dpp_max_u64(unsigned long long k) {
#define DPP_STEP(ctrl)                                                        \
  {                                                                           \
    int hi = (int)(k >> 32), lo = (int)(unsigned)k;                           \
    int oh = __builtin_amdgcn_update_dpp(0, hi, ctrl, 0xF, 0xF, 1);           \
    int ol = __builtin_amdgcn_update_dpp(0, lo, ctrl, 0xF, 0xF, 1);           \
    unsigned long long ok =                                                   \
        ((unsigned long long)(unsigned)oh << 32) | (unsigned)ol;              \
    if (ok > k) k = ok;                                                       \
  }
  DPP_STEP(0x111)  // row_shr:1
  DPP_STEP(0x112)  // row_shr:2
  DPP_STEP(0x114)  // row_shr:4
  DPP_STEP(0x118)  // row_shr:8
  DPP_STEP(0x142)  // row_bcast:15
  DPP_STEP(0x143)  // row_bcast:31
#undef DPP_STEP
  return k;
}

// ---------------------------------------------------------------- FPS body (R4-proven, LOCKED)
template<int N, int NP, int NT>
DEVINL void fps_body(const float* __restrict__ xyz, float* __restrict__ nxyz,
                     int b, int t) {
  constexpr int PTS = N / NT;
  constexpr int NW = NT / 64;
  __shared__ float xs[N], ys[N], zs[N];
  __shared__ int farr[NP];
  __shared__ unsigned long long sk[2][(NW > 1 ? NW : 1)];
  float px[PTS], py[PTS], pz[PTS], dst[PTS];
  const float* base = xyz + (size_t)b * N * 3;
#pragma unroll
  for (int j = 0; j < PTS; ++j) {
    int i = t + j * NT;
    float x = base[i * 3 + 0], y = base[i * 3 + 1], z = base[i * 3 + 2];
    px[j] = x; py[j] = y; pz[j] = z;
    xs[i] = x; ys[i] = y; zs[i] = z;
    dst[j] = 1e10f;
  }
  if constexpr (NW > 1) __syncthreads();
  int far = 0;
  const int wv = t >> 6, ln = t & 63;
  for (int s = 0; s < NP; ++s) {
    float cx = xs[far], cy = ys[far], cz = zs[far];
    if (t == 0) farr[s] = far;
    float bv = -1.f; int bi = 0;
#pragma unroll
    for (int j = 0; j < PTS; ++j) {
      // no-fma, left-to-right: matches numpy elementwise + sum order
      float dx = __fsub_rn(px[j], cx), dy = __fsub_rn(py[j], cy), dz = __fsub_rn(pz[j], cz);
      float d = __fadd_rn(__fadd_rn(__fmul_rn(dx, dx), __fmul_rn(dy, dy)), __fmul_rn(dz, dz));
      float nd = fminf(dst[j], d);
      dst[j] = nd;
      int i = t + j * NT;
      if (nd > bv) { bv = nd; bi = i; }  // strict >: first max kept per thread
    }
    // pack: max key == max dist, tie -> larger ~idx == smaller idx
    unsigned long long key =
        ((unsigned long long)__float_as_uint(bv) << 32) | (unsigned)(~bi);
    key = dpp_max_u64(key);
    if constexpr (NW == 1) {
      int rl = __builtin_amdgcn_readlane((int)(unsigned)key, 63);
      far = (int)(~(unsigned)rl);
    } else {
      const int p = s & 1;
      if (ln == 63) sk[p][wv] = key;
      __syncthreads();
      unsigned long long m = sk[p][0];
#pragma unroll
      for (int q = 1; q < NW; ++q) {
        unsigned long long qk = sk[p][q];
        if (qk > m) m = qk;
      }
      far = (int)(~(unsigned)m);
    }
  }
  if constexpr (NW > 1) __syncthreads();
  for (int s2 = t; s2 < NP; s2 += NT) {
    int fi = farr[s2];
    float* o = nxyz + ((size_t)b * NP + s2) * 3;
    o[0] = xs[fi]; o[1] = ys[fi]; o[2] = zs[fi];
  }
}

// ---------------------------------------------------------------- ball query body (pipelined)
template<int N, int NS>
DEVINL void bq_body(const float* __restrict__ pts, const float* __restrict__ centers,
                    int* __restrict__ gidx, int Q, float r2, int blk, int t) {
  const int wv = t >> 6, ln = t & 63;
  const int g = blk * 4 + wv;
  const int b = g / Q, q = g % Q;
  const float* pb = pts + (size_t)b * N * 3;
  const float* c = centers + ((size_t)b * Q + q) * 3;
  const float cx = c[0], cy = c[1], cz = c[2];
  __shared__ int gbuf[4][NS];
  float nx = pb[ln * 3 + 0], ny = pb[ln * 3 + 1], nz = pb[ln * 3 + 2];
  int taken = 0;
  for (int base = 0; base < N; base += 64) {
    const float x = nx, y = ny, z = nz;
    if (base + 64 < N) {
      const float* np = pb + (size_t)(base + 64 + ln) * 3;
      nx = np[0]; ny = np[1]; nz = np[2];
    }
    int i = base + ln;
    float dx = __fsub_rn(x, cx), dy = __fsub_rn(y, cy), dz = __fsub_rn(z, cz);
    float d = __fadd_rn(__fadd_rn(__fmul_rn(dx, dx), __fmul_rn(dy, dy)), __fmul_rn(dz, dz));
    bool in = (d <= r2);
    unsigned long long mk = __ballot(in);
    int rank = __popcll(mk & ((1ull << ln) - 1ull));
    int pos = taken + rank;
    if (in && pos < NS) gbuf[wv][pos] = i;
    taken += (int)__popcll(mk);
    if (taken >= NS) break;
  }
  int total = taken < NS ? taken : NS;
  int first = gbuf[wv][0];
  int* out = gidx + ((size_t)b * Q + q) * NS;
  for (int j = ln; j < NS; j += 64) out[j] = (j < total) ? gbuf[wv][j] : first;
}

// ---------------------------------------------------------------- weight prep body
struct WPEnt { const float* W; unsigned short* hi; unsigned short* lo; int K, N, row0, beg, end; };
struct WPTab { WPEnt e[8]; };
DEVINL void wprep_body(const WPTab& tab, int idx) {
#pragma unroll
  for (int i = 0; i < 8; ++i) {
    const WPEnt& E = tab.e[i];
    if (idx >= E.beg && idx < E.end) {
      int local = idx - E.beg;
      int k = local / E.N, n = local - k * E.N;
      float v = E.W[(size_t)(E.row0 + k) * E.N + n];
      unsigned short h = f2bh(v);
      E.hi[(size_t)n * E.K + k] = h;
      E.lo[(size_t)n * E.K + k] = f2bh(v - bh2f(h));
    }
  }
}

// ---------------------------------------------------------------- fused launches
// [fps1 || wprep]
__global__ __launch_bounds__(256) void fps1_wprep_kernel(const float* __restrict__ xyz,
                                                         float* __restrict__ nx1, WPTab tab) {
  if (blockIdx.x < 32) { fps_body<4096, 512, 256>(xyz, nx1, blockIdx.x, threadIdx.x); return; }
  wprep_body(tab, (blockIdx.x - 32) * 256 + threadIdx.x);
}

// [fps2 || bq1]: fps2 as single wave (barrier-free); waves 1-3 retire.
__global__ __launch_bounds__(256) void fps2_bq1_kernel(const float* __restrict__ xyz,
                                                       const float* __restrict__ nx1,
                                                       int* __restrict__ gidx1,
                                                       float* __restrict__ nx2, float r21) {
  if (blockIdx.x < 32) {
    if (threadIdx.x < 64) fps_body<512, 128, 64>(nx1, nx2, blockIdx.x, threadIdx.x);
    return;
  }
  bq_body<4096, 32>(xyz, nx1, gidx1, 512, r21, blockIdx.x - 32, threadIdx.x);
}

// ---------------------------------------------------------------- split-bf16 MFMA layer (CW-col chunks, A from LDS)
template<int K, int N, int CW, int AS, int WS, int NTH>
DEVINL void do_layer(const unsigned short* __restrict__ Ghi, const unsigned short* __restrict__ Glo,
                     const float* __restrict__ A, unsigned short* __restrict__ Whi,
                     unsigned short* __restrict__ Wlo, f32x4* acc, int t) {
  constexpr int KT = K / 32;
  constexpr int NCH = N / CW;
  constexpr int K8 = K / 8;
  constexpr int SI = (CW * K8) / NTH;
  constexpr int CT = CW / 16;
  const int l = t & 63, wv = t >> 6;

  u16x8 rh[SI], rl[SI];
#pragma unroll
  for (int s = 0; s < SI; ++s) {
    int u = t + s * NTH;
    int nn = u / K8, k8 = (u - nn * K8) * 8;
    rh[s] = *reinterpret_cast<const u16x8*>(Ghi + (size_t)nn * K + k8);
    rl[s] = *reinterpret_cast<const u16x8*>(Glo + (size_t)nn * K + k8);
  }

  bf16x8 ahi[KT], alo[KT];
  {
    const int row = wv * 16 + (l & 15);
    const float* ap = A + row * AS + (l >> 4) * 8;
#pragma unroll
    for (int kt = 0; kt < KT; ++kt) {
      float4 v0 = *reinterpret_cast<const float4*>(ap + kt * 32);
      float4 v1 = *reinterpret_cast<const float4*>(ap + kt * 32 + 4);
      float f[8] = {v0.x, v0.y, v0.z, v0.w, v1.x, v1.y, v1.z, v1.w};
      bf16x8 h, lo2;
#pragma unroll
      for (int j = 0; j < 8; ++j) {
        unsigned short hb = f2bh(f[j]);
        h[j] = (short)hb;
        lo2[j] = (short)f2bh(f[j] - bh2f(hb));
      }
      ahi[kt] = h; alo[kt] = lo2;
    }
  }
#pragma unroll
  for (int i = 0; i < N / 16; ++i) acc[i] = f32x4{0.f, 0.f, 0.f, 0.f};

#pragma unroll
  for (int c = 0; c < NCH; ++c) {
    __syncthreads();  // all waves done reading previous W contents
#pragma unroll
    for (int s = 0; s < SI; ++s) {
      int u = t + s * NTH;
      int nn = u / K8, k8 = (u - nn * K8) * 8;
      *reinterpret_cast<u16x8*>(Whi + nn * WS + k8) = rh[s];
      *reinterpret_cast<u16x8*>(Wlo + nn * WS + k8) = rl[s];
    }
    if (c + 1 < NCH) {
#pragma unroll
      for (int s = 0; s < SI; ++s) {
        int u = t + s * NTH;
        int nn = u / K8, k8 = (u - nn * K8) * 8;
        rh[s] = *reinterpret_cast<const u16x8*>(Ghi + (size_t)((c + 1) * CW + nn) * K + k8);
        rl[s] = *reinterpret_cast<const u16x8*>(Glo + (size_t)((c + 1) * CW + nn) * K + k8);
      }
    }
    __syncthreads();
#pragma unroll
    for (int ct = 0; ct < CT; ++ct) {
      const unsigned short* wp = Whi + (ct * 16 + (l & 15)) * WS + (l >> 4) * 8;
      const unsigned short* wq = Wlo + (ct * 16 + (l & 15)) * WS + (l >> 4) * 8;
      f32x4 a = acc[c * CT + ct];
#pragma unroll
      for (int kt = 0; kt < KT; ++kt) {
        bf16x8 wh = *reinterpret_cast<const bf16x8*>(wp + kt * 32);
        bf16x8 wl = *reinterpret_cast<const bf16x8*>(wq + kt * 32);
        a = __builtin_amdgcn_mfma_f32_16x16x32_bf16(ahi[kt], wh, a, 0, 0, 0);
        a = __builtin_amdgcn_mfma_f32_16x16x32_bf16(alo[kt], wh, a, 0, 0, 0);
        a = __builtin_amdgcn_mfma_f32_16x16x32_bf16(ahi[kt], wl, a, 0, 0, 0);
      }
      acc[c * CT + ct] = a;
    }
  }
}

// ---------------------------------------------------------------- layer0 variant: A hi/lo fragments gathered DIRECT from
// global (f1 stored pre-split by sa1) -- no LDS staging, no cvt on A path.
// MFMA inputs bit-identical to the staged+split version.
template<int K, int N, int CW, int WS, int NTH>
DEVINL void do_layer0_gather(const unsigned short* __restrict__ Ghi,
                             const unsigned short* __restrict__ Glo,
                             const float* __restrict__ Wxyz,
                             const unsigned short* __restrict__ f1h,  // batch-offset
                             const unsigned short* __restrict__ f1l,
                             const int* __restrict__ idxs, const float* __restrict__ sxyz,
                             unsigned short* __restrict__ Whi, unsigned short* __restrict__ Wlo,
                             f32x4* acc, int t) {
  constexpr int KT = K / 32;
  constexpr int NCH = N / CW;
  constexpr int K8 = K / 8;
  constexpr int SI = (CW * K8) / NTH;
  constexpr int CT = CW / 16;
  const int l = t & 63, wv = t >> 6;

  u16x8 rh[SI], rl[SI];
#pragma unroll
  for (int s = 0; s < SI; ++s) {
    int u = t + s * NTH;
    int nn = u / K8, k8 = (u - nn * K8) * 8;
    rh[s] = *reinterpret_cast<const u16x8*>(Ghi + (size_t)nn * K + k8);
    rl[s] = *reinterpret_cast<const u16x8*>(Glo + (size_t)nn * K + k8);
  }

  bf16x8 ahi[KT], alo[KT];
  {
    const int row = wv * 16 + (l & 15);
    const int i = idxs[row];
    const unsigned short* hp = f1h + (size_t)i * K + (l >> 4) * 8;
    const unsigned short* lp = f1l + (size_t)i * K + (l >> 4) * 8;
#pragma unroll
    for (int kt = 0; kt < KT; ++kt) {
      ahi[kt] = *reinterpret_cast<const bf16x8*>(hp + kt * 32);
      alo[kt] = *reinterpret_cast<const bf16x8*>(lp + kt * 32);
    }
  }
#pragma unroll
  for (int i = 0; i < N / 16; ++i) acc[i] = f32x4{0.f, 0.f, 0.f, 0.f};

#pragma unroll
  for (int c = 0; c < NCH; ++c) {
    __syncthreads();
#pragma unroll
    for (int s = 0; s < SI; ++s) {
      int u = t + s * NTH;
      int nn = u / K8, k8 = (u - nn * K8) * 8;
      *reinterpret_cast<u16x8*>(Whi + nn * WS + k8) = rh[s];
      *reinterpret_cast<u16x8*>(Wlo + nn * WS + k8) = rl[s];
    }
    if (c + 1 < NCH) {
#pragma unroll
      for (int s = 0; s < SI; ++s) {
        int u = t + s * NTH;
        int nn = u / K8, k8 = (u - nn * K8) * 8;
        rh[s] = *reinterpret_cast<const u16x8*>(Ghi + (size_t)((c + 1) * CW + nn) * K + k8);
        rl[s] = *reinterpret_cast<const u16x8*>(Glo + (size_t)((c + 1) * CW + nn) * K + k8);
      }
    }
    __syncthreads();
#pragma unroll
    for (int ct = 0; ct < CT; ++ct) {
      const unsigned short* wp = Whi + (ct * 16 + (l & 15)) * WS + (l >> 4) * 8;
      const unsigned short* wq = Wlo + (ct * 16 + (l & 15)) * WS + (l >> 4) * 8;
      f32x4 a = acc[c * CT + ct];
#pragma unroll
      for (int kt = 0; kt < KT; ++kt) {
        bf16x8 wh = *reinterpret_cast<const bf16x8*>(wp + kt * 32);
        bf16x8 wl = *reinterpret_cast<const bf16x8*>(wq + kt * 32);
        a = __builtin_amdgcn_mfma_f32_16x16x32_bf16(ahi[kt], wh, a, 0, 0, 0);
        a = __builtin_amdgcn_mfma_f32_16x16x32_bf16(alo[kt], wh, a, 0, 0, 0);
        a = __builtin_amdgcn_mfma_f32_16x16x32_bf16(ahi[kt], wl, a, 0, 0, 0);
      }
      acc[c * CT + ct] = a;
    }
  }
  {  // exact f32 xyz correction (W rows 0..2)
    float xr[4][3];
#pragma unroll
    for (int r = 0; r < 4; ++r) {
      int row = wv * 16 + (l >> 4) * 4 + r;
      xr[r][0] = sxyz[row * 4 + 0];
      xr[r][1] = sxyz[row * 4 + 1];
      xr[r][2] = sxyz[row * 4 + 2];
    }
#pragma unroll
    for (int gt = 0; gt < N / 16; ++gt) {
      int col = gt * 16 + (l & 15);
      float w0 = Wxyz[col], w1 = Wxyz[N + col], w2 = Wxyz[2 * N + col];
#pragma unroll
      for (int r = 0; r < 4; ++r)
        acc[gt][r] += xr[r][0] * w0 + xr[r][1] * w1 + xr[r][2] * w2;
    }
  }
}

// ---------------------------------------------------------------- SA2 fused, 512 threads / 128 rows, 128-col chunks
template<int NPTS, int Q, int M, int GPB, int FD, int C1, int C2, int C3>
__global__ __launch_bounds__(512) void sa2_kernel(
    const float* __restrict__ pts, const float* __restrict__ centers,
    const int* __restrict__ gidx,
    const unsigned short* __restrict__ f1h, const unsigned short* __restrict__ f1l,
    const float* __restrict__ W0, const float* __restrict__ B0,
    const unsigned short* __restrict__ G0h, const unsigned short* __restrict__ G0l,
    const unsigned short* __restrict__ G1h, const unsigned short* __restrict__ G1l,
    const float* __restrict__ B1,
    const unsigned short* __restrict__ G2h, const unsigned short* __restrict__ G2l,
    const float* __restrict__ B2,
    float* __restrict__ fout) {
  constexpr int NTH = 512;
  constexpr int ROWS = M * GPB;                 // 128
  constexpr int NWV = NTH / 64;                 // 8
  static_assert(ROWS == 16 * NWV, "wave owns 16 rows");
  constexpr int MAXK = (C1 > C2 ? C1 : C2);
  constexpr int AS = MAXK + 12;
  constexpr int WS = MAXK + 8;
  constexpr int CW = 128;
  __shared__ __align__(16) float A[ROWS * AS];
  __shared__ __align__(16) unsigned short Whi[CW * WS];
  __shared__ __align__(16) unsigned short Wlo[CW * WS];
  __shared__ float sxyz[ROWS * 4];
  __shared__ int idxs[ROWS];
  __shared__ float ctr[GPB][4];
  __shared__ float red[NWV][C3];

  const int t = threadIdx.x;
  const int blk = blockIdx.x;
  const int b = blk / (Q / GPB);
  const int q0 = (blk % (Q / GPB)) * GPB;
  const int l = t & 63, wv = t >> 6;

  if (t < GPB * 3) {
    int g = t / 3, c2 = t % 3;
    ctr[g][c2] = centers[((size_t)b * Q + q0 + g) * 3 + c2];
  }
  for (int m = t; m < ROWS; m += NTH)
    idxs[m] = gidx[((size_t)b * Q + q0 + (m / M)) * M + (m % M)];
  __syncthreads();
  const float* pb = pts + (size_t)b * NPTS * 3;
  // one-component-per-thread gather (3x memory parallelism)
  for (int u = t; u < ROWS * 3; u += NTH) {
    int m = u / 3, cmp = u - m * 3;
    int g = m / M, i = idxs[m];
    sxyz[m * 4 + cmp] = pb[i * 3 + cmp] - ctr[g][cmp];
  }
  __syncthreads();

  f32x4 acc[C3 / 16];

  // layer0: A frags direct-gathered from pre-split f1 (no LDS staging)
  do_layer0_gather<FD, C1, CW, WS, NTH>(
      G0h, G0l, W0, f1h + (size_t)b * NPTS * FD, f1l + (size_t)b * NPTS * FD,
      idxs, sxyz, Whi, Wlo, acc, t);
#pragma unroll
  for (int gt = 0; gt < C1 / 16; ++gt) {
    int col = gt * 16 + (l & 15);
    float bia = B0[col];
#pragma unroll
    for (int r = 0; r < 4; ++r)
      A[(wv * 16 + (l >> 4) * 4 + r) * AS + col] = fmaxf(acc[gt][r] + bia, 0.f);
  }

  do_layer<C1, C2, CW, AS, WS, NTH>(G1h, G1l, A, Whi, Wlo, acc, t);
#pragma unroll
  for (int gt = 0; gt < C2 / 16; ++gt) {
    int col = gt * 16 + (l & 15);
    float bia = B1[col];
#pragma unroll
    for (int r = 0; r < 4; ++r)
      A[(wv * 16 + (l >> 4) * 4 + r) * AS + col] = fmaxf(acc[gt][r] + bia, 0.f);
  }

  do_layer<C2, C3, CW, AS, WS, NTH>(G2h, G2l, A, Whi, Wlo, acc, t);
#pragma unroll
  for (int gt = 0; gt < C3 / 16; ++gt) {
    int col = gt * 16 + (l & 15);
    float v = fmaxf(fmaxf(acc[gt][0], acc[gt][1]), fmaxf(acc[gt][2], acc[gt][3]));
    v = fmaxf(v, __shfl_xor(v, 16, 64));
    v = fmaxf(v, __shfl_xor(v, 32, 64));
    if (l < 16) red[wv][col] = v + B2[col];
  }
  __syncthreads();
  constexpr int WPG = NWV / GPB;
  for (int u = t; u < GPB * C3; u += NTH) {
    int g = u / C3, c2 = u - g * C3;
    float v = red[g * WPG][c2];
#pragma unroll
    for (int w = 1; w < WPG; ++w) v = fmaxf(v, red[g * WPG + w][c2]);
    fout[((size_t)b * Q + q0 + g) * C3 + c2] = fmaxf(v, 0.f);
  }
}

// ---------------------------------------------------------------- SA1 body, grid-strided; f1 written PRE-SPLIT (hi/lo bf16)
template<int NPTS, int Q, int M, int GPB, int TPB>
DEVINL void sa1_body(const float* __restrict__ pts, const float* __restrict__ centers,
                     const int* __restrict__ gidx,
                     const float* __restrict__ W0, const float* __restrict__ B0,
                     const unsigned short* __restrict__ G1h, const unsigned short* __restrict__ G1l,
                     const float* __restrict__ B1,
                     const unsigned short* __restrict__ G2h, const unsigned short* __restrict__ G2l,
                     const float* __restrict__ B2,
                     unsigned short* __restrict__ f1h, unsigned short* __restrict__ f1l,
                     int sblk, int t) {
  static_assert(M * GPB == 64, "");
  constexpr int C1 = 64, C2 = 64, C3 = 128;
  constexpr int AS = 76;
  constexpr int WS = 72;
  constexpr int NC = C2 + C3;
  __shared__ __align__(16) float A[64 * AS];
  __shared__ __align__(16) unsigned short Wh[NC * WS];
  __shared__ __align__(16) unsigned short Wl[NC * WS];
  __shared__ float sxyz[64 * 4];
  __shared__ int idxs[64];
  __shared__ float ctr[GPB][4];
  __shared__ float red[4][C3];

  const int l = t & 63, wv = t >> 6;

  for (int u = t; u < NC * 8; u += 256) {
    int col = u >> 3, k8 = (u & 7) * 8;
    const unsigned short* sh = (col < C2) ? G1h + (size_t)col * 64 + k8
                                          : G2h + (size_t)(col - C2) * 64 + k8;
    const unsigned short* sl = (col < C2) ? G1l + (size_t)col * 64 + k8
                                          : G2l + (size_t)(col - C2) * 64 + k8;
    *reinterpret_cast<u16x8*>(Wh + col * WS + k8) = *reinterpret_cast<const u16x8*>(sh);
    *reinterpret_cast<u16x8*>(Wl + col * WS + k8) = *reinterpret_cast<const u16x8*>(sl);
  }

  for (int it = 0; it < TPB; ++it) {
    const int blk = sblk * TPB + it;
    const int b = blk / (Q / GPB);
    const int q0 = (blk % (Q / GPB)) * GPB;

    if (t < GPB * 3) {
      int g = t / 3, c2 = t % 3;
      ctr[g][c2] = centers[((size_t)b * Q + q0 + g) * 3 + c2];
    }
    for (int m = t; m < 64; m += 256)
      idxs[m] = gidx[((size_t)b * Q + q0 + (m / M)) * M + (m % M)];
    __syncthreads();
    const float* pb = pts + (size_t)b * NPTS * 3;
    for (int u = t; u < 64 * 3; u += 256) {
      int m = u / 3, cmp = u - m * 3;
      int g = m / M, i = idxs[m];
      sxyz[m * 4 + cmp] = pb[i * 3 + cmp] - ctr[g][cmp];
    }
    __syncthreads();

    for (int u = t; u < 64 * C1; u += 256) {
      int m = u / C1, c2 = u - m * C1;
      float v = B0[c2] + sxyz[m * 4 + 0] * W0[0 * C1 + c2]
                       + sxyz[m * 4 + 1] * W0[1 * C1 + c2]
                       + sxyz[m * 4 + 2] * W0[2 * C1 + c2];
      A[m * AS + c2] = fmaxf(v, 0.f);
    }
    __syncthreads();

    f32x4 acc[8];
    // ---- L2: 64 -> 64, W cols [0,64), barrier-free
    {
      bf16x8 ah[2], al[2];
      const float* ap = A + (wv * 16 + (l & 15)) * AS + (l >> 4) * 8;
#pragma unroll
      for (int kt = 0; kt < 2; ++kt) {
        float4 v0 = *reinterpret_cast<const float4*>(ap + kt * 32);
        float4 v1 = *reinterpret_cast<const float4*>(ap + kt * 32 + 4);
        float f[8] = {v0.x, v0.y, v0.z, v0.w, v1.x, v1.y, v1.z, v1.w};
        bf16x8 h, lo2;
#pragma unroll
        for (int j = 0; j < 8; ++j) {
          unsigned short hb = f2bh(f[j]);
          h[j] = (short)hb;
          lo2[j] = (short)f2bh(f[j] - bh2f(hb));
        }
        ah[kt] = h; al[kt] = lo2;
      }
#pragma unroll
      for (int i = 0; i < 4; ++i) acc[i] = f32x4{0.f, 0.f, 0.f, 0.f};
#pragma unroll
      for (int ct = 0; ct < 4; ++ct) {
        const unsigned short* wp = Wh + (ct * 16 + (l & 15)) * WS + (l >> 4) * 8;
        const unsigned short* wq = Wl + (ct * 16 + (l & 15)) * WS + (l >> 4) * 8;
        f32x4 a = acc[ct];
#pragma unroll
        for (int kt = 0; kt < 2; ++kt) {
          bf16x8 wh = *reinterpret_cast<const bf16x8*>(wp + kt * 32);
          bf16x8 wl = *reinterpret_cast<const bf16x8*>(wq + kt * 32);
          a = __builtin_amdgcn_mfma_f32_16x16x32_bf16(ah[kt], wh, a, 0, 0, 0);
          a = __builtin_amdgcn_mfma_f32_16x16x32_bf16(al[kt], wh, a, 0, 0, 0);
          a = __builtin_amdgcn_mfma_f32_16x16x32_bf16(ah[kt], wl, a, 0, 0, 0);
        }
        acc[ct] = a;
      }
#pragma unroll
      for (int gt = 0; gt < 4; ++gt) {
        int col = gt * 16 + (l & 15);
        float bia = B1[col];
#pragma unroll
        for (int r = 0; r < 4; ++r)
          A[(wv * 16 + (l >> 4) * 4 + r) * AS + col] = fmaxf(acc[gt][r] + bia, 0.f);
      }
    }

    // ---- L3: 64 -> 128, W cols [64,192), maxpool epilogue
    {
      bf16x8 ah[2], al[2];
      const float* ap = A + (wv * 16 + (l & 15)) * AS + (l >> 4) * 8;
#pragma unroll
      for (int kt = 0; kt < 2; ++kt) {
        float4 v0 = *reinterpret_cast<const float4*>(ap + kt * 32);
        float4 v1 = *reinterpret_cast<const float4*>(ap + kt * 32 + 4);
        float f[8] = {v0.x, v0.y, v0.z, v0.w, v1.x, v1.y, v1.z, v1.w};
        bf16x8 h, lo2;
#pragma unroll
        for (int j = 0; j < 8; ++j) {
          unsigned short hb = f2bh(f[j]);
          h[j] = (short)hb;
          lo2[j] = (short)f2bh(f[j] - bh2f(hb));
        }
        ah[kt] = h; al[kt] = lo2;
      }
#pragma unroll
      for (int i = 0; i < 8; ++i) acc[i] = f32x4{0.f, 0.f, 0.f, 0.f};
#pragma unroll
      for (int gt = 0; gt < 8; ++gt) {
        const unsigned short* wp = Wh + (C2 + gt * 16 + (l & 15)) * WS + (l >> 4) * 8;
        const unsigned short* wq = Wl + (C2 + gt * 16 + (l & 15)) * WS + (l >> 4) * 8;
        f32x4 a = acc[gt];
#pragma unroll
        for (int kt = 0; kt < 2; ++kt) {
          bf16x8 wh = *reinterpret_cast<const bf16x8*>(wp + kt * 32);
          bf16x8 wl = *reinterpret_cast<const bf16x8*>(wq + kt * 32);
          a = __builtin_amdgcn_mfma_f32_16x16x32_bf16(ah[kt], wh, a, 0, 0, 0);
          a = __builtin_amdgcn_mfma_f32_16x16x32_bf16(al[kt], wh, a, 0, 0, 0);
          a = __builtin_amdgcn_mfma_f32_16x16x32_bf16(ah[kt], wl, a, 0, 0, 0);
        }
        acc[gt] = a;
      }
#pragma unroll
      for (int gt = 0; gt < 8; ++gt) {
        int col = gt * 16 + (l & 15);
        float v = fmaxf(fmaxf(acc[gt][0], acc[gt][1]), fmaxf(acc[gt][2], acc[gt][3]));
        v = fmaxf(v, __shfl_xor(v, 16, 64));
        v = fmaxf(v, __shfl_xor(v, 32, 64));
        if (l < 16) red[wv][col] = v + B2[col];
      }
    }
    __syncthreads();
    constexpr int WPG = 4 / GPB;
    // f1 written PRE-SPLIT: hi = rne(v), lo = rne(v - hi). Identical values
    // to what sa2's staged split would compute -> bit-identical MFMA inputs.
    for (int u = t; u < GPB * C3; u += 256) {
      int g = u / C3, c2 = u - g * C3;
      float v = red[g * WPG][c2];
#pragma unroll
      for (int w = 1; w < WPG; ++w) v = fmaxf(v, red[g * WPG + w][c2]);
      v = fmaxf(v, 0.f);
      size_t o = ((size_t)b * Q + q0 + g) * C3 + c2;
      unsigned short h = f2bh(v);
      f1h[o] = h;
      f1l[o] = f2bh(v - bh2f(h));
    }
    __syncthreads();
  }
}

// [bq2 || sa1]
__global__ __launch_bounds__(256) void bq2_sa1_kernel(
    const float* __restrict__ xyz, const float* __restrict__ nx1,
    const float* __restrict__ nx2, int* __restrict__ gidx2, float r22,
    const int* __restrict__ gidx1,
    const float* __restrict__ s1w0, const float* __restrict__ s1b0,
    const unsigned short* __restrict__ g11h, const unsigned short* __restrict__ g11l,
    const float* __restrict__ s1b1,
    const unsigned short* __restrict__ g12h, const unsigned short* __restrict__ g12l,
    const float* __restrict__ s1b2,
    unsigned short* __restrict__ f1h, unsigned short* __restrict__ f1l) {
  if (blockIdx.x < 1024) {
    bq_body<512, 64>(nx1, nx2, gidx2, 128, r22, blockIdx.x, threadIdx.x);
    return;
  }
  sa1_body<4096, 512, 32, 2, 8>(xyz, nx1, gidx1, s1w0, s1b0, g11h, g11l, s1b1,
                                g12h, g12l, s1b2, f1h, f1l,
                                blockIdx.x - 1024, threadIdx.x);
}

// ---------------------------------------------------------------- SA3 fused (512 threads / 8 waves)
constexpr int AS3 = 532;
DEVINL void sa3_frags(const float* __restrict__ A, int l, int KT, bf16x8* ahi, bf16x8* alo) {
  const float* ap = A + (l & 15) * AS3 + (l >> 4) * 8;
  for (int kt = 0; kt < KT; ++kt) {
    float4 v0 = *reinterpret_cast<const float4*>(ap + kt * 32);
    float4 v1 = *reinterpret_cast<const float4*>(ap + kt * 32 + 4);
    float f[8] = {v0.x, v0.y, v0.z, v0.w, v1.x, v1.y, v1.z, v1.w};
    bf16x8 h, lo2;
#pragma unroll
    for (int j = 0; j < 8; ++j) {
      unsigned short hb = f2bh(f[j]);
      h[j] = (short)hb;
      lo2[j] = (short)f2bh(f[j] - bh2f(hb));
    }
    ahi[kt] = h; alo[kt] = lo2;
  }
}

template<int CT, int K>
DEVINL void sa3_mmN(const unsigned short* __restrict__ Gh, const unsigned short* __restrict__ Gl,
                    int ncol0, int l, const bf16x8* ahi, const bf16x8* alo, f32x4* acc4) {
  constexpr int KT = K / 32;
#pragma unroll
  for (int ct = 0; ct < CT; ++ct) {
    const unsigned short* hp = Gh + (size_t)(ncol0 + ct * 16 + (l & 15)) * K + (l >> 4) * 8;
    const unsigned short* lp = Gl + (size_t)(ncol0 + ct * 16 + (l & 15)) * K + (l >> 4) * 8;
    f32x4 a = acc4[ct];
#pragma unroll
    for (int kt = 0; kt < KT; ++kt) {
      bf16x8 wh = *reinterpret_cast<const bf16x8*>(hp + kt * 32);
      bf16x8 wl = *reinterpret_cast<const bf16x8*>(lp + kt * 32);
      a = __builtin_amdgcn_mfma_f32_16x16x32_bf16(ahi[kt], wh, a, 0, 0, 0);
      a = __builtin_amdgcn_mfma_f32_16x16x32_bf16(alo[kt], wh, a, 0, 0, 0);
      a = __builtin_amdgcn_mfma_f32_16x16x32_bf16(ahi[kt], wl, a, 0, 0, 0);
    }
    acc4[ct] = a;
  }
}

__global__ __launch_bounds__(512) void sa3f_kernel(
    const float* __restrict__ nx2, const float* __restrict__ f2,
    const float* __restrict__ W0full,
    const unsigned short* __restrict__ G0h, const unsigned short* __restrict__ G0l,
    const float* __restrict__ B0,
    const unsigned short* __restrict__ G1h, const unsigned short* __restrict__ G1l,
    const float* __restrict__ B1,
    const unsigned short* __restrict__ G2h, const unsigned short* __restrict__ G2l,
    const float* __restrict__ B2,
    float* __restrict__ partial) {
  __shared__ __align__(16) float A[16 * AS3];
  __shared__ float sxyz[16][4];
  const int t = threadIdx.x, l = t & 63, w = t >> 6;  // w in 0..7
  const int b = blockIdx.x >> 3, rb = blockIdx.x & 7;
  const int row0 = rb * 16;
  {
    int r = t >> 5, cc = (t & 31) * 8;
    const float* src = f2 + ((size_t)b * 128 + row0 + r) * 256 + cc;
    float* dstp = A + r * AS3 + cc;
#pragma unroll
    for (int j = 0; j < 8; j += 4)
      *reinterpret_cast<float4*>(dstp + j) = *reinterpret_cast<const float4*>(src + j);
    if (t < 16) {
      const float* s = nx2 + ((size_t)b * 128 + row0 + t) * 3;
      sxyz[t][0] = s[0]; sxyz[t][1] = s[1]; sxyz[t][2] = s[2];
    }
  }
  __syncthreads();

  {  // L1: K=256 MFMA + xyz f32 correction -> N=256 (wave cols 32)
    bf16x8 ah[8], al[8];
    sa3_frags(A, l, 8, ah, al);
    __syncthreads();
    f32x4 acc[2];
#pragma unroll
    for (int i = 0; i < 2; ++i) acc[i] = f32x4{0.f, 0.f, 0.f, 0.f};
    sa3_mmN<2, 256>(G0h, G0l, w * 32, l, ah, al, acc);
    float xr[4][3];
#pragma unroll
    for (int r = 0; r < 4; ++r) {
      int row = (l >> 4) * 4 + r;
      xr[r][0] = sxyz[row][0]; xr[r][1] = sxyz[row][1]; xr[r][2] = sxyz[row][2];
    }
#pragma unroll
    for (int ct = 0; ct < 2; ++ct) {
      int col = w * 32 + ct * 16 + (l & 15);
      float w0 = W0full[col], w1 = W0full[256 + col], w2 = W0full[512 + col];
      float bia = B0[col];
#pragma unroll
      for (int r = 0; r < 4; ++r) {
        int row = (l >> 4) * 4 + r;
        float v = acc[ct][r] + xr[r][0] * w0 + xr[r][1] * w1 + xr[r][2] * w2 + bia;
        A[row * AS3 + col] = fmaxf(v, 0.f);
      }
    }
    __syncthreads();
  }

  {  // L2: K=256 -> N=512 (wave cols 64)
    bf16x8 ah[8], al[8];
    sa3_frags(A, l, 8, ah, al);
    __syncthreads();
    f32x4 acc[4];
#pragma unroll
    for (int i = 0; i < 4; ++i) acc[i] = f32x4{0.f, 0.f, 0.f, 0.f};
    sa3_mmN<4, 256>(G1h, G1l, w * 64, l, ah, al, acc);
#pragma unroll
    for (int cc = 0; cc < 4; ++cc) {
      int col = w * 64 + cc * 16 + (l & 15);
      float bia = B1[col];
#pragma unroll
      for (int r = 0; r < 4; ++r) {
        int row = (l >> 4) * 4 + r;
        A[row * AS3 + col] = fmaxf(acc[cc][r] + bia, 0.f);
      }
    }
    __syncthreads();
  }

  {  // L3: K=512 -> N=1024 (wave cols 128 = 2 subs x 64), maxpool -> partial
    bf16x8 ah[16], al[16];
    sa3_frags(A, l, 16, ah, al);
    float* pout = partial + ((size_t)(b * 8 + rb)) * 1024;
#pragma unroll
    for (int sub = 0; sub < 2; ++sub) {
      f32x4 acc[4];
#pragma unroll
      for (int i = 0; i < 4; ++i) acc[i] = f32x4{0.f, 0.f, 0.f, 0.f};
      sa3_mmN<4, 512>(G2h, G2l, w * 128 + sub * 64, l, ah, al, acc);
#pragma unroll
      for (int ct = 0; ct < 4; ++ct) {
        int col = w * 128 + sub * 64 + ct * 16 + (l & 15);
        float v = fmaxf(fmaxf(acc[ct][0], acc[ct][1]), fmaxf(acc[ct][2], acc[ct][3]));
        v = fmaxf(v, __shfl_xor(v, 16, 64));
        v = fmaxf(v, __shfl_xor(v, 32, 64));
        if (l < 16) pout[col] = v + B2[col];  // relu deferred to heads (monotone)
      }
    }
  }
}

// ---------------------------------------------------------------- heads (8-way partial max + relu + dots)
__global__ __launch_bounds__(256) void heads_kernel(const float* __restrict__ partial,
                                                    const float* __restrict__ cw,
                                                    const float* __restrict__ cb,
                                                    const float* __restrict__ rw,
                                                    const float* __restrict__ rb,
                                                    float* __restrict__ out) {
  const int b = blockIdx.x, t = threadIdx.x;
  const float* pb = partial + (size_t)b * 8 * 1024;
  float a0 = 0, a1 = 0, a2 = 0, a3 = 0, a4 = 0;
  for (int k = t; k < 1024; k += 256) {
    float m = pb[k];
#pragma unroll
    for (int p = 1; p < 8; ++p) m = fmaxf(m, pb[p * 1024 + k]);
    float f = fmaxf(m, 0.f);
    a0 += f * cw[k];
    const float* r = rw + (size_t)k * 4;
    a1 += f * r[0]; a2 += f * r[1]; a3 += f * r[2]; a4 += f * r[3];
  }
#pragma unroll
  for (int m = 32; m >= 1; m >>= 1) {
    a0 += __shfl_xor(a0, m, 64); a1 += __shfl_xor(a1, m, 64);
    a2 += __shfl_xor(a2, m, 64); a3 += __shfl_xor(a3, m, 64);
    a4 += __shfl_xor(a4, m, 64);
  }
  __shared__ float red[4][5];
  const int wv = t >> 6, ln = t & 63;
  if (ln == 0) { red[wv][0] = a0; red[wv][1] = a1; red[wv][2] = a2; red[wv][3] = a3; red[wv][4] = a4; }
  __syncthreads();
  if (t == 0) {
    float s0 = red[0][0] + red[1][0] + red[2][0] + red[3][0];
    float s1 = red[0][1] + red[1][1] + red[2][1] + red[3][1];
    float s2 = red[0][2] + red[1][2] + red[2][2] + red[3][2];
    float s3 = red[0][3] + red[1][3] + red[2][3] + red[3][3];
    float s4 = red[0][4] + red[1][4] + red[2][4] + red[3][4];
    out[b] = s0 + cb[0];
    out[32 + b * 4 + 0] = s1 + rb[0];
    out[32 + b * 4 + 1] = s2 + rb[1];
    out[32 + b * 4 + 2] = s3 + rb[2];
    out[32 + b * 4 + 3] = s4 + rb[3];
  }
}

// ---------------------------------------------------------------- launch
extern "C" void kernel_launch(void* const* d_in, const int* in_sizes, int n_in,
                              void* d_out, int out_size, void* d_ws, size_t ws_size,
                              hipStream_t stream) {
  (void)in_sizes; (void)n_in; (void)out_size; (void)ws_size;
  const float* xyz  = (const float*)d_in[0];
  const float* s1w0 = (const float*)d_in[1];  const float* s1b0 = (const float*)d_in[2];
  const float* s1w1 = (const float*)d_in[3];  const float* s1b1 = (const float*)d_in[4];
  const float* s1w2 = (const float*)d_in[5];  const float* s1b2 = (const float*)d_in[6];
  const float* s2w0 = (const float*)d_in[7];  const float* s2b0 = (const float*)d_in[8];
  const float* s2w1 = (const float*)d_in[9];  const float* s2b1 = (const float*)d_in[10];
  const float* s2w2 = (const float*)d_in[11]; const float* s2b2 = (const float*)d_in[12];
  const float* s3w0 = (const float*)d_in[13]; const float* s3b0 = (const float*)d_in[14];
  const float* s3w1 = (const float*)d_in[15]; const float* s3b1 = (const float*)d_in[16];
  const float* s3w2 = (const float*)d_in[17]; const float* s3b2 = (const float*)d_in[18];
  const float* clsw = (const float*)d_in[19]; const float* clsb = (const float*)d_in[20];
  const float* regw = (const float*)d_in[21]; const float* regb = (const float*)d_in[22];

  char* ws = (char*)d_ws;
  float* nx1   = (float*)(ws + 0);          // 32*512*3
  int*   gidx1 = (int*)  (ws + 196608);     // 32*512*32
  unsigned short* f1h = (unsigned short*)(ws + 2293760);  // 32*512*128 u16 = 4 MB
  unsigned short* f1l = (unsigned short*)(ws + 6488064);  // 4 MB
  float* nx2   = (float*)(ws + 10682368);   // 32*128*3
  int*   gidx2 = (int*)  (ws + 10731520);   // 32*128*64
  float* f2    = (float*)(ws + 11780096);   // 32*128*256

  // SA1/SA2 prepped weights (u16 hi/lo, transposed [n][k])
  unsigned short* wt = (unsigned short*)(ws + 20168704);
  unsigned short* g11h = wt;            // 64*64
  unsigned short* g11l = wt + 4096;
  unsigned short* g12h = wt + 8192;     // 128*64
  unsigned short* g12l = wt + 16384;
  unsigned short* g20h = wt + 24576;    // 128*128 (rows 3..130 of s2w0)
  unsigned short* g20l = wt + 40960;
  unsigned short* g21h = wt + 57344;    // 128*128
  unsigned short* g21l = wt + 73728;
  unsigned short* g22h = wt + 90112;    // 256*128
  unsigned short* g22l = wt + 122880;   // ends at byte 20168704+311296 = 20480000
  // SA3 prepped weights
  unsigned short* g30h = (unsigned short*)(ws + 20480000);  // 256x256
  unsigned short* g30l = (unsigned short*)(ws + 20611072);
  unsigned short* g31h = (unsigned short*)(ws + 20742144);  // 512x256
  unsigned short* g31l = (unsigned short*)(ws + 21004288);
  unsigned short* g32h = (unsigned short*)(ws + 21266432);  // 1024x512
  unsigned short* g32l = (unsigned short*)(ws + 22315008);
  float* partial = (float*)(ws + 23363584);                 // 32*8*1024 f32 -> ends 24412160

  const float r21 = (float)(0.2 * 0.2);
  const float r22 = (float)(0.4 * 0.4);

  WPTab tab;
  int off = 0;
  auto set = [&](int i, const float* W, unsigned short* hi, unsigned short* lo,
                 int K, int N, int row0) {
    tab.e[i] = WPEnt{W, hi, lo, K, N, row0, off, off + K * N};
    off += K * N;
  };
  set(0, s1w1, g11h, g11l, 64, 64, 0);
  set(1, s1w2, g12h, g12l, 64, 128, 0);
  set(2, s2w0, g20h, g20l, 128, 128, 3);
  set(3, s2w1, g21h, g21l, 128, 128, 0);
  set(4, s2w2, g22h, g22l, 128, 256, 0);
  set(5, s3w0, g30h, g30l, 256, 256, 3);
  set(6, s3w1, g31h, g31l, 256, 512, 0);
  set(7, s3w2, g32h, g32l, 512, 1024, 0);
  const int wblocks = (off + 255) / 256;

  fps1_wprep_kernel<<<32 + wblocks, 256, 0, stream>>>(xyz, nx1, tab);
  fps2_bq1_kernel<<<32 + 4096, 256, 0, stream>>>(xyz, nx1, gidx1, nx2, r21);
  bq2_sa1_kernel<<<1024 + 1024, 256, 0, stream>>>(
      xyz, nx1, nx2, gidx2, r22, gidx1,
      s1w0, s1b0, g11h, g11l, s1b1, g12h, g12l, s1b2, f1h, f1l);
  sa2_kernel<512, 128, 64, 2, 128, 128, 128, 256><<<2048, 512, 0, stream>>>(
      nx1, nx2, gidx2, f1h, f1l, s2w0, s2b0,
      g20h, g20l, g21h, g21l, s2b1, g22h, g22l, s2b2, f2);
  sa3f_kernel<<<256, 512, 0, stream>>>(nx2, f2, s3w0, g30h, g30l, s3b0,
                                       g31h, g31l, s3b1, g32h, g32l, s3b2, partial);
  heads_kernel<<<32, 256, 0, stream>>>(partial, clsw, clsb, regw, regb, (float*)d_out);
}